// Round 1
// 1910.701 us; speedup vs baseline: 2.0773x; 2.0773x over previous
//
#include <hip/hip_runtime.h>
#include <hip/hip_bf16.h>

#define BB 2
#define LL 2048
#define DD 1024
#define HH 16
#define DK 64
#define UU 40
#define BH (BB*HH)

typedef unsigned short u16;

__device__ inline float b2f_r8(u16 x) {
    union { unsigned short u; __hip_bfloat16 b; } c; c.u = x;
    return __bfloat162float(c.b);
}
// dual-dtype element load (fp32 or bf16 input), wave-uniform isF
__device__ inline float ldf_r8(const void* p, size_t i, int isF) {
    return isF ? ((const float*)p)[i] : b2f_r8(((const u16*)p)[i]);
}

// ---------------- K0: input dtype probe ----------------
__global__ __launch_bounds__(256) void detect_dtype_r8(const u16* __restrict__ q,
                                                       int* __restrict__ flag) {
    __shared__ float red[256];
    int tid = threadIdx.x;
    float mx = 0.f;
    for (int i = tid; i < 4096; i += 256) {
        float v = fabsf(b2f_r8(q[i]));
        if (!(v < 1e30f)) v = 1e38f;
        mx = fmaxf(mx, v);
    }
    red[tid] = mx; __syncthreads();
    for (int s = 128; s > 0; s >>= 1) {
        if (tid < s) red[tid] = fmaxf(red[tid], red[tid + s]);
        __syncthreads();
    }
    if (tid == 0) *flag = (red[0] > 1e20f) ? 1 : 0;
}

// ------------- K1: exact K projection, fp64 accum, hi/lo fp32 store -------------
__global__ __launch_bounds__(256) void kproj_exact_r8(
    const void* __restrict__ X, const void* __restrict__ W,
    const void* __restrict__ bias, float* __restrict__ Khi,
    float* __restrict__ Klo, const int* __restrict__ flag)
{
    __shared__ float sx[64 * 65];
    __shared__ float sw[64 * 65];
    int tid = threadIdx.x;
    int n0 = blockIdx.x * 64, f0 = blockIdx.y * 64;
    int isF = *flag;
    int ty = tid >> 4, tx = tid & 15;
    double acc[4][4] = {};
    for (int kc = 0; kc < 16; ++kc) {
        __syncthreads();
        for (int i = tid; i < 4096; i += 256) {
            int r = i >> 6, c = i & 63;
            sx[r * 65 + c] = ldf_r8(X, (size_t)(n0 + r) * DD + kc * 64 + c, isF);
            sw[r * 65 + c] = ldf_r8(W, (size_t)(f0 + r) * DD + kc * 64 + c, isF);
        }
        __syncthreads();
        for (int c = 0; c < 64; ++c) {
            double xa[4], wb[4];
#pragma unroll
            for (int a = 0; a < 4; ++a) xa[a] = (double)sx[(ty * 4 + a) * 65 + c];
#pragma unroll
            for (int q = 0; q < 4; ++q) wb[q] = (double)sw[(tx * 4 + q) * 65 + c];
#pragma unroll
            for (int a = 0; a < 4; ++a)
#pragma unroll
                for (int q = 0; q < 4; ++q) acc[a][q] += xa[a] * wb[q];
        }
    }
#pragma unroll
    for (int a = 0; a < 4; ++a) {
        int n = n0 + ty * 4 + a, b = n >> 11, l = n & (LL - 1);
#pragma unroll
        for (int q = 0; q < 4; ++q) {
            int f = f0 + tx * 4 + q, h = f >> 6, dk = f & 63;
            double v = acc[a][q] + (double)ldf_r8(bias, (size_t)f, isF);
            size_t o = ((size_t)(b * HH + h) * LL + l) * DK + dk;
            float hi = (float)v;
            Khi[o] = hi;
            Klo[o] = (float)(v - (double)hi);
        }
    }
}

// ---------------- K2: generic fp32 projection (used for V and Q) ----------------
__global__ __launch_bounds__(256) void proj_v_r8(
    const void* __restrict__ X, const void* __restrict__ W,
    const void* __restrict__ bias, float* __restrict__ out,
    const int* __restrict__ flag)
{
    __shared__ float sx[64 * 65];
    __shared__ float sw[64 * 65];
    int tid = threadIdx.x;
    int n0 = blockIdx.x * 64, f0 = blockIdx.y * 64;
    int isF = *flag;
    int ty = tid >> 4, tx = tid & 15;
    float acc[4][4] = {};
    for (int kc = 0; kc < 16; ++kc) {
        __syncthreads();
        for (int i = tid; i < 4096; i += 256) {
            int r = i >> 6, c = i & 63;
            sx[r * 65 + c] = ldf_r8(X, (size_t)(n0 + r) * DD + kc * 64 + c, isF);
            sw[r * 65 + c] = ldf_r8(W, (size_t)(f0 + r) * DD + kc * 64 + c, isF);
        }
        __syncthreads();
        for (int c = 0; c < 64; ++c) {
            float xa[4], wb[4];
#pragma unroll
            for (int a = 0; a < 4; ++a) xa[a] = sx[(ty * 4 + a) * 65 + c];
#pragma unroll
            for (int q = 0; q < 4; ++q) wb[q] = sw[(tx * 4 + q) * 65 + c];
#pragma unroll
            for (int a = 0; a < 4; ++a)
#pragma unroll
                for (int q = 0; q < 4; ++q) acc[a][q] = fmaf(xa[a], wb[q], acc[a][q]);
        }
    }
#pragma unroll
    for (int a = 0; a < 4; ++a) {
        int n = n0 + ty * 4 + a, b = n >> 11, l = n & (LL - 1);
#pragma unroll
        for (int q = 0; q < 4; ++q) {
            int f = f0 + tx * 4 + q, h = f >> 6, dk = f & 63;
            out[((size_t)(b * HH + h) * LL + l) * DK + dk] = acc[a][q] + ldf_r8(bias, (size_t)f, isF);
        }
    }
}

// ---------------- K2b: Kbar[bh][d] = mean over l of exact K (fp64) ----------------
__global__ __launch_bounds__(256) void kbar_r8(
    const float* __restrict__ Khi, const float* __restrict__ Klo,
    double* __restrict__ Kbar)
{
    __shared__ double red[256];
    int bh = blockIdx.x, tid = threadIdx.x;
    int d = tid & 63, seg = tid >> 6;
    double s = 0;
    for (int l = seg * 512; l < seg * 512 + 512; ++l) {
        size_t o = ((size_t)bh * LL + l) * DK + d;
        s += (double)Khi[o] + (double)Klo[o];
    }
    red[tid] = s; __syncthreads();
    if (tid < 128) red[tid] += red[tid + 128];
    __syncthreads();
    if (tid < 64) Kbar[(size_t)bh * DK + d] = (red[tid] + red[tid + 64]) * (1.0 / (double)LL);
}

// ---- K3: rowmax(Q K^T) via fp32 register-tiled GEMM; M = rowmax - Q.Kbar ----
// 128q x 128k tiles, d-major LDS (PAD=132 => 16B-aligned rows, 2-way max conflicts).
#define QT 128
#define KT 128
#define PAD 132
__global__ __launch_bounds__(256) void stats_max_r8(
    const float* __restrict__ Qf, const float* __restrict__ Khi,
    const double* __restrict__ Kbar, double* __restrict__ Mv)
{
    __shared__ float sQ[64 * PAD];
    __shared__ float sK[64 * PAD];
    __shared__ float rowmax[QT];
    int tid = threadIdx.x;
    int q0 = blockIdx.x * QT, bh = blockIdx.y;
    int tx = tid & 15, ty = tid >> 4;

    // stage Q tile transposed to d-major: sQ[d][row]
    {
        const float* src = Qf + ((size_t)bh * LL + q0) * DK;
#pragma unroll
        for (int j = 0; j < 8; ++j) {
            int row = (tid >> 4) + j * 16;
            int d0 = (tid & 15) * 4;
            const float4 v = *(const float4*)(src + (size_t)row * DK + d0);
            sQ[(d0 + 0) * PAD + row] = v.x;
            sQ[(d0 + 1) * PAD + row] = v.y;
            sQ[(d0 + 2) * PAD + row] = v.z;
            sQ[(d0 + 3) * PAD + row] = v.w;
        }
    }
    float rmax8[8];
#pragma unroll
    for (int a = 0; a < 8; ++a) rmax8[a] = -INFINITY;

    const float* kbase = Khi + (size_t)bh * LL * DK;
    for (int kc = 0; kc < LL / KT; ++kc) {
        __syncthreads();   // guard sK rewrite vs previous compute (and sQ at kc=0)
#pragma unroll
        for (int j = 0; j < 8; ++j) {
            int row = (tid >> 4) + j * 16;
            int d0 = (tid & 15) * 4;
            const float4 v = *(const float4*)(kbase + (size_t)(kc * KT + row) * DK + d0);
            sK[(d0 + 0) * PAD + row] = v.x;
            sK[(d0 + 1) * PAD + row] = v.y;
            sK[(d0 + 2) * PAD + row] = v.z;
            sK[(d0 + 3) * PAD + row] = v.w;
        }
        __syncthreads();
        float acc[8][8];
#pragma unroll
        for (int a = 0; a < 8; ++a)
#pragma unroll
            for (int c = 0; c < 8; ++c) acc[a][c] = 0.f;
        for (int d = 0; d < 64; ++d) {
            const float4 qa = *(const float4*)(&sQ[d * PAD + ty * 4]);
            const float4 qb = *(const float4*)(&sQ[d * PAD + 64 + ty * 4]);
            const float4 ka = *(const float4*)(&sK[d * PAD + tx * 4]);
            const float4 kb = *(const float4*)(&sK[d * PAD + 64 + tx * 4]);
            float qv[8] = {qa.x, qa.y, qa.z, qa.w, qb.x, qb.y, qb.z, qb.w};
            float kv[8] = {ka.x, ka.y, ka.z, ka.w, kb.x, kb.y, kb.z, kb.w};
#pragma unroll
            for (int a = 0; a < 8; ++a)
#pragma unroll
                for (int c = 0; c < 8; ++c)
                    acc[a][c] = fmaf(qv[a], kv[c], acc[a][c]);
        }
#pragma unroll
        for (int a = 0; a < 8; ++a)
#pragma unroll
            for (int c = 0; c < 8; ++c) rmax8[a] = fmaxf(rmax8[a], acc[a][c]);
    }
    // cross-tx max reduce within 16-lane groups (tx = lane&15)
#pragma unroll
    for (int a = 0; a < 8; ++a) {
        float v = rmax8[a];
        v = fmaxf(v, __shfl_xor(v, 1));
        v = fmaxf(v, __shfl_xor(v, 2));
        v = fmaxf(v, __shfl_xor(v, 4));
        v = fmaxf(v, __shfl_xor(v, 8));
        rmax8[a] = v;
    }
    if (tx == 0) {
#pragma unroll
        for (int a = 0; a < 8; ++a) {
            int row = ty * 4 + (a & 3) + (a >> 2) * 64;
            rowmax[row] = rmax8[a];
        }
    }
    __syncthreads();
    if (tid < QT) {
        const double* kb = Kbar + (size_t)bh * DK;
        double s = 0;
#pragma unroll
        for (int d = 0; d < 64; ++d) s += (double)sQ[d * PAD + tid] * kb[d];
        Mv[(size_t)bh * LL + q0 + tid] = (double)rowmax[tid] - s;
    }
}

// ------- K4: exact top-40 per (b,h), DESCENDING (jax.lax.top_k), tie->low -------
__global__ __launch_bounds__(256) void topk_exact_r8(
    const double* __restrict__ Mv, int* __restrict__ sel)
{
    __shared__ double vals[LL];
    __shared__ double rv[256];
    __shared__ int ri[256];
    int bh = blockIdx.x, tid = threadIdx.x;
    for (int j = tid; j < LL; j += 256) vals[j] = Mv[(size_t)bh * LL + j];
    __syncthreads();
    for (int u = 0; u < UU; ++u) {
        double bv = -1e301; int bi = LL;
        for (int j = tid; j < LL; j += 256) {
            double v = vals[j];
            if (v > bv) { bv = v; bi = j; }
        }
        rv[tid] = bv; ri[tid] = bi;
        __syncthreads();
        for (int s = 128; s > 0; s >>= 1) {
            if (tid < s) {
                double ov = rv[tid + s]; int oi = ri[tid + s];
                if (ov > rv[tid] || (ov == rv[tid] && oi < ri[tid])) {
                    rv[tid] = ov; ri[tid] = oi;
                }
            }
            __syncthreads();
        }
        if (tid == 0) { sel[bh * UU + u] = ri[0]; vals[ri[0]] = -1e302; }
        __syncthreads();
    }
}

// ---- K5: exact q-row proj + scores + causal + softmax + probs + PV + attn ----
// OUTPUTS ARE FLOAT32 (reference output dtype is jnp.float32).
__global__ __launch_bounds__(256) void attn_out_r8(
    const void* __restrict__ query, const void* __restrict__ Wq,
    const void* __restrict__ bq, const float* __restrict__ Khi,
    const float* __restrict__ Klo, const float* __restrict__ Vf,
    const int* __restrict__ sel, float* __restrict__ attnOut,
    float* __restrict__ probsOut, const int* __restrict__ flag)
{
    __shared__ double qd[DK];
    __shared__ double redD[256];
    __shared__ float pl[LL];
    __shared__ float red[256];
    int u = blockIdx.x, bh = blockIdx.y, tid = threadIdx.x;
    int b = bh >> 4, h = bh & 15;
    int isF = *flag;
    int qpos = sel[bh * UU + u];

    {
        int dk = tid & 63, kg = tid >> 6;
        double s = 0;
        for (int k = kg * 256; k < kg * 256 + 256; ++k)
            s += (double)ldf_r8(query, ((size_t)b * LL + qpos) * DD + k, isF)
               * (double)ldf_r8(Wq, (size_t)(h * 64 + dk) * DD + k, isF);
        redD[tid] = s; __syncthreads();
        if (tid < 64) {
            double t = redD[tid] + redD[tid + 64] + redD[tid + 128] + redD[tid + 192];
            qd[tid] = t + (double)ldf_r8(bq, (size_t)(h * 64 + tid), isF);
        }
        __syncthreads();
    }

    float sloc[8];
    float lmax = -INFINITY;
#pragma unroll
    for (int c = 0; c < 8; ++c) {
        int l = c * 256 + tid;
        size_t o = ((size_t)bh * LL + l) * DK;
        double s = 0;
        for (int d = 0; d < 64; ++d)
            s += qd[d] * ((double)Khi[o + d] + (double)Klo[o + d]);
        float sf = (float)(s * 0.125);
        if (l > qpos) sf -= 1e9f;
        sloc[c] = sf;
        lmax = fmaxf(lmax, sf);
    }
    red[tid] = lmax; __syncthreads();
    for (int s2 = 128; s2 > 0; s2 >>= 1) {
        if (tid < s2) red[tid] = fmaxf(red[tid], red[tid + s2]);
        __syncthreads();
    }
    float mval = red[0];
    __syncthreads();
    float lsum = 0.f;
#pragma unroll
    for (int c = 0; c < 8; ++c) { sloc[c] = expf(sloc[c] - mval); lsum += sloc[c]; }
    red[tid] = lsum; __syncthreads();
    for (int s2 = 128; s2 > 0; s2 >>= 1) {
        if (tid < s2) red[tid] += red[tid + s2];
        __syncthreads();
    }
    float inv = 1.0f / red[0];
    size_t rowo = ((size_t)bh * UU + u) * LL;
#pragma unroll
    for (int c = 0; c < 8; ++c) {
        int l = c * 256 + tid;
        float p = sloc[c] * inv;
        pl[l] = p;
        probsOut[rowo + l] = p;           // fp32 store
    }
    __syncthreads();

    int dk = tid & 63, c4 = tid >> 6;
    const float* vb = Vf + (size_t)bh * LL * DK;
    float acc = 0.f;
    for (int l = c4 * (LL / 4); l < (c4 + 1) * (LL / 4); ++l)
        acc = fmaf(pl[l], vb[(size_t)l * DK + dk], acc);
    red[tid] = acc; __syncthreads();
    if (tid < 64) {
        float s2 = red[tid] + red[tid + 64] + red[tid + 128] + red[tid + 192];
        attnOut[((size_t)b * UU + u) * DD + h * DK + dk] = s2;   // fp32 store
    }
}

extern "C" void kernel_launch(void* const* d_in, const int* in_sizes, int n_in,
                              void* d_out, int out_size, void* d_ws, size_t ws_size,
                              hipStream_t stream) {
    (void)in_sizes; (void)n_in; (void)out_size; (void)ws_size;
    const void* query = d_in[0];
    const void* key   = d_in[1];
    const void* value = d_in[2];
    const void* Wq    = d_in[3];
    const void* bq    = d_in[4];
    const void* Wk    = d_in[5];
    const void* bk    = d_in[6];
    const void* Wv    = d_in[7];
    const void* bv    = d_in[8];

    char* w = (char*)d_ws;
    const size_t NE = (size_t)BB * HH * LL * DK;   // 4,194,304
    float* Khi = (float*)w;  w += NE * 4;
    float* Klo = (float*)w;  w += NE * 4;
    float* Vf  = (float*)w;  w += NE * 4;
    float* Qf  = (float*)w;  w += NE * 4;
    double* Mv = (double*)w; w += (size_t)BH * LL * 8;
    double* Kbar = (double*)w; w += (size_t)BH * DK * 8;
    int* sel   = (int*)w;    w += (size_t)BH * UU * 4;
    int* flag  = (int*)w;    w += 64;

    float* attnOut  = (float*)d_out;                       // FP32 outputs
    float* probsOut = attnOut + (size_t)BB * UU * DD;

    dim3 blk(256);
    detect_dtype_r8<<<1, blk, 0, stream>>>((const u16*)query, flag);
    kproj_exact_r8<<<dim3(64, 16), blk, 0, stream>>>(key, Wk, bk, Khi, Klo, flag);
    proj_v_r8<<<dim3(64, 16), blk, 0, stream>>>(value, Wv, bv, Vf, flag);
    proj_v_r8<<<dim3(64, 16), blk, 0, stream>>>(query, Wq, bq, Qf, flag);
    kbar_r8<<<32, blk, 0, stream>>>(Khi, Klo, Kbar);
    stats_max_r8<<<dim3(LL / QT, 32), blk, 0, stream>>>(Qf, Khi, Kbar, Mv);
    topk_exact_r8<<<32, blk, 0, stream>>>(Mv, sel);
    attn_out_r8<<<dim3(UU, 32), blk, 0, stream>>>(query, Wq, bq, Khi, Klo, Vf,
                                                  sel, attnOut, probsOut, flag);
}

// Round 2
// 1405.393 us; speedup vs baseline: 2.8241x; 1.3595x over previous
//
#include <hip/hip_runtime.h>
#include <hip/hip_bf16.h>

#define BB 2
#define LL 2048
#define DD 1024
#define HH 16
#define DK 64
#define UU 40
#define BH (BB*HH)

typedef unsigned short u16;

__device__ inline float b2f_r8(u16 x) {
    union { unsigned short u; __hip_bfloat16 b; } c; c.u = x;
    return __bfloat162float(c.b);
}
// dual-dtype element load (fp32 or bf16 input), wave-uniform isF
__device__ inline float ldf_r8(const void* p, size_t i, int isF) {
    return isF ? ((const float*)p)[i] : b2f_r8(((const u16*)p)[i]);
}

// ---------------- K0: input dtype probe ----------------
__global__ __launch_bounds__(256) void detect_dtype_r8(const u16* __restrict__ q,
                                                       int* __restrict__ flag) {
    __shared__ float red[256];
    int tid = threadIdx.x;
    float mx = 0.f;
    for (int i = tid; i < 4096; i += 256) {
        float v = fabsf(b2f_r8(q[i]));
        if (!(v < 1e30f)) v = 1e38f;
        mx = fmaxf(mx, v);
    }
    red[tid] = mx; __syncthreads();
    for (int s = 128; s > 0; s >>= 1) {
        if (tid < s) red[tid] = fmaxf(red[tid], red[tid + s]);
        __syncthreads();
    }
    if (tid == 0) *flag = (red[0] > 1e20f) ? 1 : 0;
}

// ---------------- K1: generic fp32 projection (used for K, V and Q) ----------------
__global__ __launch_bounds__(256) void proj_v_r8(
    const void* __restrict__ X, const void* __restrict__ W,
    const void* __restrict__ bias, float* __restrict__ out,
    const int* __restrict__ flag)
{
    __shared__ float sx[64 * 65];
    __shared__ float sw[64 * 65];
    int tid = threadIdx.x;
    int n0 = blockIdx.x * 64, f0 = blockIdx.y * 64;
    int isF = *flag;
    int ty = tid >> 4, tx = tid & 15;
    float acc[4][4] = {};
    for (int kc = 0; kc < 16; ++kc) {
        __syncthreads();
        for (int i = tid; i < 4096; i += 256) {
            int r = i >> 6, c = i & 63;
            sx[r * 65 + c] = ldf_r8(X, (size_t)(n0 + r) * DD + kc * 64 + c, isF);
            sw[r * 65 + c] = ldf_r8(W, (size_t)(f0 + r) * DD + kc * 64 + c, isF);
        }
        __syncthreads();
        for (int c = 0; c < 64; ++c) {
            float xa[4], wb[4];
#pragma unroll
            for (int a = 0; a < 4; ++a) xa[a] = sx[(ty * 4 + a) * 65 + c];
#pragma unroll
            for (int q = 0; q < 4; ++q) wb[q] = sw[(tx * 4 + q) * 65 + c];
#pragma unroll
            for (int a = 0; a < 4; ++a)
#pragma unroll
                for (int q = 0; q < 4; ++q) acc[a][q] = fmaf(xa[a], wb[q], acc[a][q]);
        }
    }
#pragma unroll
    for (int a = 0; a < 4; ++a) {
        int n = n0 + ty * 4 + a, b = n >> 11, l = n & (LL - 1);
#pragma unroll
        for (int q = 0; q < 4; ++q) {
            int f = f0 + tx * 4 + q, h = f >> 6, dk = f & 63;
            out[((size_t)(b * HH + h) * LL + l) * DK + dk] = acc[a][q] + ldf_r8(bias, (size_t)f, isF);
        }
    }
}

// ---------------- K2b: Kbar[bh][d] = mean over l of K (fp64 accumulate) ----------------
__global__ __launch_bounds__(256) void kbar_r8(
    const float* __restrict__ Kf, double* __restrict__ Kbar)
{
    __shared__ double red[256];
    int bh = blockIdx.x, tid = threadIdx.x;
    int d = tid & 63, seg = tid >> 6;
    double s = 0;
    for (int l = seg * 512; l < seg * 512 + 512; ++l)
        s += (double)Kf[((size_t)bh * LL + l) * DK + d];
    red[tid] = s; __syncthreads();
    if (tid < 128) red[tid] += red[tid + 128];
    __syncthreads();
    if (tid < 64) Kbar[(size_t)bh * DK + d] = (red[tid] + red[tid + 64]) * (1.0 / (double)LL);
}

// ---- K3: rowmax(Q K^T) via fp32 register-tiled GEMM; M = rowmax - Q.Kbar ----
// 128q x 128k tiles, d-major LDS (PAD=132 => 16B-aligned rows, 2-way max conflicts).
#define QT 128
#define KT 128
#define PAD 132
__global__ __launch_bounds__(256) void stats_max_r8(
    const float* __restrict__ Qf, const float* __restrict__ Kf,
    const double* __restrict__ Kbar, double* __restrict__ Mv)
{
    __shared__ float sQ[64 * PAD];
    __shared__ float sK[64 * PAD];
    __shared__ float rowmax[QT];
    int tid = threadIdx.x;
    int q0 = blockIdx.x * QT, bh = blockIdx.y;
    int tx = tid & 15, ty = tid >> 4;

    // stage Q tile transposed to d-major: sQ[d][row]
    {
        const float* src = Qf + ((size_t)bh * LL + q0) * DK;
#pragma unroll
        for (int j = 0; j < 8; ++j) {
            int row = (tid >> 4) + j * 16;
            int d0 = (tid & 15) * 4;
            const float4 v = *(const float4*)(src + (size_t)row * DK + d0);
            sQ[(d0 + 0) * PAD + row] = v.x;
            sQ[(d0 + 1) * PAD + row] = v.y;
            sQ[(d0 + 2) * PAD + row] = v.z;
            sQ[(d0 + 3) * PAD + row] = v.w;
        }
    }
    float rmax8[8];
#pragma unroll
    for (int a = 0; a < 8; ++a) rmax8[a] = -INFINITY;

    const float* kbase = Kf + (size_t)bh * LL * DK;
    for (int kc = 0; kc < LL / KT; ++kc) {
        __syncthreads();   // guard sK rewrite vs previous compute (and sQ at kc=0)
#pragma unroll
        for (int j = 0; j < 8; ++j) {
            int row = (tid >> 4) + j * 16;
            int d0 = (tid & 15) * 4;
            const float4 v = *(const float4*)(kbase + (size_t)(kc * KT + row) * DK + d0);
            sK[(d0 + 0) * PAD + row] = v.x;
            sK[(d0 + 1) * PAD + row] = v.y;
            sK[(d0 + 2) * PAD + row] = v.z;
            sK[(d0 + 3) * PAD + row] = v.w;
        }
        __syncthreads();
        float acc[8][8];
#pragma unroll
        for (int a = 0; a < 8; ++a)
#pragma unroll
            for (int c = 0; c < 8; ++c) acc[a][c] = 0.f;
        for (int d = 0; d < 64; ++d) {
            const float4 qa = *(const float4*)(&sQ[d * PAD + ty * 4]);
            const float4 qb = *(const float4*)(&sQ[d * PAD + 64 + ty * 4]);
            const float4 ka = *(const float4*)(&sK[d * PAD + tx * 4]);
            const float4 kb = *(const float4*)(&sK[d * PAD + 64 + tx * 4]);
            float qv[8] = {qa.x, qa.y, qa.z, qa.w, qb.x, qb.y, qb.z, qb.w};
            float kv[8] = {ka.x, ka.y, ka.z, ka.w, kb.x, kb.y, kb.z, kb.w};
#pragma unroll
            for (int a = 0; a < 8; ++a)
#pragma unroll
                for (int c = 0; c < 8; ++c)
                    acc[a][c] = fmaf(qv[a], kv[c], acc[a][c]);
        }
#pragma unroll
        for (int a = 0; a < 8; ++a)
#pragma unroll
            for (int c = 0; c < 8; ++c) rmax8[a] = fmaxf(rmax8[a], acc[a][c]);
    }
    // cross-tx max reduce within 16-lane groups (tx = lane&15)
#pragma unroll
    for (int a = 0; a < 8; ++a) {
        float v = rmax8[a];
        v = fmaxf(v, __shfl_xor(v, 1));
        v = fmaxf(v, __shfl_xor(v, 2));
        v = fmaxf(v, __shfl_xor(v, 4));
        v = fmaxf(v, __shfl_xor(v, 8));
        rmax8[a] = v;
    }
    if (tx == 0) {
#pragma unroll
        for (int a = 0; a < 8; ++a) {
            int row = ty * 4 + (a & 3) + (a >> 2) * 64;
            rowmax[row] = rmax8[a];
        }
    }
    __syncthreads();
    if (tid < QT) {
        const double* kb = Kbar + (size_t)bh * DK;
        double s = 0;
#pragma unroll
        for (int d = 0; d < 64; ++d) s += (double)sQ[d * PAD + tid] * kb[d];
        Mv[(size_t)bh * LL + q0 + tid] = (double)rowmax[tid] - s;
    }
}

// ------- K4: exact top-40 per (b,h), DESCENDING (jax.lax.top_k), tie->low -------
__global__ __launch_bounds__(256) void topk_exact_r8(
    const double* __restrict__ Mv, int* __restrict__ sel)
{
    __shared__ double vals[LL];
    __shared__ double rv[256];
    __shared__ int ri[256];
    int bh = blockIdx.x, tid = threadIdx.x;
    for (int j = tid; j < LL; j += 256) vals[j] = Mv[(size_t)bh * LL + j];
    __syncthreads();
    for (int u = 0; u < UU; ++u) {
        double bv = -1e301; int bi = LL;
        for (int j = tid; j < LL; j += 256) {
            double v = vals[j];
            if (v > bv) { bv = v; bi = j; }
        }
        rv[tid] = bv; ri[tid] = bi;
        __syncthreads();
        for (int s = 128; s > 0; s >>= 1) {
            if (tid < s) {
                double ov = rv[tid + s]; int oi = ri[tid + s];
                if (ov > rv[tid] || (ov == rv[tid] && oi < ri[tid])) {
                    rv[tid] = ov; ri[tid] = oi;
                }
            }
            __syncthreads();
        }
        if (tid == 0) { sel[bh * UU + u] = ri[0]; vals[ri[0]] = -1e302; }
        __syncthreads();
    }
}

// ---- K5: fp32 vectorized scores + causal + softmax + probs + PV + attn ----
// Reads precomputed Qf/Kf/Vf; one block per (u, bh). OUTPUTS FLOAT32.
__global__ __launch_bounds__(256) void attn_out2_r8(
    const float* __restrict__ Qf, const float* __restrict__ Kf,
    const float* __restrict__ Vf, const int* __restrict__ sel,
    float* __restrict__ attnOut, float* __restrict__ probsOut)
{
    __shared__ float qs[DK];
    __shared__ float pl[LL];
    __shared__ float red[256];
    __shared__ float4 sred4[16 * 16];
    int u = blockIdx.x, bh = blockIdx.y, tid = threadIdx.x;
    int b = bh >> 4, h = bh & 15;
    int qpos = sel[bh * UU + u];

    if (tid < DK) qs[tid] = Qf[((size_t)bh * LL + qpos) * DK + tid];
    __syncthreads();

    // q row into registers (broadcast LDS reads)
    float4 qv[16];
#pragma unroll
    for (int i = 0; i < 16; ++i) qv[i] = *(const float4*)(&qs[i * 4]);

    // ---- scores: 8 keys per thread, float4 K reads ----
    const float* kb = Kf + (size_t)bh * LL * DK;
    float sloc[8];
    float lmax = -INFINITY;
#pragma unroll
    for (int c = 0; c < 8; ++c) {
        int l = c * 256 + tid;
        const float4* kr = (const float4*)(kb + (size_t)l * DK);
        float s = 0.f;
#pragma unroll
        for (int i = 0; i < 16; ++i) {
            const float4 kvv = kr[i];
            s = fmaf(qv[i].x, kvv.x, s);
            s = fmaf(qv[i].y, kvv.y, s);
            s = fmaf(qv[i].z, kvv.z, s);
            s = fmaf(qv[i].w, kvv.w, s);
        }
        s *= 0.125f;
        if (l > qpos) s -= 1e9f;
        sloc[c] = s;
        lmax = fmaxf(lmax, s);
    }
    red[tid] = lmax; __syncthreads();
    for (int s2 = 128; s2 > 0; s2 >>= 1) {
        if (tid < s2) red[tid] = fmaxf(red[tid], red[tid + s2]);
        __syncthreads();
    }
    float mval = red[0];
    __syncthreads();
    float lsum = 0.f;
#pragma unroll
    for (int c = 0; c < 8; ++c) { sloc[c] = expf(sloc[c] - mval); lsum += sloc[c]; }
    red[tid] = lsum; __syncthreads();
    for (int s2 = 128; s2 > 0; s2 >>= 1) {
        if (tid < s2) red[tid] += red[tid + s2];
        __syncthreads();
    }
    float inv = 1.0f / red[0];
    size_t rowo = ((size_t)bh * UU + u) * LL;
#pragma unroll
    for (int c = 0; c < 8; ++c) {
        int l = c * 256 + tid;
        float p = sloc[c] * inv;
        pl[l] = p;
        probsOut[rowo + l] = p;           // fp32 store
    }
    __syncthreads();

    // ---- PV: 16 l-segments x 16 dk-quads, float4 V loads ----
    int tx = tid & 15, g = tid >> 4;
    int dk4 = tx * 4;
    const float* vb = Vf + (size_t)bh * LL * DK;
    float ax = 0.f, ay = 0.f, az = 0.f, aw = 0.f;
#pragma unroll 4
    for (int l = g * 128; l < g * 128 + 128; ++l) {
        float p = pl[l];
        const float4 v = *(const float4*)(vb + (size_t)l * DK + dk4);
        ax = fmaf(p, v.x, ax);
        ay = fmaf(p, v.y, ay);
        az = fmaf(p, v.z, az);
        aw = fmaf(p, v.w, aw);
    }
    sred4[g * 16 + tx] = make_float4(ax, ay, az, aw);
    __syncthreads();
    if (tid < 64) {
        float s = 0.f;
#pragma unroll
        for (int g2 = 0; g2 < 16; ++g2) {
            const float* sp = (const float*)&sred4[g2 * 16 + (tid >> 2)];
            s += sp[tid & 3];
        }
        attnOut[((size_t)b * UU + u) * DD + h * DK + tid] = s;   // fp32 store
    }
}

extern "C" void kernel_launch(void* const* d_in, const int* in_sizes, int n_in,
                              void* d_out, int out_size, void* d_ws, size_t ws_size,
                              hipStream_t stream) {
    (void)in_sizes; (void)n_in; (void)out_size; (void)ws_size;
    const void* query = d_in[0];
    const void* key   = d_in[1];
    const void* value = d_in[2];
    const void* Wq    = d_in[3];
    const void* bq    = d_in[4];
    const void* Wk    = d_in[5];
    const void* bk    = d_in[6];
    const void* Wv    = d_in[7];
    const void* bv    = d_in[8];

    char* w = (char*)d_ws;
    const size_t NE = (size_t)BB * HH * LL * DK;   // 4,194,304
    float* Kf  = (float*)w;  w += NE * 4;
    float* Vf  = (float*)w;  w += NE * 4;
    float* Qf  = (float*)w;  w += NE * 4;
    double* Mv = (double*)w; w += (size_t)BH * LL * 8;
    double* Kbar = (double*)w; w += (size_t)BH * DK * 8;
    int* sel   = (int*)w;    w += (size_t)BH * UU * 4;
    int* flag  = (int*)w;    w += 64;

    float* attnOut  = (float*)d_out;                       // FP32 outputs
    float* probsOut = attnOut + (size_t)BB * UU * DD;

    dim3 blk(256);
    detect_dtype_r8<<<1, blk, 0, stream>>>((const u16*)query, flag);
    proj_v_r8<<<dim3(64, 16), blk, 0, stream>>>(key, Wk, bk, Kf, flag);
    proj_v_r8<<<dim3(64, 16), blk, 0, stream>>>(value, Wv, bv, Vf, flag);
    proj_v_r8<<<dim3(64, 16), blk, 0, stream>>>(query, Wq, bq, Qf, flag);
    kbar_r8<<<32, blk, 0, stream>>>(Kf, Kbar);
    stats_max_r8<<<dim3(LL / QT, 32), blk, 0, stream>>>(Qf, Kf, Kbar, Mv);
    topk_exact_r8<<<32, blk, 0, stream>>>(Mv, sel);
    attn_out2_r8<<<dim3(UU, 32), blk, 0, stream>>>(Qf, Kf, Vf, sel, attnOut, probsOut);
}

// Round 4
// 1105.884 us; speedup vs baseline: 3.5890x; 1.2708x over previous
//
#include <hip/hip_runtime.h>
#include <hip/hip_bf16.h>

#define BB 2
#define LL 2048
#define DD 1024
#define HH 16
#define DK 64
#define UU 40
#define BH (BB*HH)

typedef unsigned short u16;
typedef float f32x4 __attribute__((ext_vector_type(4)));
typedef short s16x8 __attribute__((ext_vector_type(8)));

__device__ inline float b2f_r8(u16 x) {
    union { unsigned short u; __hip_bfloat16 b; } c; c.u = x;
    return __bfloat162float(c.b);
}
// dual-dtype element load (fp32 or bf16 input), wave-uniform isF
__device__ inline float ldf_r8(const void* p, size_t i, int isF) {
    return isF ? ((const float*)p)[i] : b2f_r8(((const u16*)p)[i]);
}
// dual-dtype 4-consecutive-element load
__device__ inline f32x4 ld4_r8(const void* p, size_t i, int isF) {
    if (isF) return *(const f32x4*)((const float*)p + i);
    ushort4 v = *(const ushort4*)((const u16*)p + i);
    f32x4 r;
    r[0] = b2f_r8(v.x); r[1] = b2f_r8(v.y); r[2] = b2f_r8(v.z); r[3] = b2f_r8(v.w);
    return r;
}
// fp32 -> bf16 hi/lo split (RN both; captures 16 high mantissa bits)
__device__ inline void cvt2_r8(float x, u16& h, u16& l) {
    union { __hip_bfloat16 b; u16 u; } ch, cl;
    ch.b = __float2bfloat16(x);
    float hf = __bfloat162float(ch.b);
    cl.b = __float2bfloat16(x - hf);
    h = ch.u; l = cl.u;
}

// ---------------- K0: input dtype probe ----------------
__global__ __launch_bounds__(256) void detect_dtype_r8(const u16* __restrict__ q,
                                                       int* __restrict__ flag) {
    __shared__ float red[256];
    int tid = threadIdx.x;
    float mx = 0.f;
    for (int i = tid; i < 4096; i += 256) {
        float v = fabsf(b2f_r8(q[i]));
        if (!(v < 1e30f)) v = 1e38f;
        mx = fmaxf(mx, v);
    }
    red[tid] = mx; __syncthreads();
    for (int s = 128; s > 0; s >>= 1) {
        if (tid < s) red[tid] = fmaxf(red[tid], red[tid + s]);
        __syncthreads();
    }
    if (tid == 0) *flag = (red[0] > 1e20f) ? 1 : 0;
}

// ---- K1: fp32 projection for Q,K — BIT-IDENTICAL fmaf order to the proven
// proj_v_r8 (selection-critical), but with float4 staging + b128 LDS reads.
// LDS row stride 68 floats: 16 b128 rows land on 16 distinct 16B slots mod 32
// banks (17 coprime 32) => conflict-free.
#define LDF 68
__global__ __launch_bounds__(256) void proj_f4_r9(
    const void* __restrict__ X, const void* __restrict__ W,
    const void* __restrict__ bias, float* __restrict__ out,
    const int* __restrict__ flag)
{
    __shared__ float sx[64 * LDF];
    __shared__ float sw[64 * LDF];
    int tid = threadIdx.x;
    int n0 = blockIdx.x * 64, f0 = blockIdx.y * 64;
    int isF = *flag;
    int ty = tid >> 4, tx = tid & 15;
    float acc[4][4] = {};
    for (int kc = 0; kc < 16; ++kc) {
        __syncthreads();
        for (int i = tid; i < 2048; i += 256) {
            int isB = i >> 10, j = i & 1023;
            int r = j >> 4, c4 = j & 15;
            f32x4 v = ld4_r8(isB ? W : X,
                             (size_t)((isB ? f0 : n0) + r) * DD + kc * 64 + c4 * 4, isF);
            float* dst = isB ? sw : sx;
            *(f32x4*)&dst[r * LDF + c4 * 4] = v;
        }
        __syncthreads();
        for (int c4 = 0; c4 < 16; ++c4) {
            f32x4 xa[4], wb[4];
#pragma unroll
            for (int a = 0; a < 4; ++a) xa[a] = *(const f32x4*)&sx[(ty * 4 + a) * LDF + c4 * 4];
#pragma unroll
            for (int q = 0; q < 4; ++q) wb[q] = *(const f32x4*)&sw[(tx * 4 + q) * LDF + c4 * 4];
#pragma unroll
            for (int cc = 0; cc < 4; ++cc)
#pragma unroll
                for (int a = 0; a < 4; ++a)
#pragma unroll
                    for (int q = 0; q < 4; ++q)
                        acc[a][q] = fmaf(xa[a][cc], wb[q][cc], acc[a][q]);
        }
    }
#pragma unroll
    for (int a = 0; a < 4; ++a) {
        int n = n0 + ty * 4 + a, b = n >> 11, l = n & (LL - 1);
#pragma unroll
        for (int q = 0; q < 4; ++q) {
            int f = f0 + tx * 4 + q, h = f >> 6, dk = f & 63;
            out[((size_t)(b * HH + h) * LL + l) * DK + dk] = acc[a][q] + ldf_r8(bias, (size_t)f, isF);
        }
    }
}

// ---- K1b: V projection via bf16x3 MFMA (hihi + lohi + hilo), fp32 accum. ----
// V feeds ONLY the attn output (threshold >= 2.4e-2 in bf16 mode); its ~1e-6
// error cannot affect selection. 128x128 tile, 4 waves 2x2, 4x4 frags of
// mfma_f32_16x16x32_bf16. LDS row stride 72 bf16 (=144B, 16B-aligned rows).
#define LDK 72
__global__ __launch_bounds__(256) void proj_mfma_v_r9(
    const void* __restrict__ X, const void* __restrict__ W,
    const void* __restrict__ bias, float* __restrict__ out,
    const int* __restrict__ flag)
{
    __shared__ u16 Ahi[128 * LDK];
    __shared__ u16 Alo[128 * LDK];
    __shared__ u16 Bhi[128 * LDK];
    __shared__ u16 Blo[128 * LDK];
    int tid = threadIdx.x;
    int n0 = blockIdx.x * 128, f0 = blockIdx.y * 128;
    int isF = *flag;
    int lane = tid & 63, w = tid >> 6, wr = w >> 1, wc = w & 1;

    f32x4 acc[4][4] = {};

    for (int kc = 0; kc < 16; ++kc) {
        __syncthreads();
#pragma unroll
        for (int it = 0; it < 16; ++it) {
            int i = it * 256 + tid;
            int isB = i >> 11, j = i & 2047;
            int row = j >> 4, c = (j & 15) << 2;
            f32x4 v = ld4_r8(isB ? W : X, (size_t)((isB ? f0 : n0) + row) * DD + kc * 64 + c, isF);
            u16* hh = isB ? Bhi : Ahi;
            u16* ll = isB ? Blo : Alo;
            ushort4 h4, l4;
            cvt2_r8(v[0], h4.x, l4.x);
            cvt2_r8(v[1], h4.y, l4.y);
            cvt2_r8(v[2], h4.z, l4.z);
            cvt2_r8(v[3], h4.w, l4.w);
            *(ushort4*)&hh[row * LDK + c] = h4;
            *(ushort4*)&ll[row * LDK + c] = l4;
        }
        __syncthreads();
#pragma unroll
        for (int kk = 0; kk < 2; ++kk) {
            int koff = kk * 32 + (lane >> 4) * 8;
            s16x8 ah[4], al[4];
#pragma unroll
            for (int mi = 0; mi < 4; ++mi) {
                int r = wr * 64 + mi * 16 + (lane & 15);
                ah[mi] = *(const s16x8*)&Ahi[r * LDK + koff];
                al[mi] = *(const s16x8*)&Alo[r * LDK + koff];
            }
#pragma unroll
            for (int ni = 0; ni < 4; ++ni) {
                int r = wc * 64 + ni * 16 + (lane & 15);
                s16x8 bh = *(const s16x8*)&Bhi[r * LDK + koff];
                s16x8 bl = *(const s16x8*)&Blo[r * LDK + koff];
#pragma unroll
                for (int mi = 0; mi < 4; ++mi) {
                    acc[mi][ni] = __builtin_amdgcn_mfma_f32_16x16x32_bf16(ah[mi], bh, acc[mi][ni], 0, 0, 0);
                    acc[mi][ni] = __builtin_amdgcn_mfma_f32_16x16x32_bf16(al[mi], bh, acc[mi][ni], 0, 0, 0);
                    acc[mi][ni] = __builtin_amdgcn_mfma_f32_16x16x32_bf16(ah[mi], bl, acc[mi][ni], 0, 0, 0);
                }
            }
        }
    }

    // epilogue: D frag (col = lane&15 -> f, row = (lane>>4)*4 + j -> n)
#pragma unroll
    for (int ni = 0; ni < 4; ++ni) {
        int f = f0 + wc * 64 + ni * 16 + (lane & 15);
        float bb = ldf_r8(bias, (size_t)f, isF);
        int h = f >> 6, dk = f & 63;
#pragma unroll
        for (int mi = 0; mi < 4; ++mi) {
            int nbase = n0 + wr * 64 + mi * 16 + ((lane >> 4) << 2);
#pragma unroll
            for (int j2 = 0; j2 < 4; ++j2) {
                int n = nbase + j2, b = n >> 11, l = n & (LL - 1);
                out[((size_t)(b * HH + h) * LL + l) * DK + dk] = acc[mi][ni][j2] + bb;
            }
        }
    }
}

// ---------------- K2b: Kbar[bh][d] = mean over l of K (fp64 accumulate) ----------------
__global__ __launch_bounds__(256) void kbar_r8(
    const float* __restrict__ Kf, double* __restrict__ Kbar)
{
    __shared__ double red[256];
    int bh = blockIdx.x, tid = threadIdx.x;
    int d = tid & 63, seg = tid >> 6;
    double s = 0;
    for (int l = seg * 512; l < seg * 512 + 512; ++l)
        s += (double)Kf[((size_t)bh * LL + l) * DK + d];
    red[tid] = s; __syncthreads();
    if (tid < 128) red[tid] += red[tid + 128];
    __syncthreads();
    if (tid < 64) Kbar[(size_t)bh * DK + d] = (red[tid] + red[tid + 64]) * (1.0 / (double)LL);
}

// ---- K3: rowmax(Q K^T) via fp32 register-tiled GEMM; M = rowmax - Q.Kbar ----
#define QT 128
#define KT 128
#define PAD 132
__global__ __launch_bounds__(256) void stats_max_r8(
    const float* __restrict__ Qf, const float* __restrict__ Kf,
    const double* __restrict__ Kbar, double* __restrict__ Mv)
{
    __shared__ float sQ[64 * PAD];
    __shared__ float sK[64 * PAD];
    __shared__ float rowmax[QT];
    int tid = threadIdx.x;
    int q0 = blockIdx.x * QT, bh = blockIdx.y;
    int tx = tid & 15, ty = tid >> 4;

    {
        const float* src = Qf + ((size_t)bh * LL + q0) * DK;
#pragma unroll
        for (int j = 0; j < 8; ++j) {
            int row = (tid >> 4) + j * 16;
            int d0 = (tid & 15) * 4;
            const float4 v = *(const float4*)(src + (size_t)row * DK + d0);
            sQ[(d0 + 0) * PAD + row] = v.x;
            sQ[(d0 + 1) * PAD + row] = v.y;
            sQ[(d0 + 2) * PAD + row] = v.z;
            sQ[(d0 + 3) * PAD + row] = v.w;
        }
    }
    float rmax8[8];
#pragma unroll
    for (int a = 0; a < 8; ++a) rmax8[a] = -INFINITY;

    const float* kbase = Kf + (size_t)bh * LL * DK;
    for (int kc = 0; kc < LL / KT; ++kc) {
        __syncthreads();
#pragma unroll
        for (int j = 0; j < 8; ++j) {
            int row = (tid >> 4) + j * 16;
            int d0 = (tid & 15) * 4;
            const float4 v = *(const float4*)(kbase + (size_t)(kc * KT + row) * DK + d0);
            sK[(d0 + 0) * PAD + row] = v.x;
            sK[(d0 + 1) * PAD + row] = v.y;
            sK[(d0 + 2) * PAD + row] = v.z;
            sK[(d0 + 3) * PAD + row] = v.w;
        }
        __syncthreads();
        float acc[8][8];
#pragma unroll
        for (int a = 0; a < 8; ++a)
#pragma unroll
            for (int c = 0; c < 8; ++c) acc[a][c] = 0.f;
        for (int d = 0; d < 64; ++d) {
            const float4 qa = *(const float4*)(&sQ[d * PAD + ty * 4]);
            const float4 qb = *(const float4*)(&sQ[d * PAD + 64 + ty * 4]);
            const float4 ka = *(const float4*)(&sK[d * PAD + tx * 4]);
            const float4 kb = *(const float4*)(&sK[d * PAD + 64 + tx * 4]);
            float qv[8] = {qa.x, qa.y, qa.z, qa.w, qb.x, qb.y, qb.z, qb.w};
            float kv[8] = {ka.x, ka.y, ka.z, ka.w, kb.x, kb.y, kb.z, kb.w};
#pragma unroll
            for (int a = 0; a < 8; ++a)
#pragma unroll
                for (int c = 0; c < 8; ++c)
                    acc[a][c] = fmaf(qv[a], kv[c], acc[a][c]);
        }
#pragma unroll
        for (int a = 0; a < 8; ++a)
#pragma unroll
            for (int c = 0; c < 8; ++c) rmax8[a] = fmaxf(rmax8[a], acc[a][c]);
    }
#pragma unroll
    for (int a = 0; a < 8; ++a) {
        float v = rmax8[a];
        v = fmaxf(v, __shfl_xor(v, 1));
        v = fmaxf(v, __shfl_xor(v, 2));
        v = fmaxf(v, __shfl_xor(v, 4));
        v = fmaxf(v, __shfl_xor(v, 8));
        rmax8[a] = v;
    }
    if (tx == 0) {
#pragma unroll
        for (int a = 0; a < 8; ++a) {
            int row = ty * 4 + (a & 3) + (a >> 2) * 64;
            rowmax[row] = rmax8[a];
        }
    }
    __syncthreads();
    if (tid < QT) {
        const double* kb = Kbar + (size_t)bh * DK;
        double s = 0;
#pragma unroll
        for (int d = 0; d < 64; ++d) s += (double)sQ[d * PAD + tid] * kb[d];
        Mv[(size_t)bh * LL + q0 + tid] = (double)rowmax[tid] - s;
    }
}

// ------- K4: exact top-40 per (b,h), DESCENDING (jax.lax.top_k), tie->low -------
__global__ __launch_bounds__(256) void topk_exact_r8(
    const double* __restrict__ Mv, int* __restrict__ sel)
{
    __shared__ double vals[LL];
    __shared__ double rv[256];
    __shared__ int ri[256];
    int bh = blockIdx.x, tid = threadIdx.x;
    for (int j = tid; j < LL; j += 256) vals[j] = Mv[(size_t)bh * LL + j];
    __syncthreads();
    for (int u = 0; u < UU; ++u) {
        double bv = -1e301; int bi = LL;
        for (int j = tid; j < LL; j += 256) {
            double v = vals[j];
            if (v > bv) { bv = v; bi = j; }
        }
        rv[tid] = bv; ri[tid] = bi;
        __syncthreads();
        for (int s = 128; s > 0; s >>= 1) {
            if (tid < s) {
                double ov = rv[tid + s]; int oi = ri[tid + s];
                if (ov > rv[tid] || (ov == rv[tid] && oi < ri[tid])) {
                    rv[tid] = ov; ri[tid] = oi;
                }
            }
            __syncthreads();
        }
        if (tid == 0) { sel[bh * UU + u] = ri[0]; vals[ri[0]] = -1e302; }
        __syncthreads();
    }
}

// ---- K5: fp32 vectorized scores + causal + softmax + probs + PV + attn ----
__global__ __launch_bounds__(256) void attn_out2_r8(
    const float* __restrict__ Qf, const float* __restrict__ Kf,
    const float* __restrict__ Vf, const int* __restrict__ sel,
    float* __restrict__ attnOut, float* __restrict__ probsOut)
{
    __shared__ float qs[DK];
    __shared__ float pl[LL];
    __shared__ float red[256];
    __shared__ float4 sred4[16 * 16];
    int u = blockIdx.x, bh = blockIdx.y, tid = threadIdx.x;
    int b = bh >> 4, h = bh & 15;
    int qpos = sel[bh * UU + u];

    if (tid < DK) qs[tid] = Qf[((size_t)bh * LL + qpos) * DK + tid];
    __syncthreads();

    float4 qv[16];
#pragma unroll
    for (int i = 0; i < 16; ++i) qv[i] = *(const float4*)(&qs[i * 4]);

    const float* kb = Kf + (size_t)bh * LL * DK;
    float sloc[8];
    float lmax = -INFINITY;
#pragma unroll
    for (int c = 0; c < 8; ++c) {
        int l = c * 256 + tid;
        const float4* kr = (const float4*)(kb + (size_t)l * DK);
        float s = 0.f;
#pragma unroll
        for (int i = 0; i < 16; ++i) {
            const float4 kvv = kr[i];
            s = fmaf(qv[i].x, kvv.x, s);
            s = fmaf(qv[i].y, kvv.y, s);
            s = fmaf(qv[i].z, kvv.z, s);
            s = fmaf(qv[i].w, kvv.w, s);
        }
        s *= 0.125f;
        if (l > qpos) s -= 1e9f;
        sloc[c] = s;
        lmax = fmaxf(lmax, s);
    }
    red[tid] = lmax; __syncthreads();
    for (int s2 = 128; s2 > 0; s2 >>= 1) {
        if (tid < s2) red[tid] = fmaxf(red[tid], red[tid + s2]);
        __syncthreads();
    }
    float mval = red[0];
    __syncthreads();
    float lsum = 0.f;
#pragma unroll
    for (int c = 0; c < 8; ++c) { sloc[c] = expf(sloc[c] - mval); lsum += sloc[c]; }
    red[tid] = lsum; __syncthreads();
    for (int s2 = 128; s2 > 0; s2 >>= 1) {
        if (tid < s2) red[tid] += red[tid + s2];
        __syncthreads();
    }
    float inv = 1.0f / red[0];
    size_t rowo = ((size_t)bh * UU + u) * LL;
#pragma unroll
    for (int c = 0; c < 8; ++c) {
        int l = c * 256 + tid;
        float p = sloc[c] * inv;
        pl[l] = p;
        probsOut[rowo + l] = p;
    }
    __syncthreads();

    int tx = tid & 15, g = tid >> 4;
    int dk4 = tx * 4;
    const float* vb = Vf + (size_t)bh * LL * DK;
    float ax = 0.f, ay = 0.f, az = 0.f, aw = 0.f;
#pragma unroll 4
    for (int l = g * 128; l < g * 128 + 128; ++l) {
        float p = pl[l];
        const float4 v = *(const float4*)(vb + (size_t)l * DK + dk4);
        ax = fmaf(p, v.x, ax);
        ay = fmaf(p, v.y, ay);
        az = fmaf(p, v.z, az);
        aw = fmaf(p, v.w, aw);
    }
    sred4[g * 16 + tx] = make_float4(ax, ay, az, aw);
    __syncthreads();
    if (tid < 64) {
        float s = 0.f;
#pragma unroll
        for (int g2 = 0; g2 < 16; ++g2) {
            const float* sp = (const float*)&sred4[g2 * 16 + (tid >> 2)];
            s += sp[tid & 3];
        }
        attnOut[((size_t)b * UU + u) * DD + h * DK + tid] = s;
    }
}

extern "C" void kernel_launch(void* const* d_in, const int* in_sizes, int n_in,
                              void* d_out, int out_size, void* d_ws, size_t ws_size,
                              hipStream_t stream) {
    (void)in_sizes; (void)n_in; (void)out_size; (void)ws_size;
    const void* query = d_in[0];
    const void* key   = d_in[1];
    const void* value = d_in[2];
    const void* Wq    = d_in[3];
    const void* bq    = d_in[4];
    const void* Wk    = d_in[5];
    const void* bk    = d_in[6];
    const void* Wv    = d_in[7];
    const void* bv    = d_in[8];

    char* w = (char*)d_ws;
    const size_t NE = (size_t)BB * HH * LL * DK;   // 4,194,304
    float* Kf  = (float*)w;  w += NE * 4;
    float* Vf  = (float*)w;  w += NE * 4;
    float* Qf  = (float*)w;  w += NE * 4;
    double* Mv = (double*)w; w += (size_t)BH * LL * 8;
    double* Kbar = (double*)w; w += (size_t)BH * DK * 8;
    int* sel   = (int*)w;    w += (size_t)BH * UU * 4;
    int* flag  = (int*)w;    w += 64;

    float* attnOut  = (float*)d_out;                       // FP32 outputs
    float* probsOut = attnOut + (size_t)BB * UU * DD;

    dim3 blk(256);
    detect_dtype_r8<<<1, blk, 0, stream>>>((const u16*)query, flag);
    proj_f4_r9<<<dim3(64, 16), blk, 0, stream>>>(key, Wk, bk, Kf, flag);
    proj_f4_r9<<<dim3(64, 16), blk, 0, stream>>>(query, Wq, bq, Qf, flag);
    proj_mfma_v_r9<<<dim3(32, 8), blk, 0, stream>>>(value, Wv, bv, Vf, flag);
    kbar_r8<<<32, blk, 0, stream>>>(Kf, Kbar);
    stats_max_r8<<<dim3(LL / QT, 32), blk, 0, stream>>>(Qf, Kf, Kbar, Mv);
    topk_exact_r8<<<32, blk, 0, stream>>>(Mv, sel);
    attn_out2_r8<<<dim3(UU, 32), blk, 0, stream>>>(Qf, Kf, Vf, sel, attnOut, probsOut);
}

// Round 5
// 1090.532 us; speedup vs baseline: 3.6395x; 1.0141x over previous
//
#include <hip/hip_runtime.h>
#include <hip/hip_bf16.h>

#define BB 2
#define LL 2048
#define DD 1024
#define HH 16
#define DK 64
#define UU 40
#define BH (BB*HH)

typedef unsigned short u16;
typedef float f32x4 __attribute__((ext_vector_type(4)));
typedef short s16x8 __attribute__((ext_vector_type(8)));

__device__ inline float b2f_r8(u16 x) {
    union { unsigned short u; __hip_bfloat16 b; } c; c.u = x;
    return __bfloat162float(c.b);
}
// dual-dtype element load (fp32 or bf16 input), wave-uniform isF
__device__ inline float ldf_r8(const void* p, size_t i, int isF) {
    return isF ? ((const float*)p)[i] : b2f_r8(((const u16*)p)[i]);
}
// dual-dtype 4-consecutive-element load
__device__ inline f32x4 ld4_r8(const void* p, size_t i, int isF) {
    if (isF) return *(const f32x4*)((const float*)p + i);
    ushort4 v = *(const ushort4*)((const u16*)p + i);
    f32x4 r;
    r[0] = b2f_r8(v.x); r[1] = b2f_r8(v.y); r[2] = b2f_r8(v.z); r[3] = b2f_r8(v.w);
    return r;
}
// fp32 -> bf16 hi/lo split (RN both; captures 16 high mantissa bits)
__device__ inline void cvt2_r8(float x, u16& h, u16& l) {
    union { __hip_bfloat16 b; u16 u; } ch, cl;
    ch.b = __float2bfloat16(x);
    float hf = __bfloat162float(ch.b);
    cl.b = __float2bfloat16(x - hf);
    h = ch.u; l = cl.u;
}

// ---------------- K0: input dtype probe ----------------
__global__ __launch_bounds__(256) void detect_dtype_r8(const u16* __restrict__ q,
                                                       int* __restrict__ flag) {
    __shared__ float red[256];
    int tid = threadIdx.x;
    float mx = 0.f;
    for (int i = tid; i < 4096; i += 256) {
        float v = fabsf(b2f_r8(q[i]));
        if (!(v < 1e30f)) v = 1e38f;
        mx = fmaxf(mx, v);
    }
    red[tid] = mx; __syncthreads();
    for (int s = 128; s > 0; s >>= 1) {
        if (tid < s) red[tid] = fmaxf(red[tid], red[tid + s]);
        __syncthreads();
    }
    if (tid == 0) *flag = (red[0] > 1e20f) ? 1 : 0;
}

// ---- K1: fp32 projection for K (z=0) and Q (z=1), fused in one launch. ----
// BIT-IDENTICAL per-output fmaf chain (c ascending) to the proven kernel.
// Thread->output remap (row = a*16+ty, col = q*16+tx): wb b128 reads now hit
// slot (tx+c4) mod 8 -> all 8 bank-quads, 2-way (free), vs 8-way before.
#define LDF 68
__global__ __launch_bounds__(256) void proj_f4_r10(
    const void* __restrict__ key, const void* __restrict__ query,
    const void* __restrict__ Wk, const void* __restrict__ Wq,
    const void* __restrict__ bk, const void* __restrict__ bq,
    float* __restrict__ Kf, float* __restrict__ Qf,
    const int* __restrict__ flag)
{
    __shared__ float sx[64 * LDF];
    __shared__ float sw[64 * LDF];
    int tid = threadIdx.x;
    int n0 = blockIdx.x * 64, f0 = blockIdx.y * 64, z = blockIdx.z;
    const void* X    = z ? query : key;
    const void* W    = z ? Wq    : Wk;
    const void* bias = z ? bq    : bk;
    float* out       = z ? Qf    : Kf;
    int isF = *flag;
    int ty = tid >> 4, tx = tid & 15;
    float acc[4][4] = {};
    for (int kc = 0; kc < 16; ++kc) {
        __syncthreads();
        for (int i = tid; i < 2048; i += 256) {
            int isB = i >> 10, j = i & 1023;
            int r = j >> 4, c4 = j & 15;
            f32x4 v = ld4_r8(isB ? W : X,
                             (size_t)((isB ? f0 : n0) + r) * DD + kc * 64 + c4 * 4, isF);
            float* dst = isB ? sw : sx;
            *(f32x4*)&dst[r * LDF + c4 * 4] = v;
        }
        __syncthreads();
        for (int c4 = 0; c4 < 16; ++c4) {
            f32x4 xa[4], wb[4];
#pragma unroll
            for (int a = 0; a < 4; ++a) xa[a] = *(const f32x4*)&sx[(a * 16 + ty) * LDF + c4 * 4];
#pragma unroll
            for (int q = 0; q < 4; ++q) wb[q] = *(const f32x4*)&sw[(q * 16 + tx) * LDF + c4 * 4];
#pragma unroll
            for (int cc = 0; cc < 4; ++cc)
#pragma unroll
                for (int a = 0; a < 4; ++a)
#pragma unroll
                    for (int q = 0; q < 4; ++q)
                        acc[a][q] = fmaf(xa[a][cc], wb[q][cc], acc[a][q]);
        }
    }
#pragma unroll
    for (int a = 0; a < 4; ++a) {
        int n = n0 + a * 16 + ty, b = n >> 11, l = n & (LL - 1);
#pragma unroll
        for (int q = 0; q < 4; ++q) {
            int f = f0 + q * 16 + tx, h = f >> 6, dk = f & 63;
            out[((size_t)(b * HH + h) * LL + l) * DK + dk] = acc[a][q] + ldf_r8(bias, (size_t)f, isF);
        }
    }
}

// ---- K1b: V projection via bf16x3 MFMA (hihi + lohi + hilo), fp32 accum. ----
// (unchanged from R4 — proven) V feeds ONLY the attn output.
#define LDK 72
__global__ __launch_bounds__(256) void proj_mfma_v_r9(
    const void* __restrict__ X, const void* __restrict__ W,
    const void* __restrict__ bias, float* __restrict__ out,
    const int* __restrict__ flag)
{
    __shared__ u16 Ahi[128 * LDK];
    __shared__ u16 Alo[128 * LDK];
    __shared__ u16 Bhi[128 * LDK];
    __shared__ u16 Blo[128 * LDK];
    int tid = threadIdx.x;
    int n0 = blockIdx.x * 128, f0 = blockIdx.y * 128;
    int isF = *flag;
    int lane = tid & 63, w = tid >> 6, wr = w >> 1, wc = w & 1;

    f32x4 acc[4][4] = {};

    for (int kc = 0; kc < 16; ++kc) {
        __syncthreads();
#pragma unroll
        for (int it = 0; it < 16; ++it) {
            int i = it * 256 + tid;
            int isB = i >> 11, j = i & 2047;
            int row = j >> 4, c = (j & 15) << 2;
            f32x4 v = ld4_r8(isB ? W : X, (size_t)((isB ? f0 : n0) + row) * DD + kc * 64 + c, isF);
            u16* hh = isB ? Bhi : Ahi;
            u16* ll = isB ? Blo : Alo;
            ushort4 h4, l4;
            cvt2_r8(v[0], h4.x, l4.x);
            cvt2_r8(v[1], h4.y, l4.y);
            cvt2_r8(v[2], h4.z, l4.z);
            cvt2_r8(v[3], h4.w, l4.w);
            *(ushort4*)&hh[row * LDK + c] = h4;
            *(ushort4*)&ll[row * LDK + c] = l4;
        }
        __syncthreads();
#pragma unroll
        for (int kk = 0; kk < 2; ++kk) {
            int koff = kk * 32 + (lane >> 4) * 8;
            s16x8 ah[4], al[4];
#pragma unroll
            for (int mi = 0; mi < 4; ++mi) {
                int r = wr * 64 + mi * 16 + (lane & 15);
                ah[mi] = *(const s16x8*)&Ahi[r * LDK + koff];
                al[mi] = *(const s16x8*)&Alo[r * LDK + koff];
            }
#pragma unroll
            for (int ni = 0; ni < 4; ++ni) {
                int r = wc * 64 + ni * 16 + (lane & 15);
                s16x8 bh = *(const s16x8*)&Bhi[r * LDK + koff];
                s16x8 bl = *(const s16x8*)&Blo[r * LDK + koff];
#pragma unroll
                for (int mi = 0; mi < 4; ++mi) {
                    acc[mi][ni] = __builtin_amdgcn_mfma_f32_16x16x32_bf16(ah[mi], bh, acc[mi][ni], 0, 0, 0);
                    acc[mi][ni] = __builtin_amdgcn_mfma_f32_16x16x32_bf16(al[mi], bh, acc[mi][ni], 0, 0, 0);
                    acc[mi][ni] = __builtin_amdgcn_mfma_f32_16x16x32_bf16(ah[mi], bl, acc[mi][ni], 0, 0, 0);
                }
            }
        }
    }

#pragma unroll
    for (int ni = 0; ni < 4; ++ni) {
        int f = f0 + wc * 64 + ni * 16 + (lane & 15);
        float bb = ldf_r8(bias, (size_t)f, isF);
        int h = f >> 6, dk = f & 63;
#pragma unroll
        for (int mi = 0; mi < 4; ++mi) {
            int nbase = n0 + wr * 64 + mi * 16 + ((lane >> 4) << 2);
#pragma unroll
            for (int j2 = 0; j2 < 4; ++j2) {
                int n = nbase + j2, b = n >> 11, l = n & (LL - 1);
                out[((size_t)(b * HH + h) * LL + l) * DK + dk] = acc[mi][ni][j2] + bb;
            }
        }
    }
}

// ---------------- K2b: Kbar[bh][d] = mean over l of K (fp64 accumulate) ----------------
__global__ __launch_bounds__(256) void kbar_r8(
    const float* __restrict__ Kf, double* __restrict__ Kbar)
{
    __shared__ double red[256];
    int bh = blockIdx.x, tid = threadIdx.x;
    int d = tid & 63, seg = tid >> 6;
    double s = 0;
    for (int l = seg * 512; l < seg * 512 + 512; ++l)
        s += (double)Kf[((size_t)bh * LL + l) * DK + d];
    red[tid] = s; __syncthreads();
    if (tid < 128) red[tid] += red[tid + 128];
    __syncthreads();
    if (tid < 64) Kbar[(size_t)bh * DK + d] = (red[tid] + red[tid + 64]) * (1.0 / (double)LL);
}

// ---- K3: rowmax(Q K^T) fp32 GEMM; M = rowmax - Q.Kbar. Compute identical to
// R4 (bit-exact). Staging index remap: per write instruction 16 rows x 4 d
// coexist -> 32 banks (2-way, free) vs single-row 8-way before.
#define QT 128
#define KT 128
#define PAD 132
__global__ __launch_bounds__(256) void stats_max_r10(
    const float* __restrict__ Qf, const float* __restrict__ Kf,
    const double* __restrict__ Kbar, double* __restrict__ Mv)
{
    __shared__ float sQ[64 * PAD];
    __shared__ float sK[64 * PAD];
    __shared__ float rowmax[QT];
    int tid = threadIdx.x;
    int q0 = blockIdx.x * QT, bh = blockIdx.y;
    int tx = tid & 15, ty = tid >> 4;

    // stage Q tile transposed to d-major: sQ[d][row] (conflict-free writes)
    {
        const float* src = Qf + ((size_t)bh * LL + q0) * DK;
#pragma unroll
        for (int it = 0; it < 8; ++it) {
            int row = 64 * (it & 1) + (tid >> 2);
            int d4 = (tid & 3) | ((it >> 1) << 2);
            f32x4 v = *(const f32x4*)(src + (size_t)row * DK + d4 * 4);
#pragma unroll
            for (int cc = 0; cc < 4; ++cc)
                sQ[(4 * d4 + cc) * PAD + row] = v[cc];
        }
    }
    float rmax8[8];
#pragma unroll
    for (int a = 0; a < 8; ++a) rmax8[a] = -INFINITY;

    const float* kbase = Kf + (size_t)bh * LL * DK;
    for (int kc = 0; kc < LL / KT; ++kc) {
        __syncthreads();   // guard sK rewrite vs previous compute (and sQ at kc=0)
#pragma unroll
        for (int it = 0; it < 8; ++it) {
            int row = 64 * (it & 1) + (tid >> 2);
            int d4 = (tid & 3) | ((it >> 1) << 2);
            f32x4 v = *(const f32x4*)(kbase + (size_t)(kc * KT + row) * DK + d4 * 4);
#pragma unroll
            for (int cc = 0; cc < 4; ++cc)
                sK[(4 * d4 + cc) * PAD + row] = v[cc];
        }
        __syncthreads();
        float acc[8][8];
#pragma unroll
        for (int a = 0; a < 8; ++a)
#pragma unroll
            for (int c = 0; c < 8; ++c) acc[a][c] = 0.f;
        for (int d = 0; d < 64; ++d) {
            const f32x4 qa = *(const f32x4*)(&sQ[d * PAD + ty * 4]);
            const f32x4 qb = *(const f32x4*)(&sQ[d * PAD + 64 + ty * 4]);
            const f32x4 ka = *(const f32x4*)(&sK[d * PAD + tx * 4]);
            const f32x4 kb = *(const f32x4*)(&sK[d * PAD + 64 + tx * 4]);
            float qv[8] = {qa[0], qa[1], qa[2], qa[3], qb[0], qb[1], qb[2], qb[3]};
            float kv[8] = {ka[0], ka[1], ka[2], ka[3], kb[0], kb[1], kb[2], kb[3]};
#pragma unroll
            for (int a = 0; a < 8; ++a)
#pragma unroll
                for (int c = 0; c < 8; ++c)
                    acc[a][c] = fmaf(qv[a], kv[c], acc[a][c]);
        }
#pragma unroll
        for (int a = 0; a < 8; ++a)
#pragma unroll
            for (int c = 0; c < 8; ++c) rmax8[a] = fmaxf(rmax8[a], acc[a][c]);
    }
    // cross-tx max reduce within 16-lane groups (tx = lane&15)
#pragma unroll
    for (int a = 0; a < 8; ++a) {
        float v = rmax8[a];
        v = fmaxf(v, __shfl_xor(v, 1));
        v = fmaxf(v, __shfl_xor(v, 2));
        v = fmaxf(v, __shfl_xor(v, 4));
        v = fmaxf(v, __shfl_xor(v, 8));
        rmax8[a] = v;
    }
    if (tx == 0) {
#pragma unroll
        for (int a = 0; a < 8; ++a) {
            int row = ty * 4 + (a & 3) + (a >> 2) * 64;
            rowmax[row] = rmax8[a];
        }
    }
    __syncthreads();
    if (tid < QT) {
        const double* kb = Kbar + (size_t)bh * DK;
        double s = 0;
#pragma unroll
        for (int d = 0; d < 64; ++d) s += (double)sQ[d * PAD + tid] * kb[d];
        Mv[(size_t)bh * LL + q0 + tid] = (double)rowmax[tid] - s;
    }
}

// ------- K4: exact top-40 per (b,h), one wave per bh, register-resident. -------
// Same total order as before: max value, tie -> lower index (jax.lax.top_k).
__global__ __launch_bounds__(64) void topk_wave_r10(
    const double* __restrict__ Mv, int* __restrict__ sel)
{
    int bh = blockIdx.x, lane = threadIdx.x;
    double v[32];
#pragma unroll
    for (int t = 0; t < 32; ++t) v[t] = Mv[(size_t)bh * LL + t * 64 + lane];
    for (int u = 0; u < UU; ++u) {
        double bv = -1e301; int bi = LL;
#pragma unroll
        for (int t = 0; t < 32; ++t) {
            double x = v[t]; int j = t * 64 + lane;
            if (x > bv || (x == bv && j < bi)) { bv = x; bi = j; }
        }
#pragma unroll
        for (int off = 1; off < 64; off <<= 1) {
            double ov = __shfl_xor(bv, off); int oi = __shfl_xor(bi, off);
            if (ov > bv || (ov == bv && oi < bi)) { bv = ov; bi = oi; }
        }
        // all lanes agree on (bv, bi); owner clears its copy (static indexing)
        if ((bi & 63) == lane) {
            int ts = bi >> 6;
#pragma unroll
            for (int t = 0; t < 32; ++t)
                if (t == ts) v[t] = -1e302;
        }
        if (lane == 0) sel[bh * UU + u] = bi;
    }
}

// ---- K5: scores + causal + softmax + probs + PV + attn; 4 u's per block ----
// Per-u numerics identical to the proven attn_out2. K/V streamed once per 4 u.
// 1D grid 320, XCD-chunked decode so same-bh blocks share an L2.
__global__ __launch_bounds__(256) void attn_out3_r10(
    const float* __restrict__ Qf, const float* __restrict__ Kf,
    const float* __restrict__ Vf, const int* __restrict__ sel,
    float* __restrict__ attnOut, float* __restrict__ probsOut)
{
    __shared__ float qs[DK];
    __shared__ float pl[LL];
    __shared__ float red[256];
    __shared__ f32x4 sred4[16 * 16];
    int id = blockIdx.x;
    int nid = (id & 7) * 40 + (id >> 3);     // chunked XCD swizzle (320 = 8*40)
    int bh = nid / 10, ug = nid % 10;
    int tid = threadIdx.x;
    int b = bh >> 4, h = bh & 15;
    const float* kb = Kf + (size_t)bh * LL * DK;
    const float* vb = Vf + (size_t)bh * LL * DK;

    for (int uu = 0; uu < 4; ++uu) {
        int u = ug * 4 + uu;
        int qpos = sel[bh * UU + u];
        __syncthreads();   // guard qs/pl/sred4 reuse across u iterations
        if (tid < DK) qs[tid] = Qf[((size_t)bh * LL + qpos) * DK + tid];
        __syncthreads();

        f32x4 qv[16];
#pragma unroll
        for (int i = 0; i < 16; ++i) qv[i] = *(const f32x4*)(&qs[i * 4]);

        float sloc[8];
        float lmax = -INFINITY;
#pragma unroll
        for (int c = 0; c < 8; ++c) {
            int l = c * 256 + tid;
            const f32x4* kr = (const f32x4*)(kb + (size_t)l * DK);
            float s = 0.f;
#pragma unroll
            for (int i = 0; i < 16; ++i) {
                const f32x4 kvv = kr[i];
                s = fmaf(qv[i][0], kvv[0], s);
                s = fmaf(qv[i][1], kvv[1], s);
                s = fmaf(qv[i][2], kvv[2], s);
                s = fmaf(qv[i][3], kvv[3], s);
            }
            s *= 0.125f;
            if (l > qpos) s -= 1e9f;
            sloc[c] = s;
            lmax = fmaxf(lmax, s);
        }
        red[tid] = lmax; __syncthreads();
        for (int s2 = 128; s2 > 0; s2 >>= 1) {
            if (tid < s2) red[tid] = fmaxf(red[tid], red[tid + s2]);
            __syncthreads();
        }
        float mval = red[0];
        __syncthreads();
        float lsum = 0.f;
#pragma unroll
        for (int c = 0; c < 8; ++c) { sloc[c] = expf(sloc[c] - mval); lsum += sloc[c]; }
        red[tid] = lsum; __syncthreads();
        for (int s2 = 128; s2 > 0; s2 >>= 1) {
            if (tid < s2) red[tid] += red[tid + s2];
            __syncthreads();
        }
        float inv = 1.0f / red[0];
        size_t rowo = ((size_t)bh * UU + u) * LL;
#pragma unroll
        for (int c = 0; c < 8; ++c) {
            int l = c * 256 + tid;
            float p = sloc[c] * inv;
            pl[l] = p;
            probsOut[rowo + l] = p;
        }
        __syncthreads();

        int tx = tid & 15, g = tid >> 4;
        int dk4 = tx * 4;
        float ax = 0.f, ay = 0.f, az = 0.f, aw = 0.f;
#pragma unroll 4
        for (int l = g * 128; l < g * 128 + 128; ++l) {
            float p = pl[l];
            const f32x4 v = *(const f32x4*)(vb + (size_t)l * DK + dk4);
            ax = fmaf(p, v[0], ax);
            ay = fmaf(p, v[1], ay);
            az = fmaf(p, v[2], az);
            aw = fmaf(p, v[3], aw);
        }
        f32x4 acc4; acc4[0] = ax; acc4[1] = ay; acc4[2] = az; acc4[3] = aw;
        sred4[g * 16 + tx] = acc4;
        __syncthreads();
        if (tid < 64) {
            float s = 0.f;
#pragma unroll
            for (int g2 = 0; g2 < 16; ++g2) {
                const float* sp = (const float*)&sred4[g2 * 16 + (tid >> 2)];
                s += sp[tid & 3];
            }
            attnOut[((size_t)b * UU + u) * DD + h * DK + tid] = s;
        }
    }
}

extern "C" void kernel_launch(void* const* d_in, const int* in_sizes, int n_in,
                              void* d_out, int out_size, void* d_ws, size_t ws_size,
                              hipStream_t stream) {
    (void)in_sizes; (void)n_in; (void)out_size; (void)ws_size;
    const void* query = d_in[0];
    const void* key   = d_in[1];
    const void* value = d_in[2];
    const void* Wq    = d_in[3];
    const void* bq    = d_in[4];
    const void* Wk    = d_in[5];
    const void* bk    = d_in[6];
    const void* Wv    = d_in[7];
    const void* bv    = d_in[8];

    char* w = (char*)d_ws;
    const size_t NE = (size_t)BB * HH * LL * DK;   // 4,194,304
    float* Kf  = (float*)w;  w += NE * 4;
    float* Vf  = (float*)w;  w += NE * 4;
    float* Qf  = (float*)w;  w += NE * 4;
    double* Mv = (double*)w; w += (size_t)BH * LL * 8;
    double* Kbar = (double*)w; w += (size_t)BH * DK * 8;
    int* sel   = (int*)w;    w += (size_t)BH * UU * 4;
    int* flag  = (int*)w;    w += 64;

    float* attnOut  = (float*)d_out;                       // FP32 outputs
    float* probsOut = attnOut + (size_t)BB * UU * DD;

    dim3 blk(256);
    detect_dtype_r8<<<1, blk, 0, stream>>>((const u16*)query, flag);
    proj_f4_r10<<<dim3(64, 16, 2), blk, 0, stream>>>(key, query, Wk, Wq, bk, bq,
                                                     Kf, Qf, flag);
    proj_mfma_v_r9<<<dim3(32, 8), blk, 0, stream>>>(value, Wv, bv, Vf, flag);
    kbar_r8<<<32, blk, 0, stream>>>(Kf, Kbar);
    stats_max_r10<<<dim3(LL / QT, 32), blk, 0, stream>>>(Qf, Kf, Kbar, Mv);
    topk_wave_r10<<<32, dim3(64), 0, stream>>>(Mv, sel);
    attn_out3_r10<<<320, blk, 0, stream>>>(Qf, Kf, Vf, sel, attnOut, probsOut);
}

// Round 6
// 999.481 us; speedup vs baseline: 3.9711x; 1.0911x over previous
//
#include <hip/hip_runtime.h>
#include <hip/hip_bf16.h>

#define BB 2
#define LL 2048
#define DD 1024
#define HH 16
#define DK 64
#define UU 40
#define BH (BB*HH)

typedef unsigned short u16;
typedef float f32x4 __attribute__((ext_vector_type(4)));
typedef short s16x8 __attribute__((ext_vector_type(8)));

__device__ inline float b2f_r8(u16 x) {
    union { unsigned short u; __hip_bfloat16 b; } c; c.u = x;
    return __bfloat162float(c.b);
}
// dual-dtype element load (fp32 or bf16 input), wave-uniform isF
__device__ inline float ldf_r8(const void* p, size_t i, int isF) {
    return isF ? ((const float*)p)[i] : b2f_r8(((const u16*)p)[i]);
}
// dual-dtype 4-consecutive-element load
__device__ inline f32x4 ld4_r8(const void* p, size_t i, int isF) {
    if (isF) return *(const f32x4*)((const float*)p + i);
    ushort4 v = *(const ushort4*)((const u16*)p + i);
    f32x4 r;
    r[0] = b2f_r8(v.x); r[1] = b2f_r8(v.y); r[2] = b2f_r8(v.z); r[3] = b2f_r8(v.w);
    return r;
}
// fp32 -> bf16 hi/lo split (RN both; captures 16 high mantissa bits)
__device__ inline void cvt2_r8(float x, u16& h, u16& l) {
    union { __hip_bfloat16 b; u16 u; } ch, cl;
    ch.b = __float2bfloat16(x);
    float hf = __bfloat162float(ch.b);
    cl.b = __float2bfloat16(x - hf);
    h = ch.u; l = cl.u;
}

// ---------------- K0: input dtype probe ----------------
__global__ __launch_bounds__(256) void detect_dtype_r8(const u16* __restrict__ q,
                                                       int* __restrict__ flag) {
    __shared__ float red[256];
    int tid = threadIdx.x;
    float mx = 0.f;
    for (int i = tid; i < 4096; i += 256) {
        float v = fabsf(b2f_r8(q[i]));
        if (!(v < 1e30f)) v = 1e38f;
        mx = fmaxf(mx, v);
    }
    red[tid] = mx; __syncthreads();
    for (int s = 128; s > 0; s >>= 1) {
        if (tid < s) red[tid] = fmaxf(red[tid], red[tid + s]);
        __syncthreads();
    }
    if (tid == 0) *flag = (red[0] > 1e20f) ? 1 : 0;
}

#define PAD 132

// ---- K1: fp32 projection for K (z=0) and Q (z=1), stats-style structure. ----
// 128x128 output tile, 8x8 per thread, d-major LDS [64][PAD] (both staging
// writes and frag reads are the conflict-free patterns proven in stats_max).
// Per-output fmaf chain: kc 0..15 x d 0..63 => c ascending 0..1023 — BIT-
// IDENTICAL to the R2-proven projection chain. Only thread->output ownership
// changes (math per output element unchanged).
__global__ __launch_bounds__(256) void proj_f4_r11(
    const void* __restrict__ key, const void* __restrict__ query,
    const void* __restrict__ Wk, const void* __restrict__ Wq,
    const void* __restrict__ bk, const void* __restrict__ bq,
    float* __restrict__ Kf, float* __restrict__ Qf,
    const int* __restrict__ flag)
{
    __shared__ float sX[64 * PAD];   // [d][n-row]
    __shared__ float sW[64 * PAD];   // [d][f-col]
    int tid = threadIdx.x;
    int n0 = blockIdx.x * 128, f0 = blockIdx.y * 128, z = blockIdx.z;
    const void* X    = z ? query : key;
    const void* W    = z ? Wq    : Wk;
    const void* bias = z ? bq    : bk;
    float* out       = z ? Qf    : Kf;
    int isF = *flag;
    int tx = tid & 15, ty = tid >> 4;

    float acc[8][8];
#pragma unroll
    for (int a = 0; a < 8; ++a)
#pragma unroll
        for (int c = 0; c < 8; ++c) acc[a][c] = 0.f;

    for (int kc = 0; kc < 16; ++kc) {
        __syncthreads();
        // stage X tile (128 rows x 64 c) transposed to d-major
#pragma unroll
        for (int it = 0; it < 8; ++it) {
            int row = 64 * (it & 1) + (tid >> 2);
            int d4 = (tid & 3) | ((it >> 1) << 2);
            f32x4 v = ld4_r8(X, (size_t)(n0 + row) * DD + kc * 64 + d4 * 4, isF);
#pragma unroll
            for (int cc = 0; cc < 4; ++cc)
                sX[(4 * d4 + cc) * PAD + row] = v[cc];
        }
        // stage W tile (128 f-rows x 64 c) transposed to d-major
#pragma unroll
        for (int it = 0; it < 8; ++it) {
            int row = 64 * (it & 1) + (tid >> 2);
            int d4 = (tid & 3) | ((it >> 1) << 2);
            f32x4 v = ld4_r8(W, (size_t)(f0 + row) * DD + kc * 64 + d4 * 4, isF);
#pragma unroll
            for (int cc = 0; cc < 4; ++cc)
                sW[(4 * d4 + cc) * PAD + row] = v[cc];
        }
        __syncthreads();
        for (int d = 0; d < 64; ++d) {
            const f32x4 xa = *(const f32x4*)(&sX[d * PAD + ty * 4]);
            const f32x4 xb = *(const f32x4*)(&sX[d * PAD + 64 + ty * 4]);
            const f32x4 wa = *(const f32x4*)(&sW[d * PAD + tx * 4]);
            const f32x4 wb = *(const f32x4*)(&sW[d * PAD + 64 + tx * 4]);
            float xv[8] = {xa[0], xa[1], xa[2], xa[3], xb[0], xb[1], xb[2], xb[3]};
            float wv[8] = {wa[0], wa[1], wa[2], wa[3], wb[0], wb[1], wb[2], wb[3]};
#pragma unroll
            for (int a = 0; a < 8; ++a)
#pragma unroll
                for (int c = 0; c < 8; ++c)
                    acc[a][c] = fmaf(xv[a], wv[c], acc[a][c]);
        }
    }
#pragma unroll
    for (int a = 0; a < 8; ++a) {
        int n = n0 + (a >> 2) * 64 + ty * 4 + (a & 3);
        int b = n >> 11, l = n & (LL - 1);
#pragma unroll
        for (int c = 0; c < 8; ++c) {
            int f = f0 + (c >> 2) * 64 + tx * 4 + (c & 3);
            int h = f >> 6, dk = f & 63;
            out[((size_t)(b * HH + h) * LL + l) * DK + dk] =
                acc[a][c] + ldf_r8(bias, (size_t)f, isF);
        }
    }
}

// ---- K1b: V projection via bf16x3 MFMA (hihi + lohi + hilo), fp32 accum. ----
// (unchanged — proven) V feeds ONLY the attn output.
#define LDK 72
__global__ __launch_bounds__(256) void proj_mfma_v_r9(
    const void* __restrict__ X, const void* __restrict__ W,
    const void* __restrict__ bias, float* __restrict__ out,
    const int* __restrict__ flag)
{
    __shared__ u16 Ahi[128 * LDK];
    __shared__ u16 Alo[128 * LDK];
    __shared__ u16 Bhi[128 * LDK];
    __shared__ u16 Blo[128 * LDK];
    int tid = threadIdx.x;
    int n0 = blockIdx.x * 128, f0 = blockIdx.y * 128;
    int isF = *flag;
    int lane = tid & 63, w = tid >> 6, wr = w >> 1, wc = w & 1;

    f32x4 acc[4][4] = {};

    for (int kc = 0; kc < 16; ++kc) {
        __syncthreads();
#pragma unroll
        for (int it = 0; it < 16; ++it) {
            int i = it * 256 + tid;
            int isB = i >> 11, j = i & 2047;
            int row = j >> 4, c = (j & 15) << 2;
            f32x4 v = ld4_r8(isB ? W : X, (size_t)((isB ? f0 : n0) + row) * DD + kc * 64 + c, isF);
            u16* hh = isB ? Bhi : Ahi;
            u16* ll = isB ? Blo : Alo;
            ushort4 h4, l4;
            cvt2_r8(v[0], h4.x, l4.x);
            cvt2_r8(v[1], h4.y, l4.y);
            cvt2_r8(v[2], h4.z, l4.z);
            cvt2_r8(v[3], h4.w, l4.w);
            *(ushort4*)&hh[row * LDK + c] = h4;
            *(ushort4*)&ll[row * LDK + c] = l4;
        }
        __syncthreads();
#pragma unroll
        for (int kk = 0; kk < 2; ++kk) {
            int koff = kk * 32 + (lane >> 4) * 8;
            s16x8 ah[4], al[4];
#pragma unroll
            for (int mi = 0; mi < 4; ++mi) {
                int r = wr * 64 + mi * 16 + (lane & 15);
                ah[mi] = *(const s16x8*)&Ahi[r * LDK + koff];
                al[mi] = *(const s16x8*)&Alo[r * LDK + koff];
            }
#pragma unroll
            for (int ni = 0; ni < 4; ++ni) {
                int r = wc * 64 + ni * 16 + (lane & 15);
                s16x8 bh = *(const s16x8*)&Bhi[r * LDK + koff];
                s16x8 bl = *(const s16x8*)&Blo[r * LDK + koff];
#pragma unroll
                for (int mi = 0; mi < 4; ++mi) {
                    acc[mi][ni] = __builtin_amdgcn_mfma_f32_16x16x32_bf16(ah[mi], bh, acc[mi][ni], 0, 0, 0);
                    acc[mi][ni] = __builtin_amdgcn_mfma_f32_16x16x32_bf16(al[mi], bh, acc[mi][ni], 0, 0, 0);
                    acc[mi][ni] = __builtin_amdgcn_mfma_f32_16x16x32_bf16(ah[mi], bl, acc[mi][ni], 0, 0, 0);
                }
            }
        }
    }

#pragma unroll
    for (int ni = 0; ni < 4; ++ni) {
        int f = f0 + wc * 64 + ni * 16 + (lane & 15);
        float bb = ldf_r8(bias, (size_t)f, isF);
        int h = f >> 6, dk = f & 63;
#pragma unroll
        for (int mi = 0; mi < 4; ++mi) {
            int nbase = n0 + wr * 64 + mi * 16 + ((lane >> 4) << 2);
#pragma unroll
            for (int j2 = 0; j2 < 4; ++j2) {
                int n = nbase + j2, b = n >> 11, l = n & (LL - 1);
                out[((size_t)(b * HH + h) * LL + l) * DK + dk] = acc[mi][ni][j2] + bb;
            }
        }
    }
}

// ---------------- K2b: Kbar[bh][d] = mean over l of K (fp64 accumulate) ----------------
__global__ __launch_bounds__(256) void kbar_r8(
    const float* __restrict__ Kf, double* __restrict__ Kbar)
{
    __shared__ double red[256];
    int bh = blockIdx.x, tid = threadIdx.x;
    int d = tid & 63, seg = tid >> 6;
    double s = 0;
    for (int l = seg * 512; l < seg * 512 + 512; ++l)
        s += (double)Kf[((size_t)bh * LL + l) * DK + d];
    red[tid] = s; __syncthreads();
    if (tid < 128) red[tid] += red[tid + 128];
    __syncthreads();
    if (tid < 64) Kbar[(size_t)bh * DK + d] = (red[tid] + red[tid + 64]) * (1.0 / (double)LL);
}

// ---- K3: rowmax(Q K^T) fp32 GEMM; M = rowmax - Q.Kbar (unchanged, proven) ----
#define QT 128
#define KT 128
__global__ __launch_bounds__(256) void stats_max_r10(
    const float* __restrict__ Qf, const float* __restrict__ Kf,
    const double* __restrict__ Kbar, double* __restrict__ Mv)
{
    __shared__ float sQ[64 * PAD];
    __shared__ float sK[64 * PAD];
    __shared__ float rowmax[QT];
    int tid = threadIdx.x;
    int q0 = blockIdx.x * QT, bh = blockIdx.y;
    int tx = tid & 15, ty = tid >> 4;

    // stage Q tile transposed to d-major: sQ[d][row] (conflict-free writes)
    {
        const float* src = Qf + ((size_t)bh * LL + q0) * DK;
#pragma unroll
        for (int it = 0; it < 8; ++it) {
            int row = 64 * (it & 1) + (tid >> 2);
            int d4 = (tid & 3) | ((it >> 1) << 2);
            f32x4 v = *(const f32x4*)(src + (size_t)row * DK + d4 * 4);
#pragma unroll
            for (int cc = 0; cc < 4; ++cc)
                sQ[(4 * d4 + cc) * PAD + row] = v[cc];
        }
    }
    float rmax8[8];
#pragma unroll
    for (int a = 0; a < 8; ++a) rmax8[a] = -INFINITY;

    const float* kbase = Kf + (size_t)bh * LL * DK;
    for (int kc = 0; kc < LL / KT; ++kc) {
        __syncthreads();   // guard sK rewrite vs previous compute (and sQ at kc=0)
#pragma unroll
        for (int it = 0; it < 8; ++it) {
            int row = 64 * (it & 1) + (tid >> 2);
            int d4 = (tid & 3) | ((it >> 1) << 2);
            f32x4 v = *(const f32x4*)(kbase + (size_t)(kc * KT + row) * DK + d4 * 4);
#pragma unroll
            for (int cc = 0; cc < 4; ++cc)
                sK[(4 * d4 + cc) * PAD + row] = v[cc];
        }
        __syncthreads();
        float acc[8][8];
#pragma unroll
        for (int a = 0; a < 8; ++a)
#pragma unroll
            for (int c = 0; c < 8; ++c) acc[a][c] = 0.f;
        for (int d = 0; d < 64; ++d) {
            const f32x4 qa = *(const f32x4*)(&sQ[d * PAD + ty * 4]);
            const f32x4 qb = *(const f32x4*)(&sQ[d * PAD + 64 + ty * 4]);
            const f32x4 ka = *(const f32x4*)(&sK[d * PAD + tx * 4]);
            const f32x4 kb = *(const f32x4*)(&sK[d * PAD + 64 + tx * 4]);
            float qv[8] = {qa[0], qa[1], qa[2], qa[3], qb[0], qb[1], qb[2], qb[3]};
            float kv[8] = {ka[0], ka[1], ka[2], ka[3], kb[0], kb[1], kb[2], kb[3]};
#pragma unroll
            for (int a = 0; a < 8; ++a)
#pragma unroll
                for (int c = 0; c < 8; ++c)
                    acc[a][c] = fmaf(qv[a], kv[c], acc[a][c]);
        }
#pragma unroll
        for (int a = 0; a < 8; ++a)
#pragma unroll
            for (int c = 0; c < 8; ++c) rmax8[a] = fmaxf(rmax8[a], acc[a][c]);
    }
    // cross-tx max reduce within 16-lane groups (tx = lane&15)
#pragma unroll
    for (int a = 0; a < 8; ++a) {
        float v = rmax8[a];
        v = fmaxf(v, __shfl_xor(v, 1));
        v = fmaxf(v, __shfl_xor(v, 2));
        v = fmaxf(v, __shfl_xor(v, 4));
        v = fmaxf(v, __shfl_xor(v, 8));
        rmax8[a] = v;
    }
    if (tx == 0) {
#pragma unroll
        for (int a = 0; a < 8; ++a) {
            int row = ty * 4 + (a & 3) + (a >> 2) * 64;
            rowmax[row] = rmax8[a];
        }
    }
    __syncthreads();
    if (tid < QT) {
        const double* kb = Kbar + (size_t)bh * DK;
        double s = 0;
#pragma unroll
        for (int d = 0; d < 64; ++d) s += (double)sQ[d * PAD + tid] * kb[d];
        Mv[(size_t)bh * LL + q0 + tid] = (double)rowmax[tid] - s;
    }
}

// ------- K4: exact top-40 per (b,h), one wave per bh, register-resident. -------
__global__ __launch_bounds__(64) void topk_wave_r10(
    const double* __restrict__ Mv, int* __restrict__ sel)
{
    int bh = blockIdx.x, lane = threadIdx.x;
    double v[32];
#pragma unroll
    for (int t = 0; t < 32; ++t) v[t] = Mv[(size_t)bh * LL + t * 64 + lane];
    for (int u = 0; u < UU; ++u) {
        double bv = -1e301; int bi = LL;
#pragma unroll
        for (int t = 0; t < 32; ++t) {
            double x = v[t]; int j = t * 64 + lane;
            if (x > bv || (x == bv && j < bi)) { bv = x; bi = j; }
        }
#pragma unroll
        for (int off = 1; off < 64; off <<= 1) {
            double ov = __shfl_xor(bv, off); int oi = __shfl_xor(bi, off);
            if (ov > bv || (ov == bv && oi < bi)) { bv = ov; bi = oi; }
        }
        if ((bi & 63) == lane) {
            int ts = bi >> 6;
#pragma unroll
            for (int t = 0; t < 32; ++t)
                if (t == ts) v[t] = -1e302;
        }
        if (lane == 0) sel[bh * UU + u] = bi;
    }
}

// ---- K5: scores + causal + softmax + probs + PV + attn; ONE u per block ----
// (per-u numerics byte-identical to the R2-proven attn_out2). 1280 blocks =
// 5/CU. XCD-affinity decode: all 40 u-blocks of a bh land on one XCD so its
// 1 MB of K+V stays L2-resident across the 40 readers.
__global__ __launch_bounds__(256) void attn_out4_r11(
    const float* __restrict__ Qf, const float* __restrict__ Kf,
    const float* __restrict__ Vf, const int* __restrict__ sel,
    float* __restrict__ attnOut, float* __restrict__ probsOut)
{
    __shared__ float qs[DK];
    __shared__ float pl[LL];
    __shared__ float red[256];
    __shared__ f32x4 sred4[16 * 16];
    int id = blockIdx.x;
    int xcd = id & 7, t = id >> 3;
    int u = t % 40, bh = ((t / 40) << 3) | xcd;
    int tid = threadIdx.x;
    int b = bh >> 4, h = bh & 15;
    int qpos = sel[bh * UU + u];

    if (tid < DK) qs[tid] = Qf[((size_t)bh * LL + qpos) * DK + tid];
    __syncthreads();

    f32x4 qv[16];
#pragma unroll
    for (int i = 0; i < 16; ++i) qv[i] = *(const f32x4*)(&qs[i * 4]);

    const float* kb = Kf + (size_t)bh * LL * DK;
    float sloc[8];
    float lmax = -INFINITY;
#pragma unroll
    for (int c = 0; c < 8; ++c) {
        int l = c * 256 + tid;
        const f32x4* kr = (const f32x4*)(kb + (size_t)l * DK);
        float s = 0.f;
#pragma unroll
        for (int i = 0; i < 16; ++i) {
            const f32x4 kvv = kr[i];
            s = fmaf(qv[i][0], kvv[0], s);
            s = fmaf(qv[i][1], kvv[1], s);
            s = fmaf(qv[i][2], kvv[2], s);
            s = fmaf(qv[i][3], kvv[3], s);
        }
        s *= 0.125f;
        if (l > qpos) s -= 1e9f;
        sloc[c] = s;
        lmax = fmaxf(lmax, s);
    }
    red[tid] = lmax; __syncthreads();
    for (int s2 = 128; s2 > 0; s2 >>= 1) {
        if (tid < s2) red[tid] = fmaxf(red[tid], red[tid + s2]);
        __syncthreads();
    }
    float mval = red[0];
    __syncthreads();
    float lsum = 0.f;
#pragma unroll
    for (int c = 0; c < 8; ++c) { sloc[c] = expf(sloc[c] - mval); lsum += sloc[c]; }
    red[tid] = lsum; __syncthreads();
    for (int s2 = 128; s2 > 0; s2 >>= 1) {
        if (tid < s2) red[tid] += red[tid + s2];
        __syncthreads();
    }
    float inv = 1.0f / red[0];
    size_t rowo = ((size_t)bh * UU + u) * LL;
#pragma unroll
    for (int c = 0; c < 8; ++c) {
        int l = c * 256 + tid;
        float p = sloc[c] * inv;
        pl[l] = p;
        probsOut[rowo + l] = p;
    }
    __syncthreads();

    int tx = tid & 15, g = tid >> 4;
    int dk4 = tx * 4;
    const float* vb = Vf + (size_t)bh * LL * DK;
    float ax = 0.f, ay = 0.f, az = 0.f, aw = 0.f;
#pragma unroll 4
    for (int l = g * 128; l < g * 128 + 128; ++l) {
        float p = pl[l];
        const f32x4 v = *(const f32x4*)(vb + (size_t)l * DK + dk4);
        ax = fmaf(p, v[0], ax);
        ay = fmaf(p, v[1], ay);
        az = fmaf(p, v[2], az);
        aw = fmaf(p, v[3], aw);
    }
    f32x4 acc4; acc4[0] = ax; acc4[1] = ay; acc4[2] = az; acc4[3] = aw;
    sred4[g * 16 + tx] = acc4;
    __syncthreads();
    if (tid < 64) {
        float s = 0.f;
#pragma unroll
        for (int g2 = 0; g2 < 16; ++g2) {
            const float* sp = (const float*)&sred4[g2 * 16 + (tid >> 2)];
            s += sp[tid & 3];
        }
        attnOut[((size_t)b * UU + u) * DD + h * DK + tid] = s;
    }
}

extern "C" void kernel_launch(void* const* d_in, const int* in_sizes, int n_in,
                              void* d_out, int out_size, void* d_ws, size_t ws_size,
                              hipStream_t stream) {
    (void)in_sizes; (void)n_in; (void)out_size; (void)ws_size;
    const void* query = d_in[0];
    const void* key   = d_in[1];
    const void* value = d_in[2];
    const void* Wq    = d_in[3];
    const void* bq    = d_in[4];
    const void* Wk    = d_in[5];
    const void* bk    = d_in[6];
    const void* Wv    = d_in[7];
    const void* bv    = d_in[8];

    char* w = (char*)d_ws;
    const size_t NE = (size_t)BB * HH * LL * DK;   // 4,194,304
    float* Kf  = (float*)w;  w += NE * 4;
    float* Vf  = (float*)w;  w += NE * 4;
    float* Qf  = (float*)w;  w += NE * 4;
    double* Mv = (double*)w; w += (size_t)BH * LL * 8;
    double* Kbar = (double*)w; w += (size_t)BH * DK * 8;
    int* sel   = (int*)w;    w += (size_t)BH * UU * 4;
    int* flag  = (int*)w;    w += 64;

    float* attnOut  = (float*)d_out;                       // FP32 outputs
    float* probsOut = attnOut + (size_t)BB * UU * DD;

    dim3 blk(256);
    detect_dtype_r8<<<1, blk, 0, stream>>>((const u16*)query, flag);
    proj_f4_r11<<<dim3(32, 8, 2), blk, 0, stream>>>(key, query, Wk, Wq, bk, bq,
                                                    Kf, Qf, flag);
    proj_mfma_v_r9<<<dim3(32, 8), blk, 0, stream>>>(value, Wv, bv, Vf, flag);
    kbar_r8<<<32, blk, 0, stream>>>(Kf, Kbar);
    stats_max_r10<<<dim3(LL / QT, 32), blk, 0, stream>>>(Qf, Kf, Kbar, Mv);
    topk_wave_r10<<<32, dim3(64), 0, stream>>>(Mv, sel);
    attn_out4_r11<<<1280, blk, 0, stream>>>(Qf, Kf, Vf, sel, attnOut, probsOut);
}

// Round 7
// 924.029 us; speedup vs baseline: 4.2953x; 1.0817x over previous
//
#include <hip/hip_runtime.h>
#include <hip/hip_bf16.h>

#define BB 2
#define LL 2048
#define DD 1024
#define HH 16
#define DK 64
#define UU 40
#define BH (BB*HH)

typedef unsigned short u16;
typedef float f32x4 __attribute__((ext_vector_type(4)));
typedef short s16x8 __attribute__((ext_vector_type(8)));

__device__ inline float b2f_r8(u16 x) {
    union { unsigned short u; __hip_bfloat16 b; } c; c.u = x;
    return __bfloat162float(c.b);
}
__device__ inline float ldf_r8(const void* p, size_t i, int isF) {
    return isF ? ((const float*)p)[i] : b2f_r8(((const u16*)p)[i]);
}
__device__ inline f32x4 ld4_r8(const void* p, size_t i, int isF) {
    if (isF) return *(const f32x4*)((const float*)p + i);
    ushort4 v = *(const ushort4*)((const u16*)p + i);
    f32x4 r;
    r[0] = b2f_r8(v.x); r[1] = b2f_r8(v.y); r[2] = b2f_r8(v.z); r[3] = b2f_r8(v.w);
    return r;
}
__device__ inline void cvt2_r8(float x, u16& h, u16& l) {
    union { __hip_bfloat16 b; u16 u; } ch, cl;
    ch.b = __float2bfloat16(x);
    float hf = __bfloat162float(ch.b);
    cl.b = __float2bfloat16(x - hf);
    h = ch.u; l = cl.u;
}

// ---------------- K0: input dtype probe ----------------
__global__ __launch_bounds__(256) void detect_dtype_r8(const u16* __restrict__ q,
                                                       int* __restrict__ flag) {
    __shared__ float red[256];
    int tid = threadIdx.x;
    float mx = 0.f;
    for (int i = tid; i < 4096; i += 256) {
        float v = fabsf(b2f_r8(q[i]));
        if (!(v < 1e30f)) v = 1e38f;
        mx = fmaxf(mx, v);
    }
    red[tid] = mx; __syncthreads();
    for (int s = 128; s > 0; s >>= 1) {
        if (tid < s) red[tid] = fmaxf(red[tid], red[tid + s]);
        __syncthreads();
    }
    if (tid == 0) *flag = (red[0] > 1e20f) ? 1 : 0;
}

#define PAD 132

// ---- K1: fp32 projection K (z=0) / Q (z=1). 128x128 tile, 32-deep k-chunks
// (LDS 33.8 KB -> 4 blocks/CU vs r11's 2). Per-output fmaf chain: kc 0..31 x
// d 0..31 => c ascending 0..1023 — BIT-IDENTICAL to the proven chain.
__global__ __launch_bounds__(256) void proj_f4_r12(
    const void* __restrict__ key, const void* __restrict__ query,
    const void* __restrict__ Wk, const void* __restrict__ Wq,
    const void* __restrict__ bk, const void* __restrict__ bq,
    float* __restrict__ Kf, float* __restrict__ Qf,
    const int* __restrict__ flag)
{
    __shared__ float sX[32 * PAD];   // [d][n-row]
    __shared__ float sW[32 * PAD];   // [d][f-col]
    int tid = threadIdx.x;
    int n0 = blockIdx.x * 128, f0 = blockIdx.y * 128, z = blockIdx.z;
    const void* X    = z ? query : key;
    const void* W    = z ? Wq    : Wk;
    const void* bias = z ? bq    : bk;
    float* out       = z ? Qf    : Kf;
    int isF = *flag;
    int tx = tid & 15, ty = tid >> 4;

    float acc[8][8];
#pragma unroll
    for (int a = 0; a < 8; ++a)
#pragma unroll
        for (int c = 0; c < 8; ++c) acc[a][c] = 0.f;

    for (int kc = 0; kc < 32; ++kc) {
        __syncthreads();
#pragma unroll
        for (int it = 0; it < 4; ++it) {
            int idx = it * 256 + tid;
            int row = idx >> 3, d4 = idx & 7;
            f32x4 v = ld4_r8(X, (size_t)(n0 + row) * DD + kc * 32 + d4 * 4, isF);
#pragma unroll
            for (int cc = 0; cc < 4; ++cc)
                sX[(4 * d4 + cc) * PAD + row] = v[cc];
        }
#pragma unroll
        for (int it = 0; it < 4; ++it) {
            int idx = it * 256 + tid;
            int row = idx >> 3, d4 = idx & 7;
            f32x4 v = ld4_r8(W, (size_t)(f0 + row) * DD + kc * 32 + d4 * 4, isF);
#pragma unroll
            for (int cc = 0; cc < 4; ++cc)
                sW[(4 * d4 + cc) * PAD + row] = v[cc];
        }
        __syncthreads();
        for (int d = 0; d < 32; ++d) {
            const f32x4 xa = *(const f32x4*)(&sX[d * PAD + ty * 4]);
            const f32x4 xb = *(const f32x4*)(&sX[d * PAD + 64 + ty * 4]);
            const f32x4 wa = *(const f32x4*)(&sW[d * PAD + tx * 4]);
            const f32x4 wb = *(const f32x4*)(&sW[d * PAD + 64 + tx * 4]);
            float xv[8] = {xa[0], xa[1], xa[2], xa[3], xb[0], xb[1], xb[2], xb[3]};
            float wv[8] = {wa[0], wa[1], wa[2], wa[3], wb[0], wb[1], wb[2], wb[3]};
#pragma unroll
            for (int a = 0; a < 8; ++a)
#pragma unroll
                for (int c = 0; c < 8; ++c)
                    acc[a][c] = fmaf(xv[a], wv[c], acc[a][c]);
        }
    }
#pragma unroll
    for (int a = 0; a < 8; ++a) {
        int n = n0 + (a >> 2) * 64 + ty * 4 + (a & 3);
        int b = n >> 11, l = n & (LL - 1);
#pragma unroll
        for (int c = 0; c < 8; ++c) {
            int f = f0 + (c >> 2) * 64 + tx * 4 + (c & 3);
            int h = f >> 6, dk = f & 63;
            out[((size_t)(b * HH + h) * LL + l) * DK + dk] =
                acc[a][c] + ldf_r8(bias, (size_t)f, isF);
        }
    }
}

// ---- K1b: V projection via bf16x3 MFMA (unchanged — proven). ----
#define LDK 72
__global__ __launch_bounds__(256) void proj_mfma_v_r9(
    const void* __restrict__ X, const void* __restrict__ W,
    const void* __restrict__ bias, float* __restrict__ out,
    const int* __restrict__ flag)
{
    __shared__ u16 Ahi[128 * LDK];
    __shared__ u16 Alo[128 * LDK];
    __shared__ u16 Bhi[128 * LDK];
    __shared__ u16 Blo[128 * LDK];
    int tid = threadIdx.x;
    int n0 = blockIdx.x * 128, f0 = blockIdx.y * 128;
    int isF = *flag;
    int lane = tid & 63, w = tid >> 6, wr = w >> 1, wc = w & 1;

    f32x4 acc[4][4] = {};

    for (int kc = 0; kc < 16; ++kc) {
        __syncthreads();
#pragma unroll
        for (int it = 0; it < 16; ++it) {
            int i = it * 256 + tid;
            int isB = i >> 11, j = i & 2047;
            int row = j >> 4, c = (j & 15) << 2;
            f32x4 v = ld4_r8(isB ? W : X, (size_t)((isB ? f0 : n0) + row) * DD + kc * 64 + c, isF);
            u16* hh = isB ? Bhi : Ahi;
            u16* ll = isB ? Blo : Alo;
            ushort4 h4, l4;
            cvt2_r8(v[0], h4.x, l4.x);
            cvt2_r8(v[1], h4.y, l4.y);
            cvt2_r8(v[2], h4.z, l4.z);
            cvt2_r8(v[3], h4.w, l4.w);
            *(ushort4*)&hh[row * LDK + c] = h4;
            *(ushort4*)&ll[row * LDK + c] = l4;
        }
        __syncthreads();
#pragma unroll
        for (int kk = 0; kk < 2; ++kk) {
            int koff = kk * 32 + (lane >> 4) * 8;
            s16x8 ah[4], al[4];
#pragma unroll
            for (int mi = 0; mi < 4; ++mi) {
                int r = wr * 64 + mi * 16 + (lane & 15);
                ah[mi] = *(const s16x8*)&Ahi[r * LDK + koff];
                al[mi] = *(const s16x8*)&Alo[r * LDK + koff];
            }
#pragma unroll
            for (int ni = 0; ni < 4; ++ni) {
                int r = wc * 64 + ni * 16 + (lane & 15);
                s16x8 bh = *(const s16x8*)&Bhi[r * LDK + koff];
                s16x8 bl = *(const s16x8*)&Blo[r * LDK + koff];
#pragma unroll
                for (int mi = 0; mi < 4; ++mi) {
                    acc[mi][ni] = __builtin_amdgcn_mfma_f32_16x16x32_bf16(ah[mi], bh, acc[mi][ni], 0, 0, 0);
                    acc[mi][ni] = __builtin_amdgcn_mfma_f32_16x16x32_bf16(al[mi], bh, acc[mi][ni], 0, 0, 0);
                    acc[mi][ni] = __builtin_amdgcn_mfma_f32_16x16x32_bf16(ah[mi], bl, acc[mi][ni], 0, 0, 0);
                }
            }
        }
    }

#pragma unroll
    for (int ni = 0; ni < 4; ++ni) {
        int f = f0 + wc * 64 + ni * 16 + (lane & 15);
        float bb = ldf_r8(bias, (size_t)f, isF);
        int h = f >> 6, dk = f & 63;
#pragma unroll
        for (int mi = 0; mi < 4; ++mi) {
            int nbase = n0 + wr * 64 + mi * 16 + ((lane >> 4) << 2);
#pragma unroll
            for (int j2 = 0; j2 < 4; ++j2) {
                int n = nbase + j2, b = n >> 11, l = n & (LL - 1);
                out[((size_t)(b * HH + h) * LL + l) * DK + dk] = acc[mi][ni][j2] + bb;
            }
        }
    }
}

// ---------------- K2b: Kbar (unchanged) ----------------
__global__ __launch_bounds__(256) void kbar_r8(
    const float* __restrict__ Kf, double* __restrict__ Kbar)
{
    __shared__ double red[256];
    int bh = blockIdx.x, tid = threadIdx.x;
    int d = tid & 63, seg = tid >> 6;
    double s = 0;
    for (int l = seg * 512; l < seg * 512 + 512; ++l)
        s += (double)Kf[((size_t)bh * LL + l) * DK + d];
    red[tid] = s; __syncthreads();
    if (tid < 128) red[tid] += red[tid + 128];
    __syncthreads();
    if (tid < 64) Kbar[(size_t)bh * DK + d] = (red[tid] + red[tid + 64]) * (1.0 / (double)LL);
}

// ---- K3: rowmax GEMM, KT=64 (LDS 51 KB -> 3 blocks/CU). Scores + max set
// identical to proven r10 (d 0..63 ascending chain; max commutative).
#define QT 128
__global__ __launch_bounds__(256) void stats_max_r12(
    const float* __restrict__ Qf, const float* __restrict__ Kf,
    const double* __restrict__ Kbar, double* __restrict__ Mv)
{
    __shared__ float sQ[64 * PAD];
    __shared__ float sK[64 * 68];
    __shared__ float rowmax[QT];
    int tid = threadIdx.x;
    int q0 = blockIdx.x * QT, bh = blockIdx.y;
    int tx = tid & 15, ty = tid >> 4;

    {
        const float* src = Qf + ((size_t)bh * LL + q0) * DK;
#pragma unroll
        for (int it = 0; it < 8; ++it) {
            int row = 64 * (it & 1) + (tid >> 2);
            int d4 = (tid & 3) | ((it >> 1) << 2);
            f32x4 v = *(const f32x4*)(src + (size_t)row * DK + d4 * 4);
#pragma unroll
            for (int cc = 0; cc < 4; ++cc)
                sQ[(4 * d4 + cc) * PAD + row] = v[cc];
        }
    }
    float rmax8[8];
#pragma unroll
    for (int a = 0; a < 8; ++a) rmax8[a] = -INFINITY;

    const float* kbase = Kf + (size_t)bh * LL * DK;
    for (int kc = 0; kc < 32; ++kc) {
        __syncthreads();
#pragma unroll
        for (int it = 0; it < 4; ++it) {
            int row = tid >> 2;
            int d4 = (tid & 3) | (it << 2);
            f32x4 v = *(const f32x4*)(kbase + (size_t)(kc * 64 + row) * DK + d4 * 4);
#pragma unroll
            for (int cc = 0; cc < 4; ++cc)
                sK[(4 * d4 + cc) * 68 + row] = v[cc];
        }
        __syncthreads();
        float acc[8][4];
#pragma unroll
        for (int a = 0; a < 8; ++a)
#pragma unroll
            for (int c = 0; c < 4; ++c) acc[a][c] = 0.f;
        for (int d = 0; d < 64; ++d) {
            const f32x4 qa = *(const f32x4*)(&sQ[d * PAD + ty * 4]);
            const f32x4 qb = *(const f32x4*)(&sQ[d * PAD + 64 + ty * 4]);
            const f32x4 ka = *(const f32x4*)(&sK[d * 68 + tx * 4]);
            float qv[8] = {qa[0], qa[1], qa[2], qa[3], qb[0], qb[1], qb[2], qb[3]};
#pragma unroll
            for (int a = 0; a < 8; ++a)
#pragma unroll
                for (int c = 0; c < 4; ++c)
                    acc[a][c] = fmaf(qv[a], ka[c], acc[a][c]);
        }
#pragma unroll
        for (int a = 0; a < 8; ++a)
#pragma unroll
            for (int c = 0; c < 4; ++c) rmax8[a] = fmaxf(rmax8[a], acc[a][c]);
    }
#pragma unroll
    for (int a = 0; a < 8; ++a) {
        float v = rmax8[a];
        v = fmaxf(v, __shfl_xor(v, 1));
        v = fmaxf(v, __shfl_xor(v, 2));
        v = fmaxf(v, __shfl_xor(v, 4));
        v = fmaxf(v, __shfl_xor(v, 8));
        rmax8[a] = v;
    }
    if (tx == 0) {
#pragma unroll
        for (int a = 0; a < 8; ++a) {
            int row = ty * 4 + (a & 3) + (a >> 2) * 64;
            rowmax[row] = rmax8[a];
        }
    }
    __syncthreads();
    if (tid < QT) {
        const double* kb = Kbar + (size_t)bh * DK;
        double s = 0;
#pragma unroll
        for (int d = 0; d < 64; ++d) s += (double)sQ[d * PAD + tid] * kb[d];
        Mv[(size_t)bh * LL + q0 + tid] = (double)rowmax[tid] - s;
    }
}

// ------- K4: exact top-40, one wave per bh (unchanged — proven). -------
__global__ __launch_bounds__(64) void topk_wave_r10(
    const double* __restrict__ Mv, int* __restrict__ sel)
{
    int bh = blockIdx.x, lane = threadIdx.x;
    double v[32];
#pragma unroll
    for (int t = 0; t < 32; ++t) v[t] = Mv[(size_t)bh * LL + t * 64 + lane];
    for (int u = 0; u < UU; ++u) {
        double bv = -1e301; int bi = LL;
#pragma unroll
        for (int t = 0; t < 32; ++t) {
            double x = v[t]; int j = t * 64 + lane;
            if (x > bv || (x == bv && j < bi)) { bv = x; bi = j; }
        }
#pragma unroll
        for (int off = 1; off < 64; off <<= 1) {
            double ov = __shfl_xor(bv, off); int oi = __shfl_xor(bi, off);
            if (ov > bv || (ov == bv && oi < bi)) { bv = ov; bi = oi; }
        }
        if ((bi & 63) == lane) {
            int ts = bi >> 6;
#pragma unroll
            for (int t = 0; t < 32; ++t)
                if (t == ts) v[t] = -1e302;
        }
        if (lane == 0) sel[bh * UU + u] = bi;
    }
}

// ---- K5a: S[u][l] for one (bh, 256-l chunk); K read ONCE per chunk. ----
// Per-score chain identical to old attn (16 x 4 sequential fmaf, *0.125, mask).
__global__ __launch_bounds__(256) void scores_r12(
    const float* __restrict__ Qf, const float* __restrict__ Kf,
    const int* __restrict__ sel, float* __restrict__ S)
{
    __shared__ float sK[256 * 68];
    __shared__ float qsm[40 * 68];
    __shared__ int qpos[UU];
    int lq = blockIdx.x, bh = blockIdx.y, tid = threadIdx.x;
    int l0 = lq * 256;
    if (tid < UU) qpos[tid] = sel[bh * UU + tid];
    __syncthreads();
    for (int i = tid; i < 640; i += 256) {
        int u = i >> 4, c4 = i & 15;
        *(f32x4*)&qsm[u * 68 + c4 * 4] =
            *(const f32x4*)&Qf[((size_t)bh * LL + qpos[u]) * DK + c4 * 4];
    }
#pragma unroll
    for (int it = 0; it < 16; ++it) {
        int idx = it * 256 + tid;
        int l = idx >> 4, d4 = idx & 15;
        *(f32x4*)&sK[l * 68 + d4 * 4] =
            *(const f32x4*)&Kf[((size_t)bh * LL + l0 + l) * DK + d4 * 4];
    }
    __syncthreads();
    int gu = tid >> 5, lt = tid & 31;
    float acc[5][8];
#pragma unroll
    for (int ui = 0; ui < 5; ++ui)
#pragma unroll
        for (int li = 0; li < 8; ++li) acc[ui][li] = 0.f;
    for (int d16 = 0; d16 < 16; ++d16) {
        f32x4 qf[5], kf[8];
#pragma unroll
        for (int ui = 0; ui < 5; ++ui)
            qf[ui] = *(const f32x4*)&qsm[(gu + 8 * ui) * 68 + d16 * 4];
#pragma unroll
        for (int li = 0; li < 8; ++li)
            kf[li] = *(const f32x4*)&sK[(lt + 32 * li) * 68 + d16 * 4];
#pragma unroll
        for (int ui = 0; ui < 5; ++ui)
#pragma unroll
            for (int li = 0; li < 8; ++li)
#pragma unroll
                for (int c = 0; c < 4; ++c)
                    acc[ui][li] = fmaf(qf[ui][c], kf[li][c], acc[ui][li]);
    }
#pragma unroll
    for (int ui = 0; ui < 5; ++ui) {
        int u = gu + 8 * ui;
        int qp = qpos[u];
#pragma unroll
        for (int li = 0; li < 8; ++li) {
            int l = l0 + lt + 32 * li;
            float s = acc[ui][li] * 0.125f;
            if (l > qp) s -= 1e9f;
            S[((size_t)bh * UU + u) * LL + l] = s;
        }
    }
}

// ---- K5b: row softmax -> probs. Reduction code identical to proven attn. ----
__global__ __launch_bounds__(256) void softmax_r12(
    const float* __restrict__ S, float* __restrict__ probsOut)
{
    __shared__ float red[256];
    int u = blockIdx.x, bh = blockIdx.y, tid = threadIdx.x;
    size_t rowo = ((size_t)bh * UU + u) * LL;
    float sloc[8];
    float lmax = -INFINITY;
#pragma unroll
    for (int c = 0; c < 8; ++c) {
        sloc[c] = S[rowo + c * 256 + tid];
        lmax = fmaxf(lmax, sloc[c]);
    }
    red[tid] = lmax; __syncthreads();
    for (int s2 = 128; s2 > 0; s2 >>= 1) {
        if (tid < s2) red[tid] = fmaxf(red[tid], red[tid + s2]);
        __syncthreads();
    }
    float mval = red[0];
    __syncthreads();
    float lsum = 0.f;
#pragma unroll
    for (int c = 0; c < 8; ++c) { sloc[c] = expf(sloc[c] - mval); lsum += sloc[c]; }
    red[tid] = lsum; __syncthreads();
    for (int s2 = 128; s2 > 0; s2 >>= 1) {
        if (tid < s2) red[tid] += red[tid + s2];
        __syncthreads();
    }
    float inv = 1.0f / red[0];
#pragma unroll
    for (int c = 0; c < 8; ++c)
        probsOut[rowo + c * 256 + tid] = sloc[c] * inv;
}

// ---- K5c: PV partials per (bh, 256-l chunk); V read once per chunk. ----
#define PVP 260
__global__ __launch_bounds__(256) void pv_r12(
    const float* __restrict__ probsOut, const float* __restrict__ Vf,
    float* __restrict__ part)
{
    __shared__ float sVd[64 * PVP];     // [dk][l]
    __shared__ float pP[40 * 256];      // [u][l]
    int lq = blockIdx.x, bh = blockIdx.y, tid = threadIdx.x;
    int l0 = lq * 256;
#pragma unroll
    for (int it = 0; it < 10; ++it) {
        int idx = it * 256 + tid;
        int u = idx >> 6, l4 = idx & 63;
        *(f32x4*)&pP[u * 256 + l4 * 4] =
            *(const f32x4*)&probsOut[((size_t)bh * UU + u) * LL + l0 + l4 * 4];
    }
#pragma unroll
    for (int it = 0; it < 16; ++it) {
        int idx = it * 256 + tid;
        int l = idx >> 4, d4 = idx & 15;
        f32x4 v = *(const f32x4*)&Vf[((size_t)bh * LL + l0 + l) * DK + d4 * 4];
#pragma unroll
        for (int cc = 0; cc < 4; ++cc)
            sVd[(4 * d4 + cc) * PVP + l] = v[cc];
    }
    __syncthreads();
    int dk = tid & 63, ug = tid >> 6;
    float acc[10];
#pragma unroll
    for (int j = 0; j < 10; ++j) acc[j] = 0.f;
    for (int l4 = 0; l4 < 64; ++l4) {
        const f32x4 v4 = *(const f32x4*)&sVd[dk * PVP + l4 * 4];
#pragma unroll
        for (int j = 0; j < 10; ++j) {
            const f32x4 p4 = *(const f32x4*)&pP[(ug * 10 + j) * 256 + l4 * 4];
            acc[j] = fmaf(p4[0], v4[0], acc[j]);
            acc[j] = fmaf(p4[1], v4[1], acc[j]);
            acc[j] = fmaf(p4[2], v4[2], acc[j]);
            acc[j] = fmaf(p4[3], v4[3], acc[j]);
        }
    }
#pragma unroll
    for (int j = 0; j < 10; ++j) {
        int u = ug * 10 + j;
        part[(((size_t)bh * 8 + lq) * UU + u) * DK + dk] = acc[j];
    }
}

// ---- K5d: reduce 8 chunk-partials -> attnOut (deterministic order). ----
__global__ __launch_bounds__(64) void pvred_r12(
    const float* __restrict__ part, float* __restrict__ attnOut)
{
    int u = blockIdx.x, bh = blockIdx.y, dk = threadIdx.x;
    int b = bh >> 4, h = bh & 15;
    float s = 0.f;
#pragma unroll
    for (int lq = 0; lq < 8; ++lq)
        s += part[(((size_t)bh * 8 + lq) * UU + u) * DK + dk];
    attnOut[((size_t)b * UU + u) * DD + h * DK + dk] = s;
}

extern "C" void kernel_launch(void* const* d_in, const int* in_sizes, int n_in,
                              void* d_out, int out_size, void* d_ws, size_t ws_size,
                              hipStream_t stream) {
    (void)in_sizes; (void)n_in; (void)out_size; (void)ws_size;
    const void* query = d_in[0];
    const void* key   = d_in[1];
    const void* value = d_in[2];
    const void* Wq    = d_in[3];
    const void* bq    = d_in[4];
    const void* Wk    = d_in[5];
    const void* bk    = d_in[6];
    const void* Wv    = d_in[7];
    const void* bv    = d_in[8];

    char* w = (char*)d_ws;
    const size_t NE = (size_t)BB * HH * LL * DK;   // 4,194,304
    float* Kf  = (float*)w;  w += NE * 4;
    float* Vf  = (float*)w;  w += NE * 4;
    float* Qf  = (float*)w;  w += NE * 4;
    double* Mv = (double*)w; w += (size_t)BH * LL * 8;
    double* Kbar = (double*)w; w += (size_t)BH * DK * 8;
    int* sel   = (int*)w;    w += (size_t)BH * UU * 4;
    int* flag  = (int*)w;    w += 64;
    float* S    = (float*)w; w += (size_t)BH * UU * LL * 4;   // 10.49 MB
    float* part = (float*)w; w += (size_t)BH * 8 * UU * DK * 4; // 2.62 MB

    float* attnOut  = (float*)d_out;                       // FP32 outputs
    float* probsOut = attnOut + (size_t)BB * UU * DD;

    dim3 blk(256);
    detect_dtype_r8<<<1, blk, 0, stream>>>((const u16*)query, flag);
    proj_f4_r12<<<dim3(32, 8, 2), blk, 0, stream>>>(key, query, Wk, Wq, bk, bq,
                                                    Kf, Qf, flag);
    proj_mfma_v_r9<<<dim3(32, 8), blk, 0, stream>>>(value, Wv, bv, Vf, flag);
    kbar_r8<<<32, blk, 0, stream>>>(Kf, Kbar);
    stats_max_r12<<<dim3(LL / QT, 32), blk, 0, stream>>>(Qf, Kf, Kbar, Mv);
    topk_wave_r10<<<32, dim3(64), 0, stream>>>(Mv, sel);
    scores_r12<<<dim3(8, 32), blk, 0, stream>>>(Qf, Kf, sel, S);
    softmax_r12<<<dim3(UU, 32), blk, 0, stream>>>(S, probsOut);
    pv_r12<<<dim3(8, 32), blk, 0, stream>>>(probsOut, Vf, part);
    pvred_r12<<<dim3(UU, 32), dim3(64), 0, stream>>>(part, attnOut);
}

// Round 8
// 918.130 us; speedup vs baseline: 4.3229x; 1.0064x over previous
//
#include <hip/hip_runtime.h>
#include <hip/hip_bf16.h>

#define BB 2
#define LL 2048
#define DD 1024
#define HH 16
#define DK 64
#define UU 40
#define BH (BB*HH)

typedef unsigned short u16;
typedef float f32x4 __attribute__((ext_vector_type(4)));
typedef short s16x8 __attribute__((ext_vector_type(8)));

__device__ inline float b2f_r8(u16 x) {
    union { unsigned short u; __hip_bfloat16 b; } c; c.u = x;
    return __bfloat162float(c.b);
}
__device__ inline float ldf_r8(const void* p, size_t i, int isF) {
    return isF ? ((const float*)p)[i] : b2f_r8(((const u16*)p)[i]);
}
__device__ inline f32x4 ld4_r8(const void* p, size_t i, int isF) {
    if (isF) return *(const f32x4*)((const float*)p + i);
    ushort4 v = *(const ushort4*)((const u16*)p + i);
    f32x4 r;
    r[0] = b2f_r8(v.x); r[1] = b2f_r8(v.y); r[2] = b2f_r8(v.z); r[3] = b2f_r8(v.w);
    return r;
}
__device__ inline void cvt2_r8(float x, u16& h, u16& l) {
    union { __hip_bfloat16 b; u16 u; } ch, cl;
    ch.b = __float2bfloat16(x);
    float hf = __bfloat162float(ch.b);
    cl.b = __float2bfloat16(x - hf);
    h = ch.u; l = cl.u;
}

// ---------------- K0: input dtype probe ----------------
__global__ __launch_bounds__(256) void detect_dtype_r8(const u16* __restrict__ q,
                                                       int* __restrict__ flag) {
    __shared__ float red[256];
    int tid = threadIdx.x;
    float mx = 0.f;
    for (int i = tid; i < 4096; i += 256) {
        float v = fabsf(b2f_r8(q[i]));
        if (!(v < 1e30f)) v = 1e38f;
        mx = fmaxf(mx, v);
    }
    red[tid] = mx; __syncthreads();
    for (int s = 128; s > 0; s >>= 1) {
        if (tid < s) red[tid] = fmaxf(red[tid], red[tid + s]);
        __syncthreads();
    }
    if (tid == 0) *flag = (red[0] > 1e20f) ? 1 : 0;
}

#define PAD 132

// ---- K1: fp32 projection K (z=0) / Q (z=1). 128(n) x 64(f) tile, 32-deep
// k-chunks. Grid 32x16x2 = 1024 blocks -> 4 blocks/CU; LDS 25.6 KB (also 4).
// Staging uses the r10-proven conflict-free pattern (2-way max). Per-output
// fmaf chain: kc 0..31 x d 0..31 => c ascending 0..1023 — BIT-IDENTICAL.
__global__ __launch_bounds__(256) void proj_f4_r13(
    const void* __restrict__ key, const void* __restrict__ query,
    const void* __restrict__ Wk, const void* __restrict__ Wq,
    const void* __restrict__ bk, const void* __restrict__ bq,
    float* __restrict__ Kf, float* __restrict__ Qf,
    const int* __restrict__ flag)
{
    __shared__ float sX[32 * PAD];   // [d][n-row], 128 rows
    __shared__ float sW[32 * 68];    // [d][f-col], 64 cols
    int tid = threadIdx.x;
    int n0 = blockIdx.x * 128, f0 = blockIdx.y * 64, z = blockIdx.z;
    const void* X    = z ? query : key;
    const void* W    = z ? Wq    : Wk;
    const void* bias = z ? bq    : bk;
    float* out       = z ? Qf    : Kf;
    int isF = *flag;
    int tx = tid & 15, ty = tid >> 4;

    float acc[8][4];
#pragma unroll
    for (int a = 0; a < 8; ++a)
#pragma unroll
        for (int c = 0; c < 4; ++c) acc[a][c] = 0.f;

    for (int kc = 0; kc < 32; ++kc) {
        __syncthreads();
        // X tile: 128 rows x 32 d (conflict-free: 16 rows x 4 d4 per instr)
#pragma unroll
        for (int it = 0; it < 4; ++it) {
            int row = 64 * (it & 1) + (tid >> 2);
            int d4 = (tid & 3) | ((it >> 1) << 2);
            f32x4 v = ld4_r8(X, (size_t)(n0 + row) * DD + kc * 32 + d4 * 4, isF);
#pragma unroll
            for (int cc = 0; cc < 4; ++cc)
                sX[(4 * d4 + cc) * PAD + row] = v[cc];
        }
        // W tile: 64 f-rows x 32 d
#pragma unroll
        for (int it = 0; it < 2; ++it) {
            int row = tid >> 2;
            int d4 = (tid & 3) | (it << 2);
            f32x4 v = ld4_r8(W, (size_t)(f0 + row) * DD + kc * 32 + d4 * 4, isF);
#pragma unroll
            for (int cc = 0; cc < 4; ++cc)
                sW[(4 * d4 + cc) * 68 + row] = v[cc];
        }
        __syncthreads();
        for (int d = 0; d < 32; ++d) {
            const f32x4 xa = *(const f32x4*)(&sX[d * PAD + ty * 4]);
            const f32x4 xb = *(const f32x4*)(&sX[d * PAD + 64 + ty * 4]);
            const f32x4 wa = *(const f32x4*)(&sW[d * 68 + tx * 4]);
            float xv[8] = {xa[0], xa[1], xa[2], xa[3], xb[0], xb[1], xb[2], xb[3]};
#pragma unroll
            for (int a = 0; a < 8; ++a)
#pragma unroll
                for (int c = 0; c < 4; ++c)
                    acc[a][c] = fmaf(xv[a], wa[c], acc[a][c]);
        }
    }
#pragma unroll
    for (int a = 0; a < 8; ++a) {
        int n = n0 + (a >> 2) * 64 + ty * 4 + (a & 3);
        int b = n >> 11, l = n & (LL - 1);
#pragma unroll
        for (int c = 0; c < 4; ++c) {
            int f = f0 + tx * 4 + c;
            int h = f >> 6, dk = f & 63;
            out[((size_t)(b * HH + h) * LL + l) * DK + dk] =
                acc[a][c] + ldf_r8(bias, (size_t)f, isF);
        }
    }
}

// ---- K1b: V projection via bf16x3 MFMA (unchanged — proven). ----
#define LDK 72
__global__ __launch_bounds__(256) void proj_mfma_v_r9(
    const void* __restrict__ X, const void* __restrict__ W,
    const void* __restrict__ bias, float* __restrict__ out,
    const int* __restrict__ flag)
{
    __shared__ u16 Ahi[128 * LDK];
    __shared__ u16 Alo[128 * LDK];
    __shared__ u16 Bhi[128 * LDK];
    __shared__ u16 Blo[128 * LDK];
    int tid = threadIdx.x;
    int n0 = blockIdx.x * 128, f0 = blockIdx.y * 128;
    int isF = *flag;
    int lane = tid & 63, w = tid >> 6, wr = w >> 1, wc = w & 1;

    f32x4 acc[4][4] = {};

    for (int kc = 0; kc < 16; ++kc) {
        __syncthreads();
#pragma unroll
        for (int it = 0; it < 16; ++it) {
            int i = it * 256 + tid;
            int isB = i >> 11, j = i & 2047;
            int row = j >> 4, c = (j & 15) << 2;
            f32x4 v = ld4_r8(isB ? W : X, (size_t)((isB ? f0 : n0) + row) * DD + kc * 64 + c, isF);
            u16* hh = isB ? Bhi : Ahi;
            u16* ll = isB ? Blo : Alo;
            ushort4 h4, l4;
            cvt2_r8(v[0], h4.x, l4.x);
            cvt2_r8(v[1], h4.y, l4.y);
            cvt2_r8(v[2], h4.z, l4.z);
            cvt2_r8(v[3], h4.w, l4.w);
            *(ushort4*)&hh[row * LDK + c] = h4;
            *(ushort4*)&ll[row * LDK + c] = l4;
        }
        __syncthreads();
#pragma unroll
        for (int kk = 0; kk < 2; ++kk) {
            int koff = kk * 32 + (lane >> 4) * 8;
            s16x8 ah[4], al[4];
#pragma unroll
            for (int mi = 0; mi < 4; ++mi) {
                int r = wr * 64 + mi * 16 + (lane & 15);
                ah[mi] = *(const s16x8*)&Ahi[r * LDK + koff];
                al[mi] = *(const s16x8*)&Alo[r * LDK + koff];
            }
#pragma unroll
            for (int ni = 0; ni < 4; ++ni) {
                int r = wc * 64 + ni * 16 + (lane & 15);
                s16x8 bh = *(const s16x8*)&Bhi[r * LDK + koff];
                s16x8 bl = *(const s16x8*)&Blo[r * LDK + koff];
#pragma unroll
                for (int mi = 0; mi < 4; ++mi) {
                    acc[mi][ni] = __builtin_amdgcn_mfma_f32_16x16x32_bf16(ah[mi], bh, acc[mi][ni], 0, 0, 0);
                    acc[mi][ni] = __builtin_amdgcn_mfma_f32_16x16x32_bf16(al[mi], bh, acc[mi][ni], 0, 0, 0);
                    acc[mi][ni] = __builtin_amdgcn_mfma_f32_16x16x32_bf16(ah[mi], bl, acc[mi][ni], 0, 0, 0);
                }
            }
        }
    }

#pragma unroll
    for (int ni = 0; ni < 4; ++ni) {
        int f = f0 + wc * 64 + ni * 16 + (lane & 15);
        float bb = ldf_r8(bias, (size_t)f, isF);
        int h = f >> 6, dk = f & 63;
#pragma unroll
        for (int mi = 0; mi < 4; ++mi) {
            int nbase = n0 + wr * 64 + mi * 16 + ((lane >> 4) << 2);
#pragma unroll
            for (int j2 = 0; j2 < 4; ++j2) {
                int n = nbase + j2, b = n >> 11, l = n & (LL - 1);
                out[((size_t)(b * HH + h) * LL + l) * DK + dk] = acc[mi][ni][j2] + bb;
            }
        }
    }
}

// ---------------- K2b: Kbar (unchanged) ----------------
__global__ __launch_bounds__(256) void kbar_r8(
    const float* __restrict__ Kf, double* __restrict__ Kbar)
{
    __shared__ double red[256];
    int bh = blockIdx.x, tid = threadIdx.x;
    int d = tid & 63, seg = tid >> 6;
    double s = 0;
    for (int l = seg * 512; l < seg * 512 + 512; ++l)
        s += (double)Kf[((size_t)bh * LL + l) * DK + d];
    red[tid] = s; __syncthreads();
    if (tid < 128) red[tid] += red[tid + 128];
    __syncthreads();
    if (tid < 64) Kbar[(size_t)bh * DK + d] = (red[tid] + red[tid + 64]) * (1.0 / (double)LL);
}

// ---- K3: rowmax GEMM, QT=64 x KT=64 (grid 32x32 = 1024 -> 4 blocks/CU,
// LDS 34.8 KB). Score set + per-score d-ascending chain + commutative max +
// fp64 Q.Kbar chain all identical to proven r12 => identical Mv bits.
#define QT 64
__global__ __launch_bounds__(256) void stats_max_r13(
    const float* __restrict__ Qf, const float* __restrict__ Kf,
    const double* __restrict__ Kbar, double* __restrict__ Mv)
{
    __shared__ float sQ[64 * 68];
    __shared__ float sK[64 * 68];
    __shared__ float rowmax[QT];
    int tid = threadIdx.x;
    int q0 = blockIdx.x * QT, bh = blockIdx.y;
    int tx = tid & 15, ty = tid >> 4;

    // stage Q tile (64 rows x 64 d) d-major, conflict-free
    {
        const float* src = Qf + ((size_t)bh * LL + q0) * DK;
#pragma unroll
        for (int it = 0; it < 4; ++it) {
            int row = tid >> 2;
            int d4 = (tid & 3) | (it << 2);
            f32x4 v = *(const f32x4*)(src + (size_t)row * DK + d4 * 4);
#pragma unroll
            for (int cc = 0; cc < 4; ++cc)
                sQ[(4 * d4 + cc) * 68 + row] = v[cc];
        }
    }
    float rmax4[4];
#pragma unroll
    for (int a = 0; a < 4; ++a) rmax4[a] = -INFINITY;

    const float* kbase = Kf + (size_t)bh * LL * DK;
    for (int kc = 0; kc < 32; ++kc) {
        __syncthreads();
#pragma unroll
        for (int it = 0; it < 4; ++it) {
            int row = tid >> 2;
            int d4 = (tid & 3) | (it << 2);
            f32x4 v = *(const f32x4*)(kbase + (size_t)(kc * 64 + row) * DK + d4 * 4);
#pragma unroll
            for (int cc = 0; cc < 4; ++cc)
                sK[(4 * d4 + cc) * 68 + row] = v[cc];
        }
        __syncthreads();
        float acc[4][4];
#pragma unroll
        for (int a = 0; a < 4; ++a)
#pragma unroll
            for (int c = 0; c < 4; ++c) acc[a][c] = 0.f;
        for (int d = 0; d < 64; ++d) {
            const f32x4 qa = *(const f32x4*)(&sQ[d * 68 + ty * 4]);
            const f32x4 ka = *(const f32x4*)(&sK[d * 68 + tx * 4]);
#pragma unroll
            for (int a = 0; a < 4; ++a)
#pragma unroll
                for (int c = 0; c < 4; ++c)
                    acc[a][c] = fmaf(qa[a], ka[c], acc[a][c]);
        }
#pragma unroll
        for (int a = 0; a < 4; ++a)
#pragma unroll
            for (int c = 0; c < 4; ++c) rmax4[a] = fmaxf(rmax4[a], acc[a][c]);
    }
    // cross-tx max reduce within 16-lane groups (tx = lane&15)
#pragma unroll
    for (int a = 0; a < 4; ++a) {
        float v = rmax4[a];
        v = fmaxf(v, __shfl_xor(v, 1));
        v = fmaxf(v, __shfl_xor(v, 2));
        v = fmaxf(v, __shfl_xor(v, 4));
        v = fmaxf(v, __shfl_xor(v, 8));
        rmax4[a] = v;
    }
    if (tx == 0) {
#pragma unroll
        for (int a = 0; a < 4; ++a)
            rowmax[ty * 4 + a] = rmax4[a];
    }
    __syncthreads();
    if (tid < QT) {
        const double* kb = Kbar + (size_t)bh * DK;
        double s = 0;
#pragma unroll
        for (int d = 0; d < 64; ++d) s += (double)sQ[d * 68 + tid] * kb[d];
        Mv[(size_t)bh * LL + q0 + tid] = (double)rowmax[tid] - s;
    }
}

// ------- K4: exact top-40, one wave per bh (unchanged — proven). -------
__global__ __launch_bounds__(64) void topk_wave_r10(
    const double* __restrict__ Mv, int* __restrict__ sel)
{
    int bh = blockIdx.x, lane = threadIdx.x;
    double v[32];
#pragma unroll
    for (int t = 0; t < 32; ++t) v[t] = Mv[(size_t)bh * LL + t * 64 + lane];
    for (int u = 0; u < UU; ++u) {
        double bv = -1e301; int bi = LL;
#pragma unroll
        for (int t = 0; t < 32; ++t) {
            double x = v[t]; int j = t * 64 + lane;
            if (x > bv || (x == bv && j < bi)) { bv = x; bi = j; }
        }
#pragma unroll
        for (int off = 1; off < 64; off <<= 1) {
            double ov = __shfl_xor(bv, off); int oi = __shfl_xor(bi, off);
            if (ov > bv || (ov == bv && oi < bi)) { bv = ov; bi = oi; }
        }
        if ((bi & 63) == lane) {
            int ts = bi >> 6;
#pragma unroll
            for (int t = 0; t < 32; ++t)
                if (t == ts) v[t] = -1e302;
        }
        if (lane == 0) sel[bh * UU + u] = bi;
    }
}

// ---- K5a: S[u][l] per (bh, 256-l chunk); K read ONCE per chunk. ----
__global__ __launch_bounds__(256) void scores_r12(
    const float* __restrict__ Qf, const float* __restrict__ Kf,
    const int* __restrict__ sel, float* __restrict__ S)
{
    __shared__ float sK[256 * 68];
    __shared__ float qsm[40 * 68];
    __shared__ int qpos[UU];
    int lq = blockIdx.x, bh = blockIdx.y, tid = threadIdx.x;
    int l0 = lq * 256;
    if (tid < UU) qpos[tid] = sel[bh * UU + tid];
    __syncthreads();
    for (int i = tid; i < 640; i += 256) {
        int u = i >> 4, c4 = i & 15;
        *(f32x4*)&qsm[u * 68 + c4 * 4] =
            *(const f32x4*)&Qf[((size_t)bh * LL + qpos[u]) * DK + c4 * 4];
    }
#pragma unroll
    for (int it = 0; it < 16; ++it) {
        int idx = it * 256 + tid;
        int l = idx >> 4, d4 = idx & 15;
        *(f32x4*)&sK[l * 68 + d4 * 4] =
            *(const f32x4*)&Kf[((size_t)bh * LL + l0 + l) * DK + d4 * 4];
    }
    __syncthreads();
    int gu = tid >> 5, lt = tid & 31;
    float acc[5][8];
#pragma unroll
    for (int ui = 0; ui < 5; ++ui)
#pragma unroll
        for (int li = 0; li < 8; ++li) acc[ui][li] = 0.f;
    for (int d16 = 0; d16 < 16; ++d16) {
        f32x4 qf[5], kf[8];
#pragma unroll
        for (int ui = 0; ui < 5; ++ui)
            qf[ui] = *(const f32x4*)&qsm[(gu + 8 * ui) * 68 + d16 * 4];
#pragma unroll
        for (int li = 0; li < 8; ++li)
            kf[li] = *(const f32x4*)&sK[(lt + 32 * li) * 68 + d16 * 4];
#pragma unroll
        for (int ui = 0; ui < 5; ++ui)
#pragma unroll
            for (int li = 0; li < 8; ++li)
#pragma unroll
                for (int c = 0; c < 4; ++c)
                    acc[ui][li] = fmaf(qf[ui][c], kf[li][c], acc[ui][li]);
    }
#pragma unroll
    for (int ui = 0; ui < 5; ++ui) {
        int u = gu + 8 * ui;
        int qp = qpos[u];
#pragma unroll
        for (int li = 0; li < 8; ++li) {
            int l = l0 + lt + 32 * li;
            float s = acc[ui][li] * 0.125f;
            if (l > qp) s -= 1e9f;
            S[((size_t)bh * UU + u) * LL + l] = s;
        }
    }
}

// ---- K5b: row softmax -> probs (unchanged). ----
__global__ __launch_bounds__(256) void softmax_r12(
    const float* __restrict__ S, float* __restrict__ probsOut)
{
    __shared__ float red[256];
    int u = blockIdx.x, bh = blockIdx.y, tid = threadIdx.x;
    size_t rowo = ((size_t)bh * UU + u) * LL;
    float sloc[8];
    float lmax = -INFINITY;
#pragma unroll
    for (int c = 0; c < 8; ++c) {
        sloc[c] = S[rowo + c * 256 + tid];
        lmax = fmaxf(lmax, sloc[c]);
    }
    red[tid] = lmax; __syncthreads();
    for (int s2 = 128; s2 > 0; s2 >>= 1) {
        if (tid < s2) red[tid] = fmaxf(red[tid], red[tid + s2]);
        __syncthreads();
    }
    float mval = red[0];
    __syncthreads();
    float lsum = 0.f;
#pragma unroll
    for (int c = 0; c < 8; ++c) { sloc[c] = expf(sloc[c] - mval); lsum += sloc[c]; }
    red[tid] = lsum; __syncthreads();
    for (int s2 = 128; s2 > 0; s2 >>= 1) {
        if (tid < s2) red[tid] += red[tid + s2];
        __syncthreads();
    }
    float inv = 1.0f / red[0];
#pragma unroll
    for (int c = 0; c < 8; ++c)
        probsOut[rowo + c * 256 + tid] = sloc[c] * inv;
}

// ---- K5c: PV partials per (bh, 256-l chunk) (unchanged). ----
#define PVP 260
__global__ __launch_bounds__(256) void pv_r12(
    const float* __restrict__ probsOut, const float* __restrict__ Vf,
    float* __restrict__ part)
{
    __shared__ float sVd[64 * PVP];     // [dk][l]
    __shared__ float pP[40 * 256];      // [u][l]
    int lq = blockIdx.x, bh = blockIdx.y, tid = threadIdx.x;
    int l0 = lq * 256;
#pragma unroll
    for (int it = 0; it < 10; ++it) {
        int idx = it * 256 + tid;
        int u = idx >> 6, l4 = idx & 63;
        *(f32x4*)&pP[u * 256 + l4 * 4] =
            *(const f32x4*)&probsOut[((size_t)bh * UU + u) * LL + l0 + l4 * 4];
    }
#pragma unroll
    for (int it = 0; it < 16; ++it) {
        int idx = it * 256 + tid;
        int l = idx >> 4, d4 = idx & 15;
        f32x4 v = *(const f32x4*)&Vf[((size_t)bh * LL + l0 + l) * DK + d4 * 4];
#pragma unroll
        for (int cc = 0; cc < 4; ++cc)
            sVd[(4 * d4 + cc) * PVP + l] = v[cc];
    }
    __syncthreads();
    int dk = tid & 63, ug = tid >> 6;
    float acc[10];
#pragma unroll
    for (int j = 0; j < 10; ++j) acc[j] = 0.f;
    for (int l4 = 0; l4 < 64; ++l4) {
        const f32x4 v4 = *(const f32x4*)&sVd[dk * PVP + l4 * 4];
#pragma unroll
        for (int j = 0; j < 10; ++j) {
            const f32x4 p4 = *(const f32x4*)&pP[(ug * 10 + j) * 256 + l4 * 4];
            acc[j] = fmaf(p4[0], v4[0], acc[j]);
            acc[j] = fmaf(p4[1], v4[1], acc[j]);
            acc[j] = fmaf(p4[2], v4[2], acc[j]);
            acc[j] = fmaf(p4[3], v4[3], acc[j]);
        }
    }
#pragma unroll
    for (int j = 0; j < 10; ++j) {
        int u = ug * 10 + j;
        part[(((size_t)bh * 8 + lq) * UU + u) * DK + dk] = acc[j];
    }
}

// ---- K5d: reduce 8 chunk-partials -> attnOut (unchanged). ----
__global__ __launch_bounds__(64) void pvred_r12(
    const float* __restrict__ part, float* __restrict__ attnOut)
{
    int u = blockIdx.x, bh = blockIdx.y, dk = threadIdx.x;
    int b = bh >> 4, h = bh & 15;
    float s = 0.f;
#pragma unroll
    for (int lq = 0; lq < 8; ++lq)
        s += part[(((size_t)bh * 8 + lq) * UU + u) * DK + dk];
    attnOut[((size_t)b * UU + u) * DD + h * DK + dk] = s;
}

extern "C" void kernel_launch(void* const* d_in, const int* in_sizes, int n_in,
                              void* d_out, int out_size, void* d_ws, size_t ws_size,
                              hipStream_t stream) {
    (void)in_sizes; (void)n_in; (void)out_size; (void)ws_size;
    const void* query = d_in[0];
    const void* key   = d_in[1];
    const void* value = d_in[2];
    const void* Wq    = d_in[3];
    const void* bq    = d_in[4];
    const void* Wk    = d_in[5];
    const void* bk    = d_in[6];
    const void* Wv    = d_in[7];
    const void* bv    = d_in[8];

    char* w = (char*)d_ws;
    const size_t NE = (size_t)BB * HH * LL * DK;   // 4,194,304
    float* Kf  = (float*)w;  w += NE * 4;
    float* Vf  = (float*)w;  w += NE * 4;
    float* Qf  = (float*)w;  w += NE * 4;
    double* Mv = (double*)w; w += (size_t)BH * LL * 8;
    double* Kbar = (double*)w; w += (size_t)BH * DK * 8;
    int* sel   = (int*)w;    w += (size_t)BH * UU * 4;
    int* flag  = (int*)w;    w += 64;
    float* S    = (float*)w; w += (size_t)BH * UU * LL * 4;   // 10.49 MB
    float* part = (float*)w; w += (size_t)BH * 8 * UU * DK * 4; // 2.62 MB

    float* attnOut  = (float*)d_out;                       // FP32 outputs
    float* probsOut = attnOut + (size_t)BB * UU * DD;

    dim3 blk(256);
    detect_dtype_r8<<<1, blk, 0, stream>>>((const u16*)query, flag);
    proj_f4_r13<<<dim3(32, 16, 2), blk, 0, stream>>>(key, query, Wk, Wq, bk, bq,
                                                     Kf, Qf, flag);
    proj_mfma_v_r9<<<dim3(32, 8), blk, 0, stream>>>(value, Wv, bv, Vf, flag);
    kbar_r8<<<32, blk, 0, stream>>>(Kf, Kbar);
    stats_max_r13<<<dim3(LL / QT, 32), blk, 0, stream>>>(Qf, Kf, Kbar, Mv);
    topk_wave_r10<<<32, dim3(64), 0, stream>>>(Mv, sel);
    scores_r12<<<dim3(8, 32), blk, 0, stream>>>(Qf, Kf, sel, S);
    softmax_r12<<<dim3(UU, 32), blk, 0, stream>>>(S, probsOut);
    pv_r12<<<dim3(8, 32), blk, 0, stream>>>(probsOut, Vf, part);
    pvred_r12<<<dim3(UU, 32), dim3(64), 0, stream>>>(part, attnOut);
}

// Round 10
// 912.167 us; speedup vs baseline: 4.3512x; 1.0065x over previous
//
#include <hip/hip_runtime.h>
#include <hip/hip_bf16.h>

#define BB 2
#define LL 2048
#define DD 1024
#define HH 16
#define DK 64
#define UU 40
#define BH (BB*HH)

typedef unsigned short u16;
typedef float f32x4 __attribute__((ext_vector_type(4)));
typedef short s16x8 __attribute__((ext_vector_type(8)));

__device__ inline float b2f_r8(u16 x) {
    union { unsigned short u; __hip_bfloat16 b; } c; c.u = x;
    return __bfloat162float(c.b);
}
__device__ inline float ldf_r8(const void* p, size_t i, int isF) {
    return isF ? ((const float*)p)[i] : b2f_r8(((const u16*)p)[i]);
}
__device__ inline f32x4 ld4_r8(const void* p, size_t i, int isF) {
    if (isF) return *(const f32x4*)((const float*)p + i);
    ushort4 v = *(const ushort4*)((const u16*)p + i);
    f32x4 r;
    r[0] = b2f_r8(v.x); r[1] = b2f_r8(v.y); r[2] = b2f_r8(v.z); r[3] = b2f_r8(v.w);
    return r;
}
__device__ inline void cvt2_r8(float x, u16& h, u16& l) {
    union { __hip_bfloat16 b; u16 u; } ch, cl;
    ch.b = __float2bfloat16(x);
    float hf = __bfloat162float(ch.b);
    cl.b = __float2bfloat16(x - hf);
    h = ch.u; l = cl.u;
}

// ---------------- K0: input dtype probe ----------------
__global__ __launch_bounds__(256) void detect_dtype_r8(const u16* __restrict__ q,
                                                       int* __restrict__ flag) {
    __shared__ float red[256];
    int tid = threadIdx.x;
    float mx = 0.f;
    for (int i = tid; i < 4096; i += 256) {
        float v = fabsf(b2f_r8(q[i]));
        if (!(v < 1e30f)) v = 1e38f;
        mx = fmaxf(mx, v);
    }
    red[tid] = mx; __syncthreads();
    for (int s = 128; s > 0; s >>= 1) {
        if (tid < s) red[tid] = fmaxf(red[tid], red[tid + s]);
        __syncthreads();
    }
    if (tid == 0) *flag = (red[0] > 1e20f) ? 1 : 0;
}

#define PAD 132

// ---- K1: fp32 projection K (z=0) / Q (z=1) (unchanged — proven r13). ----
__global__ __launch_bounds__(256) void proj_f4_r13(
    const void* __restrict__ key, const void* __restrict__ query,
    const void* __restrict__ Wk, const void* __restrict__ Wq,
    const void* __restrict__ bk, const void* __restrict__ bq,
    float* __restrict__ Kf, float* __restrict__ Qf,
    const int* __restrict__ flag)
{
    __shared__ float sX[32 * PAD];   // [d][n-row], 128 rows
    __shared__ float sW[32 * 68];    // [d][f-col], 64 cols
    int tid = threadIdx.x;
    int n0 = blockIdx.x * 128, f0 = blockIdx.y * 64, z = blockIdx.z;
    const void* X    = z ? query : key;
    const void* W    = z ? Wq    : Wk;
    const void* bias = z ? bq    : bk;
    float* out       = z ? Qf    : Kf;
    int isF = *flag;
    int tx = tid & 15, ty = tid >> 4;

    float acc[8][4];
#pragma unroll
    for (int a = 0; a < 8; ++a)
#pragma unroll
        for (int c = 0; c < 4; ++c) acc[a][c] = 0.f;

    for (int kc = 0; kc < 32; ++kc) {
        __syncthreads();
#pragma unroll
        for (int it = 0; it < 4; ++it) {
            int row = 64 * (it & 1) + (tid >> 2);
            int d4 = (tid & 3) | ((it >> 1) << 2);
            f32x4 v = ld4_r8(X, (size_t)(n0 + row) * DD + kc * 32 + d4 * 4, isF);
#pragma unroll
            for (int cc = 0; cc < 4; ++cc)
                sX[(4 * d4 + cc) * PAD + row] = v[cc];
        }
#pragma unroll
        for (int it = 0; it < 2; ++it) {
            int row = tid >> 2;
            int d4 = (tid & 3) | (it << 2);
            f32x4 v = ld4_r8(W, (size_t)(f0 + row) * DD + kc * 32 + d4 * 4, isF);
#pragma unroll
            for (int cc = 0; cc < 4; ++cc)
                sW[(4 * d4 + cc) * 68 + row] = v[cc];
        }
        __syncthreads();
        for (int d = 0; d < 32; ++d) {
            const f32x4 xa = *(const f32x4*)(&sX[d * PAD + ty * 4]);
            const f32x4 xb = *(const f32x4*)(&sX[d * PAD + 64 + ty * 4]);
            const f32x4 wa = *(const f32x4*)(&sW[d * 68 + tx * 4]);
            float xv[8] = {xa[0], xa[1], xa[2], xa[3], xb[0], xb[1], xb[2], xb[3]};
#pragma unroll
            for (int a = 0; a < 8; ++a)
#pragma unroll
                for (int c = 0; c < 4; ++c)
                    acc[a][c] = fmaf(xv[a], wa[c], acc[a][c]);
        }
    }
#pragma unroll
    for (int a = 0; a < 8; ++a) {
        int n = n0 + (a >> 2) * 64 + ty * 4 + (a & 3);
        int b = n >> 11, l = n & (LL - 1);
#pragma unroll
        for (int c = 0; c < 4; ++c) {
            int f = f0 + tx * 4 + c;
            int h = f >> 6, dk = f & 63;
            out[((size_t)(b * HH + h) * LL + l) * DK + dk] =
                acc[a][c] + ldf_r8(bias, (size_t)f, isF);
        }
    }
}

// ---- K1b: V projection via bf16x3 MFMA (unchanged — proven). ----
#define LDK 72
__global__ __launch_bounds__(256) void proj_mfma_v_r9(
    const void* __restrict__ X, const void* __restrict__ W,
    const void* __restrict__ bias, float* __restrict__ out,
    const int* __restrict__ flag)
{
    __shared__ u16 Ahi[128 * LDK];
    __shared__ u16 Alo[128 * LDK];
    __shared__ u16 Bhi[128 * LDK];
    __shared__ u16 Blo[128 * LDK];
    int tid = threadIdx.x;
    int n0 = blockIdx.x * 128, f0 = blockIdx.y * 128;
    int isF = *flag;
    int lane = tid & 63, w = tid >> 6, wr = w >> 1, wc = w & 1;

    f32x4 acc[4][4] = {};

    for (int kc = 0; kc < 16; ++kc) {
        __syncthreads();
#pragma unroll
        for (int it = 0; it < 16; ++it) {
            int i = it * 256 + tid;
            int isB = i >> 11, j = i & 2047;
            int row = j >> 4, c = (j & 15) << 2;
            f32x4 v = ld4_r8(isB ? W : X, (size_t)((isB ? f0 : n0) + row) * DD + kc * 64 + c, isF);
            u16* hh = isB ? Bhi : Ahi;
            u16* ll = isB ? Blo : Alo;
            ushort4 h4, l4;
            cvt2_r8(v[0], h4.x, l4.x);
            cvt2_r8(v[1], h4.y, l4.y);
            cvt2_r8(v[2], h4.z, l4.z);
            cvt2_r8(v[3], h4.w, l4.w);
            *(ushort4*)&hh[row * LDK + c] = h4;
            *(ushort4*)&ll[row * LDK + c] = l4;
        }
        __syncthreads();
#pragma unroll
        for (int kk = 0; kk < 2; ++kk) {
            int koff = kk * 32 + (lane >> 4) * 8;
            s16x8 ah[4], al[4];
#pragma unroll
            for (int mi = 0; mi < 4; ++mi) {
                int r = wr * 64 + mi * 16 + (lane & 15);
                ah[mi] = *(const s16x8*)&Ahi[r * LDK + koff];
                al[mi] = *(const s16x8*)&Alo[r * LDK + koff];
            }
#pragma unroll
            for (int ni = 0; ni < 4; ++ni) {
                int r = wc * 64 + ni * 16 + (lane & 15);
                s16x8 bh = *(const s16x8*)&Bhi[r * LDK + koff];
                s16x8 bl = *(const s16x8*)&Blo[r * LDK + koff];
#pragma unroll
                for (int mi = 0; mi < 4; ++mi) {
                    acc[mi][ni] = __builtin_amdgcn_mfma_f32_16x16x32_bf16(ah[mi], bh, acc[mi][ni], 0, 0, 0);
                    acc[mi][ni] = __builtin_amdgcn_mfma_f32_16x16x32_bf16(al[mi], bh, acc[mi][ni], 0, 0, 0);
                    acc[mi][ni] = __builtin_amdgcn_mfma_f32_16x16x32_bf16(ah[mi], bl, acc[mi][ni], 0, 0, 0);
                }
            }
        }
    }

#pragma unroll
    for (int ni = 0; ni < 4; ++ni) {
        int f = f0 + wc * 64 + ni * 16 + (lane & 15);
        float bb = ldf_r8(bias, (size_t)f, isF);
        int h = f >> 6, dk = f & 63;
#pragma unroll
        for (int mi = 0; mi < 4; ++mi) {
            int nbase = n0 + wr * 64 + mi * 16 + ((lane >> 4) << 2);
#pragma unroll
            for (int j2 = 0; j2 < 4; ++j2) {
                int n = nbase + j2, b = n >> 11, l = n & (LL - 1);
                out[((size_t)(b * HH + h) * LL + l) * DK + dk] = acc[mi][ni][j2] + bb;
            }
        }
    }
}

// ---------------- K2b: Kbar (unchanged) ----------------
__global__ __launch_bounds__(256) void kbar_r8(
    const float* __restrict__ Kf, double* __restrict__ Kbar)
{
    __shared__ double red[256];
    int bh = blockIdx.x, tid = threadIdx.x;
    int d = tid & 63, seg = tid >> 6;
    double s = 0;
    for (int l = seg * 512; l < seg * 512 + 512; ++l)
        s += (double)Kf[((size_t)bh * LL + l) * DK + d];
    red[tid] = s; __syncthreads();
    if (tid < 128) red[tid] += red[tid + 128];
    __syncthreads();
    if (tid < 64) Kbar[(size_t)bh * DK + d] = (red[tid] + red[tid + 64]) * (1.0 / (double)LL);
}

// ---- K3: rowmax GEMM QT=64 x KT=64 (unchanged — r13, identical Mv bits). ----
#define QT 64
__global__ __launch_bounds__(256) void stats_max_r13(
    const float* __restrict__ Qf, const float* __restrict__ Kf,
    const double* __restrict__ Kbar, double* __restrict__ Mv)
{
    __shared__ float sQ[64 * 68];
    __shared__ float sK[64 * 68];
    __shared__ float rowmax[QT];
    int tid = threadIdx.x;
    int q0 = blockIdx.x * QT, bh = blockIdx.y;
    int tx = tid & 15, ty = tid >> 4;

    {
        const float* src = Qf + ((size_t)bh * LL + q0) * DK;
#pragma unroll
        for (int it = 0; it < 4; ++it) {
            int row = tid >> 2;
            int d4 = (tid & 3) | (it << 2);
            f32x4 v = *(const f32x4*)(src + (size_t)row * DK + d4 * 4);
#pragma unroll
            for (int cc = 0; cc < 4; ++cc)
                sQ[(4 * d4 + cc) * 68 + row] = v[cc];
        }
    }
    float rmax4[4];
#pragma unroll
    for (int a = 0; a < 4; ++a) rmax4[a] = -INFINITY;

    const float* kbase = Kf + (size_t)bh * LL * DK;
    for (int kc = 0; kc < 32; ++kc) {
        __syncthreads();
#pragma unroll
        for (int it = 0; it < 4; ++it) {
            int row = tid >> 2;
            int d4 = (tid & 3) | (it << 2);
            f32x4 v = *(const f32x4*)(kbase + (size_t)(kc * 64 + row) * DK + d4 * 4);
#pragma unroll
            for (int cc = 0; cc < 4; ++cc)
                sK[(4 * d4 + cc) * 68 + row] = v[cc];
        }
        __syncthreads();
        float acc[4][4];
#pragma unroll
        for (int a = 0; a < 4; ++a)
#pragma unroll
            for (int c = 0; c < 4; ++c) acc[a][c] = 0.f;
        for (int d = 0; d < 64; ++d) {
            const f32x4 qa = *(const f32x4*)(&sQ[d * 68 + ty * 4]);
            const f32x4 ka = *(const f32x4*)(&sK[d * 68 + tx * 4]);
#pragma unroll
            for (int a = 0; a < 4; ++a)
#pragma unroll
                for (int c = 0; c < 4; ++c)
                    acc[a][c] = fmaf(qa[a], ka[c], acc[a][c]);
        }
#pragma unroll
        for (int a = 0; a < 4; ++a)
#pragma unroll
            for (int c = 0; c < 4; ++c) rmax4[a] = fmaxf(rmax4[a], acc[a][c]);
    }
#pragma unroll
    for (int a = 0; a < 4; ++a) {
        float v = rmax4[a];
        v = fmaxf(v, __shfl_xor(v, 1));
        v = fmaxf(v, __shfl_xor(v, 2));
        v = fmaxf(v, __shfl_xor(v, 4));
        v = fmaxf(v, __shfl_xor(v, 8));
        rmax4[a] = v;
    }
    if (tx == 0) {
#pragma unroll
        for (int a = 0; a < 4; ++a)
            rowmax[ty * 4 + a] = rmax4[a];
    }
    __syncthreads();
    if (tid < QT) {
        const double* kb = Kbar + (size_t)bh * DK;
        double s = 0;
#pragma unroll
        for (int d = 0; d < 64; ++d) s += (double)sQ[d * 68 + tid] * kb[d];
        Mv[(size_t)bh * LL + q0 + tid] = (double)rowmax[tid] - s;
    }
}

// ------- K4: exact top-40, one wave per bh (unchanged — proven). -------
__global__ __launch_bounds__(64) void topk_wave_r10(
    const double* __restrict__ Mv, int* __restrict__ sel)
{
    int bh = blockIdx.x, lane = threadIdx.x;
    double v[32];
#pragma unroll
    for (int t = 0; t < 32; ++t) v[t] = Mv[(size_t)bh * LL + t * 64 + lane];
    for (int u = 0; u < UU; ++u) {
        double bv = -1e301; int bi = LL;
#pragma unroll
        for (int t = 0; t < 32; ++t) {
            double x = v[t]; int j = t * 64 + lane;
            if (x > bv || (x == bv && j < bi)) { bv = x; bi = j; }
        }
#pragma unroll
        for (int off = 1; off < 64; off <<= 1) {
            double ov = __shfl_xor(bv, off); int oi = __shfl_xor(bi, off);
            if (ov > bv || (ov == bv && oi < bi)) { bv = ov; bi = oi; }
        }
        if ((bi & 63) == lane) {
            int ts = bi >> 6;
#pragma unroll
            for (int t = 0; t < 32; ++t)
                if (t == ts) v[t] = -1e302;
        }
        if (lane == 0) sel[bh * UU + u] = bi;
    }
}

// ---- K5a: S[u][l] per (bh, 128-l chunk); LDS 46 KB -> 2 blocks/CU. ----
// Per-score fmaf chain identical to r12 (d16 0..15 x c 0..3) -> S bits same.
__global__ __launch_bounds__(256) void scores_r15(
    const float* __restrict__ Qf, const float* __restrict__ Kf,
    const int* __restrict__ sel, float* __restrict__ S)
{
    __shared__ float sK[128 * 68];
    __shared__ float qsm[40 * 68];
    __shared__ int qpos[UU];
    int lq = blockIdx.x, bh = blockIdx.y, tid = threadIdx.x;
    int l0 = lq * 128;
    if (tid < UU) qpos[tid] = sel[bh * UU + tid];
    __syncthreads();
    for (int i = tid; i < 640; i += 256) {
        int u = i >> 4, c4 = i & 15;
        *(f32x4*)&qsm[u * 68 + c4 * 4] =
            *(const f32x4*)&Qf[((size_t)bh * LL + qpos[u]) * DK + c4 * 4];
    }
#pragma unroll
    for (int it = 0; it < 8; ++it) {
        int idx = it * 256 + tid;
        int l = idx >> 4, d4 = idx & 15;
        *(f32x4*)&sK[l * 68 + d4 * 4] =
            *(const f32x4*)&Kf[((size_t)bh * LL + l0 + l) * DK + d4 * 4];
    }
    __syncthreads();
    int gu = tid >> 5, lt = tid & 31;
    float acc[5][4];
#pragma unroll
    for (int ui = 0; ui < 5; ++ui)
#pragma unroll
        for (int li = 0; li < 4; ++li) acc[ui][li] = 0.f;
    for (int d16 = 0; d16 < 16; ++d16) {
        f32x4 qf[5], kf[4];
#pragma unroll
        for (int ui = 0; ui < 5; ++ui)
            qf[ui] = *(const f32x4*)&qsm[(gu + 8 * ui) * 68 + d16 * 4];
#pragma unroll
        for (int li = 0; li < 4; ++li)
            kf[li] = *(const f32x4*)&sK[(lt + 32 * li) * 68 + d16 * 4];
#pragma unroll
        for (int ui = 0; ui < 5; ++ui)
#pragma unroll
            for (int li = 0; li < 4; ++li)
#pragma unroll
                for (int c = 0; c < 4; ++c)
                    acc[ui][li] = fmaf(qf[ui][c], kf[li][c], acc[ui][li]);
    }
#pragma unroll
    for (int ui = 0; ui < 5; ++ui) {
        int u = gu + 8 * ui;
        int qp = qpos[u];
#pragma unroll
        for (int li = 0; li < 4; ++li) {
            int l = l0 + lt + 32 * li;
            float s = acc[ui][li] * 0.125f;
            if (l > qp) s -= 1e9f;
            S[((size_t)bh * UU + u) * LL + l] = s;
        }
    }
}

// ---- K5b: row softmax -> probs (unchanged — probs bits identical). ----
__global__ __launch_bounds__(256) void softmax_r12(
    const float* __restrict__ S, float* __restrict__ probsOut)
{
    __shared__ float red[256];
    int u = blockIdx.x, bh = blockIdx.y, tid = threadIdx.x;
    size_t rowo = ((size_t)bh * UU + u) * LL;
    float sloc[8];
    float lmax = -INFINITY;
#pragma unroll
    for (int c = 0; c < 8; ++c) {
        sloc[c] = S[rowo + c * 256 + tid];
        lmax = fmaxf(lmax, sloc[c]);
    }
    red[tid] = lmax; __syncthreads();
    for (int s2 = 128; s2 > 0; s2 >>= 1) {
        if (tid < s2) red[tid] = fmaxf(red[tid], red[tid + s2]);
        __syncthreads();
    }
    float mval = red[0];
    __syncthreads();
    float lsum = 0.f;
#pragma unroll
    for (int c = 0; c < 8; ++c) { sloc[c] = expf(sloc[c] - mval); lsum += sloc[c]; }
    red[tid] = lsum; __syncthreads();
    for (int s2 = 128; s2 > 0; s2 >>= 1) {
        if (tid < s2) red[tid] += red[tid + s2];
        __syncthreads();
    }
    float inv = 1.0f / red[0];
#pragma unroll
    for (int c = 0; c < 8; ++c)
        probsOut[rowo + c * 256 + tid] = sloc[c] * inv;
}

// ---- K5c: PV partials per (bh, 256-l chunk, 20-u half). V from global
// (L2-resident, coalesced); only probs slice in LDS (20.5 KB) -> 2 blocks/CU,
// grid 512. Per-(u,dk) chain (l ascending, c ascending) identical to r12 ->
// attnOut bits unchanged.
__global__ __launch_bounds__(256) void pv_r15(
    const float* __restrict__ probsOut, const float* __restrict__ Vf,
    float* __restrict__ part)
{
    __shared__ float pP[20 * 256];      // [ur][l]
    int lq = blockIdx.x, bh = blockIdx.y, ug2 = blockIdx.z, tid = threadIdx.x;
    int l0 = lq * 256;
#pragma unroll
    for (int it = 0; it < 5; ++it) {
        int idx = it * 256 + tid;
        int ur = idx >> 6, l4 = idx & 63;
        *(f32x4*)&pP[ur * 256 + l4 * 4] =
            *(const f32x4*)&probsOut[((size_t)bh * UU + ug2 * 20 + ur) * LL + l0 + l4 * 4];
    }
    __syncthreads();
    int dk = tid & 63, ug = tid >> 6;
    const float* vb = Vf + ((size_t)bh * LL + l0) * DK + dk;
    float acc[5];
#pragma unroll
    for (int j = 0; j < 5; ++j) acc[j] = 0.f;
    for (int l4 = 0; l4 < 64; ++l4) {
        float vv0 = vb[(size_t)(l4 * 4 + 0) * DK];
        float vv1 = vb[(size_t)(l4 * 4 + 1) * DK];
        float vv2 = vb[(size_t)(l4 * 4 + 2) * DK];
        float vv3 = vb[(size_t)(l4 * 4 + 3) * DK];
#pragma unroll
        for (int j = 0; j < 5; ++j) {
            const f32x4 p4 = *(const f32x4*)&pP[(ug * 5 + j) * 256 + l4 * 4];
            acc[j] = fmaf(p4[0], vv0, acc[j]);
            acc[j] = fmaf(p4[1], vv1, acc[j]);
            acc[j] = fmaf(p4[2], vv2, acc[j]);
            acc[j] = fmaf(p4[3], vv3, acc[j]);
        }
    }
#pragma unroll
    for (int j = 0; j < 5; ++j) {
        int u = ug2 * 20 + ug * 5 + j;
        part[(((size_t)bh * 8 + lq) * UU + u) * DK + dk] = acc[j];
    }
}

// ---- K5d: reduce 8 chunk-partials -> attnOut (unchanged). ----
__global__ __launch_bounds__(64) void pvred_r12(
    const float* __restrict__ part, float* __restrict__ attnOut)
{
    int u = blockIdx.x, bh = blockIdx.y, dk = threadIdx.x;
    int b = bh >> 4, h = bh & 15;
    float s = 0.f;
#pragma unroll
    for (int lq = 0; lq < 8; ++lq)
        s += part[(((size_t)bh * 8 + lq) * UU + u) * DK + dk];
    attnOut[((size_t)b * UU + u) * DD + h * DK + dk] = s;
}

extern "C" void kernel_launch(void* const* d_in, const int* in_sizes, int n_in,
                              void* d_out, int out_size, void* d_ws, size_t ws_size,
                              hipStream_t stream) {
    (void)in_sizes; (void)n_in; (void)out_size; (void)ws_size;
    const void* query = d_in[0];
    const void* key   = d_in[1];
    const void* value = d_in[2];
    const void* Wq    = d_in[3];
    const void* bq    = d_in[4];
    const void* Wk    = d_in[5];
    const void* bk    = d_in[6];
    const void* Wv    = d_in[7];
    const void* bv    = d_in[8];

    char* w = (char*)d_ws;
    const size_t NE = (size_t)BB * HH * LL * DK;   // 4,194,304
    float* Kf  = (float*)w;  w += NE * 4;
    float* Vf  = (float*)w;  w += NE * 4;
    float* Qf  = (float*)w;  w += NE * 4;
    double* Mv = (double*)w; w += (size_t)BH * LL * 8;
    double* Kbar = (double*)w; w += (size_t)BH * DK * 8;
    int* sel   = (int*)w;    w += (size_t)BH * UU * 4;
    int* flag  = (int*)w;    w += 64;
    float* S    = (float*)w; w += (size_t)BH * UU * LL * 4;   // 10.49 MB
    float* part = (float*)w; w += (size_t)BH * 8 * UU * DK * 4; // 2.62 MB

    float* attnOut  = (float*)d_out;                       // FP32 outputs
    float* probsOut = attnOut + (size_t)BB * UU * DD;

    dim3 blk(256);
    detect_dtype_r8<<<1, blk, 0, stream>>>((const u16*)query, flag);
    proj_f4_r13<<<dim3(32, 16, 2), blk, 0, stream>>>(key, query, Wk, Wq, bk, bq,
                                                     Kf, Qf, flag);
    proj_mfma_v_r9<<<dim3(32, 8), blk, 0, stream>>>(value, Wv, bv, Vf, flag);
    kbar_r8<<<32, blk, 0, stream>>>(Kf, Kbar);
    stats_max_r13<<<dim3(LL / QT, 32), blk, 0, stream>>>(Qf, Kf, Kbar, Mv);
    topk_wave_r10<<<32, dim3(64), 0, stream>>>(Mv, sel);
    scores_r15<<<dim3(16, 32), blk, 0, stream>>>(Qf, Kf, sel, S);
    softmax_r12<<<dim3(UU, 32), blk, 0, stream>>>(S, probsOut);
    pv_r15<<<dim3(8, 32, 2), blk, 0, stream>>>(probsOut, Vf, part);
    pvred_r12<<<dim3(UU, 32), dim3(64), 0, stream>>>(part, attnOut);
}

// Round 11
// 821.148 us; speedup vs baseline: 4.8335x; 1.1108x over previous
//
#include <hip/hip_runtime.h>
#include <hip/hip_bf16.h>

#define BB 2
#define LL 2048
#define DD 1024
#define HH 16
#define DK 64
#define UU 40
#define BH (BB*HH)

typedef unsigned short u16;
typedef float f32x4 __attribute__((ext_vector_type(4)));
typedef short s16x8 __attribute__((ext_vector_type(8)));

__device__ inline float b2f_r8(u16 x) {
    union { unsigned short u; __hip_bfloat16 b; } c; c.u = x;
    return __bfloat162float(c.b);
}
__device__ inline float ldf_r8(const void* p, size_t i, int isF) {
    return isF ? ((const float*)p)[i] : b2f_r8(((const u16*)p)[i]);
}
__device__ inline f32x4 ld4_r8(const void* p, size_t i, int isF) {
    if (isF) return *(const f32x4*)((const float*)p + i);
    ushort4 v = *(const ushort4*)((const u16*)p + i);
    f32x4 r;
    r[0] = b2f_r8(v.x); r[1] = b2f_r8(v.y); r[2] = b2f_r8(v.z); r[3] = b2f_r8(v.w);
    return r;
}
__device__ inline void cvt2_r8(float x, u16& h, u16& l) {
    union { __hip_bfloat16 b; u16 u; } ch, cl;
    ch.b = __float2bfloat16(x);
    float hf = __bfloat162float(ch.b);
    cl.b = __float2bfloat16(x - hf);
    h = ch.u; l = cl.u;
}

// ---------------- K0: input dtype probe ----------------
__global__ __launch_bounds__(256) void detect_dtype_r8(const u16* __restrict__ q,
                                                       int* __restrict__ flag) {
    __shared__ float red[256];
    int tid = threadIdx.x;
    float mx = 0.f;
    for (int i = tid; i < 4096; i += 256) {
        float v = fabsf(b2f_r8(q[i]));
        if (!(v < 1e30f)) v = 1e38f;
        mx = fmaxf(mx, v);
    }
    red[tid] = mx; __syncthreads();
    for (int s = 128; s > 0; s >>= 1) {
        if (tid < s) red[tid] = fmaxf(red[tid], red[tid + s]);
        __syncthreads();
    }
    if (tid == 0) *flag = (red[0] > 1e20f) ? 1 : 0;
}

#define PAD 132

// ---- K1: fp32 projection K (z=0) / Q (z=1) (unchanged — proven r13). ----
__global__ __launch_bounds__(256) void proj_f4_r13(
    const void* __restrict__ key, const void* __restrict__ query,
    const void* __restrict__ Wk, const void* __restrict__ Wq,
    const void* __restrict__ bk, const void* __restrict__ bq,
    float* __restrict__ Kf, float* __restrict__ Qf,
    const int* __restrict__ flag)
{
    __shared__ float sX[32 * PAD];   // [d][n-row], 128 rows
    __shared__ float sW[32 * 68];    // [d][f-col], 64 cols
    int tid = threadIdx.x;
    int n0 = blockIdx.x * 128, f0 = blockIdx.y * 64, z = blockIdx.z;
    const void* X    = z ? query : key;
    const void* W    = z ? Wq    : Wk;
    const void* bias = z ? bq    : bk;
    float* out       = z ? Qf    : Kf;
    int isF = *flag;
    int tx = tid & 15, ty = tid >> 4;

    float acc[8][4];
#pragma unroll
    for (int a = 0; a < 8; ++a)
#pragma unroll
        for (int c = 0; c < 4; ++c) acc[a][c] = 0.f;

    for (int kc = 0; kc < 32; ++kc) {
        __syncthreads();
#pragma unroll
        for (int it = 0; it < 4; ++it) {
            int row = 64 * (it & 1) + (tid >> 2);
            int d4 = (tid & 3) | ((it >> 1) << 2);
            f32x4 v = ld4_r8(X, (size_t)(n0 + row) * DD + kc * 32 + d4 * 4, isF);
#pragma unroll
            for (int cc = 0; cc < 4; ++cc)
                sX[(4 * d4 + cc) * PAD + row] = v[cc];
        }
#pragma unroll
        for (int it = 0; it < 2; ++it) {
            int row = tid >> 2;
            int d4 = (tid & 3) | (it << 2);
            f32x4 v = ld4_r8(W, (size_t)(f0 + row) * DD + kc * 32 + d4 * 4, isF);
#pragma unroll
            for (int cc = 0; cc < 4; ++cc)
                sW[(4 * d4 + cc) * 68 + row] = v[cc];
        }
        __syncthreads();
        for (int d = 0; d < 32; ++d) {
            const f32x4 xa = *(const f32x4*)(&sX[d * PAD + ty * 4]);
            const f32x4 xb = *(const f32x4*)(&sX[d * PAD + 64 + ty * 4]);
            const f32x4 wa = *(const f32x4*)(&sW[d * 68 + tx * 4]);
            float xv[8] = {xa[0], xa[1], xa[2], xa[3], xb[0], xb[1], xb[2], xb[3]};
#pragma unroll
            for (int a = 0; a < 8; ++a)
#pragma unroll
                for (int c = 0; c < 4; ++c)
                    acc[a][c] = fmaf(xv[a], wa[c], acc[a][c]);
        }
    }
#pragma unroll
    for (int a = 0; a < 8; ++a) {
        int n = n0 + (a >> 2) * 64 + ty * 4 + (a & 3);
        int b = n >> 11, l = n & (LL - 1);
#pragma unroll
        for (int c = 0; c < 4; ++c) {
            int f = f0 + tx * 4 + c;
            int h = f >> 6, dk = f & 63;
            out[((size_t)(b * HH + h) * LL + l) * DK + dk] =
                acc[a][c] + ldf_r8(bias, (size_t)f, isF);
        }
    }
}

// ---- K1a: pre-convert Wv to bf16 hi/lo (one pass; kills 32x redundant cvt). ----
__global__ __launch_bounds__(256) void preconvW_r16(
    const void* __restrict__ Wv, u16* __restrict__ Whi, u16* __restrict__ Wlo,
    const int* __restrict__ flag)
{
    int isF = *flag;
    size_t i = ((size_t)blockIdx.x * 256 + threadIdx.x) * 4;   // 1024 blocks x 4 elem
    f32x4 v = ld4_r8(Wv, i, isF);
    ushort4 h4, l4;
    cvt2_r8(v[0], h4.x, l4.x);
    cvt2_r8(v[1], h4.y, l4.y);
    cvt2_r8(v[2], h4.z, l4.z);
    cvt2_r8(v[3], h4.w, l4.w);
    *(ushort4*)&Whi[i] = h4;
    *(ushort4*)&Wlo[i] = l4;
}

// ---- K1b: V projection via bf16x3 MFMA, 64(n) x 128(f) tile (LDS 55 KB ->
// 2 blocks/CU, grid 512 -> 2/CU). W from pre-converted hi/lo. Per-output MFMA
// sequence (kc -> kk -> {hh, lo.hi, hi.lo}) and fragment values unchanged vs
// r9 => Vf BIT-IDENTICAL.
#define LDK 72
__global__ __launch_bounds__(256) void proj_mfma_v_r16(
    const void* __restrict__ X, const u16* __restrict__ Whi,
    const u16* __restrict__ Wlo, const void* __restrict__ bias,
    float* __restrict__ out, const int* __restrict__ flag)
{
    __shared__ u16 Ahi[64 * LDK];
    __shared__ u16 Alo[64 * LDK];
    __shared__ u16 Bhi[128 * LDK];
    __shared__ u16 Blo[128 * LDK];
    int tid = threadIdx.x;
    int n0 = blockIdx.x * 64, f0 = blockIdx.y * 128;
    int isF = *flag;
    int lane = tid & 63, w = tid >> 6, wr = w >> 1, wc = w & 1;

    f32x4 acc[2][4] = {};

    for (int kc = 0; kc < 16; ++kc) {
        __syncthreads();
        // A: 64 rows x 64 c, converted in-flight (4096 elems, 16/thread)
#pragma unroll
        for (int it = 0; it < 4; ++it) {
            int i = it * 256 + tid;
            int row = i >> 4, c = (i & 15) << 2;
            f32x4 v = ld4_r8(X, (size_t)(n0 + row) * DD + kc * 64 + c, isF);
            ushort4 h4, l4;
            cvt2_r8(v[0], h4.x, l4.x);
            cvt2_r8(v[1], h4.y, l4.y);
            cvt2_r8(v[2], h4.z, l4.z);
            cvt2_r8(v[3], h4.w, l4.w);
            *(ushort4*)&Ahi[row * LDK + c] = h4;
            *(ushort4*)&Alo[row * LDK + c] = l4;
        }
        // B: 128 rows x 64 c, straight copies from pre-converted W
#pragma unroll
        for (int it = 0; it < 8; ++it) {
            int i = it * 256 + tid;
            int row = i >> 4, c = (i & 15) << 2;
            size_t go = (size_t)(f0 + row) * DD + kc * 64 + c;
            *(ushort4*)&Bhi[row * LDK + c] = *(const ushort4*)&Whi[go];
            *(ushort4*)&Blo[row * LDK + c] = *(const ushort4*)&Wlo[go];
        }
        __syncthreads();
#pragma unroll
        for (int kk = 0; kk < 2; ++kk) {
            int koff = kk * 32 + (lane >> 4) * 8;
            s16x8 ah[2], al[2];
#pragma unroll
            for (int mi = 0; mi < 2; ++mi) {
                int r = wr * 32 + mi * 16 + (lane & 15);
                ah[mi] = *(const s16x8*)&Ahi[r * LDK + koff];
                al[mi] = *(const s16x8*)&Alo[r * LDK + koff];
            }
#pragma unroll
            for (int ni = 0; ni < 4; ++ni) {
                int r = wc * 64 + ni * 16 + (lane & 15);
                s16x8 bh = *(const s16x8*)&Bhi[r * LDK + koff];
                s16x8 bl = *(const s16x8*)&Blo[r * LDK + koff];
#pragma unroll
                for (int mi = 0; mi < 2; ++mi) {
                    acc[mi][ni] = __builtin_amdgcn_mfma_f32_16x16x32_bf16(ah[mi], bh, acc[mi][ni], 0, 0, 0);
                    acc[mi][ni] = __builtin_amdgcn_mfma_f32_16x16x32_bf16(al[mi], bh, acc[mi][ni], 0, 0, 0);
                    acc[mi][ni] = __builtin_amdgcn_mfma_f32_16x16x32_bf16(ah[mi], bl, acc[mi][ni], 0, 0, 0);
                }
            }
        }
    }

#pragma unroll
    for (int ni = 0; ni < 4; ++ni) {
        int f = f0 + wc * 64 + ni * 16 + (lane & 15);
        float bb = ldf_r8(bias, (size_t)f, isF);
        int h = f >> 6, dk = f & 63;
#pragma unroll
        for (int mi = 0; mi < 2; ++mi) {
            int nbase = n0 + wr * 32 + mi * 16 + ((lane >> 4) << 2);
#pragma unroll
            for (int j2 = 0; j2 < 4; ++j2) {
                int n = nbase + j2, b = n >> 11, l = n & (LL - 1);
                out[((size_t)(b * HH + h) * LL + l) * DK + dk] = acc[mi][ni][j2] + bb;
            }
        }
    }
}

// ---------------- K2b: Kbar (unchanged) ----------------
__global__ __launch_bounds__(256) void kbar_r8(
    const float* __restrict__ Kf, double* __restrict__ Kbar)
{
    __shared__ double red[256];
    int bh = blockIdx.x, tid = threadIdx.x;
    int d = tid & 63, seg = tid >> 6;
    double s = 0;
    for (int l = seg * 512; l < seg * 512 + 512; ++l)
        s += (double)Kf[((size_t)bh * LL + l) * DK + d];
    red[tid] = s; __syncthreads();
    if (tid < 128) red[tid] += red[tid + 128];
    __syncthreads();
    if (tid < 64) Kbar[(size_t)bh * DK + d] = (red[tid] + red[tid + 64]) * (1.0 / (double)LL);
}

// ---- K3: rowmax GEMM, QT=128 x KT=64 (REVERT to proven r12 — ~205 us,
// 32 FMA per 3 b128 reads). Identical Mv bits. ----
#define QTS 128
__global__ __launch_bounds__(256) void stats_max_r12(
    const float* __restrict__ Qf, const float* __restrict__ Kf,
    const double* __restrict__ Kbar, double* __restrict__ Mv)
{
    __shared__ float sQ[64 * PAD];
    __shared__ float sK[64 * 68];
    __shared__ float rowmax[QTS];
    int tid = threadIdx.x;
    int q0 = blockIdx.x * QTS, bh = blockIdx.y;
    int tx = tid & 15, ty = tid >> 4;

    {
        const float* src = Qf + ((size_t)bh * LL + q0) * DK;
#pragma unroll
        for (int it = 0; it < 8; ++it) {
            int row = 64 * (it & 1) + (tid >> 2);
            int d4 = (tid & 3) | ((it >> 1) << 2);
            f32x4 v = *(const f32x4*)(src + (size_t)row * DK + d4 * 4);
#pragma unroll
            for (int cc = 0; cc < 4; ++cc)
                sQ[(4 * d4 + cc) * PAD + row] = v[cc];
        }
    }
    float rmax8[8];
#pragma unroll
    for (int a = 0; a < 8; ++a) rmax8[a] = -INFINITY;

    const float* kbase = Kf + (size_t)bh * LL * DK;
    for (int kc = 0; kc < 32; ++kc) {
        __syncthreads();
#pragma unroll
        for (int it = 0; it < 4; ++it) {
            int row = tid >> 2;
            int d4 = (tid & 3) | (it << 2);
            f32x4 v = *(const f32x4*)(kbase + (size_t)(kc * 64 + row) * DK + d4 * 4);
#pragma unroll
            for (int cc = 0; cc < 4; ++cc)
                sK[(4 * d4 + cc) * 68 + row] = v[cc];
        }
        __syncthreads();
        float acc[8][4];
#pragma unroll
        for (int a = 0; a < 8; ++a)
#pragma unroll
            for (int c = 0; c < 4; ++c) acc[a][c] = 0.f;
        for (int d = 0; d < 64; ++d) {
            const f32x4 qa = *(const f32x4*)(&sQ[d * PAD + ty * 4]);
            const f32x4 qb = *(const f32x4*)(&sQ[d * PAD + 64 + ty * 4]);
            const f32x4 ka = *(const f32x4*)(&sK[d * 68 + tx * 4]);
            float qv[8] = {qa[0], qa[1], qa[2], qa[3], qb[0], qb[1], qb[2], qb[3]};
#pragma unroll
            for (int a = 0; a < 8; ++a)
#pragma unroll
                for (int c = 0; c < 4; ++c)
                    acc[a][c] = fmaf(qv[a], ka[c], acc[a][c]);
        }
#pragma unroll
        for (int a = 0; a < 8; ++a)
#pragma unroll
            for (int c = 0; c < 4; ++c) rmax8[a] = fmaxf(rmax8[a], acc[a][c]);
    }
#pragma unroll
    for (int a = 0; a < 8; ++a) {
        float v = rmax8[a];
        v = fmaxf(v, __shfl_xor(v, 1));
        v = fmaxf(v, __shfl_xor(v, 2));
        v = fmaxf(v, __shfl_xor(v, 4));
        v = fmaxf(v, __shfl_xor(v, 8));
        rmax8[a] = v;
    }
    if (tx == 0) {
#pragma unroll
        for (int a = 0; a < 8; ++a) {
            int row = ty * 4 + (a & 3) + (a >> 2) * 64;
            rowmax[row] = rmax8[a];
        }
    }
    __syncthreads();
    if (tid < QTS) {
        const double* kb = Kbar + (size_t)bh * DK;
        double s = 0;
#pragma unroll
        for (int d = 0; d < 64; ++d) s += (double)sQ[d * PAD + tid] * kb[d];
        Mv[(size_t)bh * LL + q0 + tid] = (double)rowmax[tid] - s;
    }
}

// ------- K4: exact top-40, one wave per bh (unchanged — proven). -------
__global__ __launch_bounds__(64) void topk_wave_r10(
    const double* __restrict__ Mv, int* __restrict__ sel)
{
    int bh = blockIdx.x, lane = threadIdx.x;
    double v[32];
#pragma unroll
    for (int t = 0; t < 32; ++t) v[t] = Mv[(size_t)bh * LL + t * 64 + lane];
    for (int u = 0; u < UU; ++u) {
        double bv = -1e301; int bi = LL;
#pragma unroll
        for (int t = 0; t < 32; ++t) {
            double x = v[t]; int j = t * 64 + lane;
            if (x > bv || (x == bv && j < bi)) { bv = x; bi = j; }
        }
#pragma unroll
        for (int off = 1; off < 64; off <<= 1) {
            double ov = __shfl_xor(bv, off); int oi = __shfl_xor(bi, off);
            if (ov > bv || (ov == bv && oi < bi)) { bv = ov; bi = oi; }
        }
        if ((bi & 63) == lane) {
            int ts = bi >> 6;
#pragma unroll
            for (int t = 0; t < 32; ++t)
                if (t == ts) v[t] = -1e302;
        }
        if (lane == 0) sel[bh * UU + u] = bi;
    }
}

// ---- K5a: S[u][l] per (bh, 128-l chunk) (unchanged r15). ----
__global__ __launch_bounds__(256) void scores_r15(
    const float* __restrict__ Qf, const float* __restrict__ Kf,
    const int* __restrict__ sel, float* __restrict__ S)
{
    __shared__ float sK[128 * 68];
    __shared__ float qsm[40 * 68];
    __shared__ int qpos[UU];
    int lq = blockIdx.x, bh = blockIdx.y, tid = threadIdx.x;
    int l0 = lq * 128;
    if (tid < UU) qpos[tid] = sel[bh * UU + tid];
    __syncthreads();
    for (int i = tid; i < 640; i += 256) {
        int u = i >> 4, c4 = i & 15;
        *(f32x4*)&qsm[u * 68 + c4 * 4] =
            *(const f32x4*)&Qf[((size_t)bh * LL + qpos[u]) * DK + c4 * 4];
    }
#pragma unroll
    for (int it = 0; it < 8; ++it) {
        int idx = it * 256 + tid;
        int l = idx >> 4, d4 = idx & 15;
        *(f32x4*)&sK[l * 68 + d4 * 4] =
            *(const f32x4*)&Kf[((size_t)bh * LL + l0 + l) * DK + d4 * 4];
    }
    __syncthreads();
    int gu = tid >> 5, lt = tid & 31;
    float acc[5][4];
#pragma unroll
    for (int ui = 0; ui < 5; ++ui)
#pragma unroll
        for (int li = 0; li < 4; ++li) acc[ui][li] = 0.f;
    for (int d16 = 0; d16 < 16; ++d16) {
        f32x4 qf[5], kf[4];
#pragma unroll
        for (int ui = 0; ui < 5; ++ui)
            qf[ui] = *(const f32x4*)&qsm[(gu + 8 * ui) * 68 + d16 * 4];
#pragma unroll
        for (int li = 0; li < 4; ++li)
            kf[li] = *(const f32x4*)&sK[(lt + 32 * li) * 68 + d16 * 4];
#pragma unroll
        for (int ui = 0; ui < 5; ++ui)
#pragma unroll
            for (int li = 0; li < 4; ++li)
#pragma unroll
                for (int c = 0; c < 4; ++c)
                    acc[ui][li] = fmaf(qf[ui][c], kf[li][c], acc[ui][li]);
    }
#pragma unroll
    for (int ui = 0; ui < 5; ++ui) {
        int u = gu + 8 * ui;
        int qp = qpos[u];
#pragma unroll
        for (int li = 0; li < 4; ++li) {
            int l = l0 + lt + 32 * li;
            float s = acc[ui][li] * 0.125f;
            if (l > qp) s -= 1e9f;
            S[((size_t)bh * UU + u) * LL + l] = s;
        }
    }
}

// ---- K5b: row softmax -> probs (unchanged). ----
__global__ __launch_bounds__(256) void softmax_r12(
    const float* __restrict__ S, float* __restrict__ probsOut)
{
    __shared__ float red[256];
    int u = blockIdx.x, bh = blockIdx.y, tid = threadIdx.x;
    size_t rowo = ((size_t)bh * UU + u) * LL;
    float sloc[8];
    float lmax = -INFINITY;
#pragma unroll
    for (int c = 0; c < 8; ++c) {
        sloc[c] = S[rowo + c * 256 + tid];
        lmax = fmaxf(lmax, sloc[c]);
    }
    red[tid] = lmax; __syncthreads();
    for (int s2 = 128; s2 > 0; s2 >>= 1) {
        if (tid < s2) red[tid] = fmaxf(red[tid], red[tid + s2]);
        __syncthreads();
    }
    float mval = red[0];
    __syncthreads();
    float lsum = 0.f;
#pragma unroll
    for (int c = 0; c < 8; ++c) { sloc[c] = expf(sloc[c] - mval); lsum += sloc[c]; }
    red[tid] = lsum; __syncthreads();
    for (int s2 = 128; s2 > 0; s2 >>= 1) {
        if (tid < s2) red[tid] += red[tid + s2];
        __syncthreads();
    }
    float inv = 1.0f / red[0];
#pragma unroll
    for (int c = 0; c < 8; ++c)
        probsOut[rowo + c * 256 + tid] = sloc[c] * inv;
}

// ---- K5c: PV partials (unchanged r15). ----
__global__ __launch_bounds__(256) void pv_r15(
    const float* __restrict__ probsOut, const float* __restrict__ Vf,
    float* __restrict__ part)
{
    __shared__ float pP[20 * 256];      // [ur][l]
    int lq = blockIdx.x, bh = blockIdx.y, ug2 = blockIdx.z, tid = threadIdx.x;
    int l0 = lq * 256;
#pragma unroll
    for (int it = 0; it < 5; ++it) {
        int idx = it * 256 + tid;
        int ur = idx >> 6, l4 = idx & 63;
        *(f32x4*)&pP[ur * 256 + l4 * 4] =
            *(const f32x4*)&probsOut[((size_t)bh * UU + ug2 * 20 + ur) * LL + l0 + l4 * 4];
    }
    __syncthreads();
    int dk = tid & 63, ug = tid >> 6;
    const float* vb = Vf + ((size_t)bh * LL + l0) * DK + dk;
    float acc[5];
#pragma unroll
    for (int j = 0; j < 5; ++j) acc[j] = 0.f;
    for (int l4 = 0; l4 < 64; ++l4) {
        float vv0 = vb[(size_t)(l4 * 4 + 0) * DK];
        float vv1 = vb[(size_t)(l4 * 4 + 1) * DK];
        float vv2 = vb[(size_t)(l4 * 4 + 2) * DK];
        float vv3 = vb[(size_t)(l4 * 4 + 3) * DK];
#pragma unroll
        for (int j = 0; j < 5; ++j) {
            const f32x4 p4 = *(const f32x4*)&pP[(ug * 5 + j) * 256 + l4 * 4];
            acc[j] = fmaf(p4[0], vv0, acc[j]);
            acc[j] = fmaf(p4[1], vv1, acc[j]);
            acc[j] = fmaf(p4[2], vv2, acc[j]);
            acc[j] = fmaf(p4[3], vv3, acc[j]);
        }
    }
#pragma unroll
    for (int j = 0; j < 5; ++j) {
        int u = ug2 * 20 + ug * 5 + j;
        part[(((size_t)bh * 8 + lq) * UU + u) * DK + dk] = acc[j];
    }
}

// ---- K5d: reduce 8 chunk-partials -> attnOut (unchanged). ----
__global__ __launch_bounds__(64) void pvred_r12(
    const float* __restrict__ part, float* __restrict__ attnOut)
{
    int u = blockIdx.x, bh = blockIdx.y, dk = threadIdx.x;
    int b = bh >> 4, h = bh & 15;
    float s = 0.f;
#pragma unroll
    for (int lq = 0; lq < 8; ++lq)
        s += part[(((size_t)bh * 8 + lq) * UU + u) * DK + dk];
    attnOut[((size_t)b * UU + u) * DD + h * DK + dk] = s;
}

extern "C" void kernel_launch(void* const* d_in, const int* in_sizes, int n_in,
                              void* d_out, int out_size, void* d_ws, size_t ws_size,
                              hipStream_t stream) {
    (void)in_sizes; (void)n_in; (void)out_size; (void)ws_size;
    const void* query = d_in[0];
    const void* key   = d_in[1];
    const void* value = d_in[2];
    const void* Wq    = d_in[3];
    const void* bq    = d_in[4];
    const void* Wk    = d_in[5];
    const void* bk    = d_in[6];
    const void* Wv    = d_in[7];
    const void* bv    = d_in[8];

    char* w = (char*)d_ws;
    const size_t NE = (size_t)BB * HH * LL * DK;   // 4,194,304
    float* Kf  = (float*)w;  w += NE * 4;
    float* Vf  = (float*)w;  w += NE * 4;
    float* Qf  = (float*)w;  w += NE * 4;
    double* Mv = (double*)w; w += (size_t)BH * LL * 8;
    double* Kbar = (double*)w; w += (size_t)BH * DK * 8;
    int* sel   = (int*)w;    w += (size_t)BH * UU * 4;
    int* flag  = (int*)w;    w += 64;
    float* S    = (float*)w; w += (size_t)BH * UU * LL * 4;    // 10.49 MB
    float* part = (float*)w; w += (size_t)BH * 8 * UU * DK * 4; // 2.62 MB
    u16* Whi = (u16*)w;      w += (size_t)DD * DD * 2;          // 2.10 MB
    u16* Wlo = (u16*)w;      w += (size_t)DD * DD * 2;          // 2.10 MB

    float* attnOut  = (float*)d_out;                       // FP32 outputs
    float* probsOut = attnOut + (size_t)BB * UU * DD;

    dim3 blk(256);
    detect_dtype_r8<<<1, blk, 0, stream>>>((const u16*)query, flag);
    preconvW_r16<<<1024, blk, 0, stream>>>(Wv, Whi, Wlo, flag);
    proj_f4_r13<<<dim3(32, 16, 2), blk, 0, stream>>>(key, query, Wk, Wq, bk, bq,
                                                     Kf, Qf, flag);
    proj_mfma_v_r16<<<dim3(64, 8), blk, 0, stream>>>(value, Whi, Wlo, bv, Vf, flag);
    kbar_r8<<<32, blk, 0, stream>>>(Kf, Kbar);
    stats_max_r12<<<dim3(LL / QTS, 32), blk, 0, stream>>>(Qf, Kf, Kbar, Mv);
    topk_wave_r10<<<32, dim3(64), 0, stream>>>(Mv, sel);
    scores_r15<<<dim3(16, 32), blk, 0, stream>>>(Qf, Kf, sel, S);
    softmax_r12<<<dim3(UU, 32), blk, 0, stream>>>(S, probsOut);
    pv_r15<<<dim3(8, 32, 2), blk, 0, stream>>>(probsOut, Vf, part);
    pvred_r12<<<dim3(UU, 32), dim3(64), 0, stream>>>(part, attnOut);
}